// Round 2
// baseline (1872.085 us; speedup 1.0000x reference)
//
#include <hip/hip_runtime.h>
#include <math.h>

#define HW 16384

// ---------------------------------------------------------------------------
// conv1x1: out[b,o,n] = act( sum_c W[o,c] * (in[b,c,n] (+ in2[b,c,n])) )
// in layout: [b][128][HW]. grid = nBatches*256, block = 256.
// ---------------------------------------------------------------------------
template<int O, int ACT, bool ADD2>
__global__ __launch_bounds__(256)
void conv1x1_k(const float* __restrict__ in, const float* __restrict__ in2,
               const float* __restrict__ W, float* __restrict__ out)
{
    __shared__ float tile[128][64];
    int t = threadIdx.x;
    int gb = blockIdx.x;
    int b = gb >> 8;              // 256 tiles per batch
    int n0 = (gb & 255) << 6;
    const float* inb = in + (size_t)b * 128 * HW + n0;
    const float* in2b = in2 ? (in2 + (size_t)b * 128 * HW + n0) : nullptr;
    #pragma unroll
    for (int i = 0; i < 32; ++i) {
        int idx = t + i * 256;
        int c = idx >> 6, j = idx & 63;
        float v = inb[(size_t)c * HW + j];
        if (ADD2) v += in2b[(size_t)c * HW + j];
        tile[c][j] = v;
    }
    __syncthreads();
    int j = t & 63;
    int og = __builtin_amdgcn_readfirstlane((int)(t >> 6));  // wave-uniform
    const int PER = O / 4;
    for (int k = 0; k < PER; k += 4) {
        int o0 = og * PER + k;
        const float* w0 = W + (size_t)o0 * 128;
        float a0 = 0.f, a1 = 0.f, a2 = 0.f, a3 = 0.f;
        #pragma unroll 8
        for (int c = 0; c < 128; ++c) {
            float v = tile[c][j];
            a0 += w0[c] * v;
            a1 += w0[128 + c] * v;
            a2 += w0[256 + c] * v;
            a3 += w0[384 + c] * v;
        }
        float r[4] = {a0, a1, a2, a3};
        #pragma unroll
        for (int i = 0; i < 4; ++i) {
            float v = r[i];
            if (ACT == 1) v = 0.5f * v * (1.0f + erff(v * 0.70710678118654752f));
            out[((size_t)b * O + (o0 + i)) * HW + n0 + j] = v;
        }
    }
}

// ---------------------------------------------------------------------------
// depthwise 3x3 SAME on V buffer ([b][128][HW] layout)
// ---------------------------------------------------------------------------
__global__ __launch_bounds__(256)
void dwconv_k(const float* __restrict__ V, const float* __restrict__ Wdw,
              float* __restrict__ vconv)
{
    int tid = blockIdx.x * 256 + threadIdx.x;   // B*128*HW threads
    int e = tid & (HW - 1);
    int bc = tid >> 14;
    int c = bc & 127;
    int y = e >> 7, x = e & 127;
    const float* vin = V + (size_t)bc * HW;
    const float* wf = Wdw + c * 9;
    float acc = 0.f;
    #pragma unroll
    for (int dy = 0; dy < 3; ++dy) {
        int yy = y + dy - 1;
        if (yy < 0 || yy > 127) continue;
        #pragma unroll
        for (int dx = 0; dx < 3; ++dx) {
            int xx = x + dx - 1;
            if (xx < 0 || xx > 127) continue;
            acc += wf[dy * 3 + dx] * vin[yy * 128 + xx];
        }
    }
    vconv[(size_t)bc * HW + e] = acc;
}

// ---------------------------------------------------------------------------
// fused S partials: computes q,k tiles on the fly from x and W_qkv.
// grid = 64 (bh) x 16 (n-slices of 1024), block 256.
// Sp[(bh*16+ns)*256 + c*16+d] = sum over slice of q[c,n]k[d,n]
// ---------------------------------------------------------------------------
__global__ __launch_bounds__(256)
void attn_s_fused_k(const float* __restrict__ x, const float* __restrict__ Wqkv,
                    float* __restrict__ Sp)
{
    __shared__ float Wq[16][128];
    __shared__ float Wk[16][128];
    __shared__ float xs[128][64];
    __shared__ float qs[16][65];
    __shared__ float ks[16][65];
    int bh = blockIdx.x >> 4;
    int ns = blockIdx.x & 15;
    int b = bh >> 3, h = bh & 7;
    int t = threadIdx.x;
    #pragma unroll
    for (int i = 0; i < 8; ++i) {
        int idx = t + i * 256;       // 0..2047
        int r = idx >> 7, ci = idx & 127;
        Wq[r][ci] = Wqkv[(size_t)(h * 16 + r) * 128 + ci];
        Wk[r][ci] = Wqkv[(size_t)(128 + h * 16 + r) * 128 + ci];
    }
    const float* xb = x + (size_t)b * 128 * HW + ns * 1024;
    float Sacc = 0.f;
    int sc = t >> 4, sd = t & 15;
    for (int nc = 0; nc < 16; ++nc) {
        __syncthreads();
        #pragma unroll
        for (int i = 0; i < 32; ++i) {
            int idx = t + i * 256;
            int ci = idx >> 6, j = idx & 63;
            xs[ci][j] = xb[(size_t)ci * HW + nc * 64 + j];
        }
        __syncthreads();
        #pragma unroll
        for (int i = 0; i < 4; ++i) {
            int vi = t + i * 256;
            int c = vi >> 6, j = vi & 63;
            float aq = 0.f, ak = 0.f;
            #pragma unroll 8
            for (int ci = 0; ci < 128; ++ci) {
                float v = xs[ci][j];
                aq += Wq[c][ci] * v;
                ak += Wk[c][ci] * v;
            }
            qs[c][j] = aq;
            ks[c][j] = ak;
        }
        __syncthreads();
        #pragma unroll 16
        for (int j = 0; j < 64; ++j)
            Sacc += qs[sc][j] * ks[sd][j];
    }
    Sp[(size_t)blockIdx.x * 256 + t] = Sacc;
}

// reduce partials + scale + softmax over d. 1024 rows (bh, c), 16 wide.
__global__ void attn_softmax_k(const float* __restrict__ Sp, float* __restrict__ S,
                               const float* __restrict__ scale)
{
    int row = blockIdx.x * blockDim.x + threadIdx.x;
    if (row >= 64 * 16) return;
    int bh = row >> 4;
    int c = row & 15;
    int h = bh & 7;
    float sc = scale[h];
    float v[16];
    #pragma unroll
    for (int d = 0; d < 16; ++d) {
        float s = 0.f;
        for (int ns = 0; ns < 16; ++ns)
            s += Sp[((size_t)(bh * 16 + ns)) * 256 + c * 16 + d];
        v[d] = s * sc;
    }
    float m = v[0];
    #pragma unroll
    for (int d = 1; d < 16; ++d) m = fmaxf(m, v[d]);
    float sum = 0.f;
    #pragma unroll
    for (int d = 0; d < 16; ++d) { v[d] = expf(v[d] - m); sum += v[d]; }
    float inv = 1.f / sum;
    #pragma unroll
    for (int d = 0; d < 16; ++d) S[(size_t)bh * 256 + c * 16 + d] = v[d] * inv;
}

// PV in-place over V: out[c,n] = sum_d A[c,d] v[d,n]. grid = 64 bh x 64 n-tiles
__global__ __launch_bounds__(256)
void attn_pv_k(float* __restrict__ V, const float* __restrict__ S)
{
    __shared__ float At[256];
    __shared__ float vt[16][256];
    int bh = blockIdx.x >> 6;
    int nt = blockIdx.x & 63;
    int b = bh >> 3, h = bh & 7;
    int t = threadIdx.x;
    At[t] = S[(size_t)bh * 256 + t];
    float* vbase = V + ((size_t)(b * 128) + h * 16) * HW + nt * 256;
    #pragma unroll
    for (int i = 0; i < 16; ++i) {
        int idx = t + i * 256;
        int d = idx >> 8, jj = idx & 255;
        vt[d][jj] = vbase[(size_t)d * HW + jj];
    }
    __syncthreads();
    float vv[16];
    #pragma unroll
    for (int d = 0; d < 16; ++d) vv[d] = vt[d][t];
    #pragma unroll
    for (int c = 0; c < 16; ++c) {
        float acc = 0.f;
        #pragma unroll
        for (int d = 0; d < 16; ++d) acc += At[c * 16 + d] * vv[d];
        vbase[(size_t)c * HW + t] = acc;
    }
}

// ---------------------------------------------------------------------------
// FFT machinery: radix-2, 128-point. DIF fwd (natural->bitrev), DIT inv.
// ---------------------------------------------------------------------------
__device__ __forceinline__ void fft_stage_dif(float2 (*buf)[128], int t, int s)
{
    int mh = 64 >> s;
    #pragma unroll
    for (int i = 0; i < 4; ++i) {
        int idx = t + i * 256;
        int rl = idx >> 6;
        int bf = idx & 63;
        int blk = bf >> (6 - s);
        int jj = bf & (mh - 1);
        int base = (blk << (7 - s)) + jj;
        float2 a = buf[rl][base];
        float2 b = buf[rl][base + mh];
        float ang = -6.283185307179586f * (float)jj / (float)(mh * 2);
        float sn, cs; sincosf(ang, &sn, &cs);
        float dx = a.x - b.x, dy = a.y - b.y;
        buf[rl][base] = make_float2(a.x + b.x, a.y + b.y);
        buf[rl][base + mh] = make_float2(dx * cs - dy * sn, dx * sn + dy * cs);
    }
}

__device__ __forceinline__ void fft_stage_dit(float2 (*buf)[128], int t, int s)
{
    int mh = 64 >> s;
    #pragma unroll
    for (int i = 0; i < 4; ++i) {
        int idx = t + i * 256;
        int rl = idx >> 6;
        int bf = idx & 63;
        int blk = bf >> (6 - s);
        int jj = bf & (mh - 1);
        int base = (blk << (7 - s)) + jj;
        float2 a = buf[rl][base];
        float2 b = buf[rl][base + mh];
        float ang = 6.283185307179586f * (float)jj / (float)(mh * 2);
        float sn, cs; sincosf(ang, &sn, &cs);
        float tx = b.x * cs - b.y * sn, ty = b.x * sn + b.y * cs;
        buf[rl][base] = make_float2(a.x + tx, a.y + ty);
        buf[rl][base + mh] = make_float2(a.x - tx, a.y - ty);
    }
}

__device__ __forceinline__ void fft16_fwd(float2 (*buf)[128], int t)
{
    for (int s = 0; s < 7; ++s) { __syncthreads(); fft_stage_dif(buf, t, s); }
    __syncthreads();
}
__device__ __forceinline__ void fft16_inv(float2 (*buf)[128], int t)
{
    for (int s = 6; s >= 0; --s) { __syncthreads(); fft_stage_dit(buf, t, s); }
    __syncthreads();
}

// P1: z = x + i*sw, row FFT over w, write transposed A[ch][i1][r]
// grid = nch*8 blocks
__global__ __launch_bounds__(256)
void fft_p1_k(const float* __restrict__ x, const float* __restrict__ sw,
              float2* __restrict__ A)
{
    __shared__ float2 buf[16][128];
    int t = threadIdx.x;
    int ch = blockIdx.x >> 3;
    int rg = blockIdx.x & 7;
    size_t base = (size_t)ch * HW + rg * 2048;
    #pragma unroll
    for (int i = 0; i < 8; ++i) {
        int idx = t + i * 256;
        int rl = idx >> 7, cc = idx & 127;
        buf[rl][cc] = make_float2(x[base + rl * 128 + cc], sw[base + rl * 128 + cc]);
    }
    fft16_fwd(buf, t);
    size_t abase = (size_t)ch * HW + rg * 16;
    #pragma unroll
    for (int i = 0; i < 8; ++i) {
        int idx = t + i * 256;
        int rl = idx & 15, k1 = idx >> 4;
        A[abase + (size_t)k1 * 128 + rl] = buf[rl][k1];
    }
}

// P2: in-place forward FFT along second dim. grid = nch*16384/2048
__global__ __launch_bounds__(256)
void fft_p2_k(float2* __restrict__ A)
{
    __shared__ float2 buf[16][128];
    int t = threadIdx.x;
    size_t base = (size_t)(blockIdx.x) * 2048;
    #pragma unroll
    for (int i = 0; i < 8; ++i) {
        int idx = t + i * 256;
        buf[idx >> 7][idx & 127] = A[base + idx];
    }
    fft16_fwd(buf, t);
    #pragma unroll
    for (int i = 0; i < 8; ++i) {
        int idx = t + i * 256;
        A[base + idx] = buf[idx >> 7][idx & 127];
    }
}

// P3: Hermitian split + product (in-place, pair-owner writes both)
// grid = nch*16384/256
__global__ __launch_bounds__(256)
void fft_p3_k(float2* __restrict__ A)
{
    int tid = blockIdx.x * 256 + threadIdx.x;
    int ch = tid >> 14;
    int e = tid & 16383;
    int i1 = e >> 7, i2 = e & 127;
    int k1 = __brev((unsigned)i1) >> 25;
    int k2 = __brev((unsigned)i2) >> 25;
    int j1 = __brev((unsigned)((128 - k1) & 127)) >> 25;
    int j2 = __brev((unsigned)((128 - k2) & 127)) >> 25;
    int ej = j1 * 128 + j2;
    if (e > ej) return;
    size_t cb = (size_t)ch * HW;
    float2 z1 = A[cb + e];
    float2 z2 = A[cb + ej];
    float2 X = make_float2(0.5f * (z1.x + z2.x), 0.5f * (z1.y - z2.y));
    float Dx = z1.x - z2.x, Dy = z1.y + z2.y;
    float2 Wf = make_float2(0.5f * Dy, -0.5f * Dx);
    float2 Y = make_float2(X.x * Wf.x - X.y * Wf.y, X.x * Wf.y + X.y * Wf.x);
    A[cb + e] = Y;
    if (ej != e) A[cb + ej] = make_float2(Y.x, -Y.y);
}

// P4: in-place inverse FFT along second dim
__global__ __launch_bounds__(256)
void fft_p4_k(float2* __restrict__ A)
{
    __shared__ float2 buf[16][128];
    int t = threadIdx.x;
    size_t base = (size_t)(blockIdx.x) * 2048;
    #pragma unroll
    for (int i = 0; i < 8; ++i) {
        int idx = t + i * 256;
        buf[idx >> 7][idx & 127] = A[base + idx];
    }
    fft16_inv(buf, t);
    #pragma unroll
    for (int i = 0; i < 8; ++i) {
        int idx = t + i * 256;
        A[base + idx] = buf[idx >> 7][idx & 127];
    }
}

// P5: inverse FFT over i1 (transposed read), write real out * scale
__global__ __launch_bounds__(256)
void fft_p5_k(const float2* __restrict__ A, float* __restrict__ outp)
{
    __shared__ float2 buf[16][128];
    int t = threadIdx.x;
    int ch = blockIdx.x >> 3;
    int rg = blockIdx.x & 7;
    size_t abase = (size_t)ch * HW + rg * 16;
    #pragma unroll
    for (int i = 0; i < 8; ++i) {
        int idx = t + i * 256;
        int rl = idx & 15, i1 = idx >> 4;
        buf[rl][i1] = A[abase + (size_t)i1 * 128 + rl];
    }
    fft16_inv(buf, t);
    const float scale = 1.f / 2097152.f;   // 1/(128^3)
    size_t obase = (size_t)ch * HW + rg * 2048;
    #pragma unroll
    for (int i = 0; i < 8; ++i) {
        int idx = t + i * 256;
        int rl = idx >> 7, cc = idx & 127;
        outp[obase + rl * 128 + cc] = buf[rl][cc].x * scale;
    }
}

// ---------------------------------------------------------------------------
// fusion (in-place on d_out): out = x + out_s*sigmoid(Wgfs@out_f + bgfs)
//                                  + out_f*sigmoid(Wgsf@out_s + bgsf)
// ---------------------------------------------------------------------------
__global__ __launch_bounds__(256)
void fuse_k(const float* __restrict__ x, const float* __restrict__ outs,
            const float* __restrict__ outf,
            const float* __restrict__ Wgsf, const float* __restrict__ bgsf,
            const float* __restrict__ Wgfs, const float* __restrict__ bgfs,
            float* __restrict__ out)
{
    __shared__ float ts[128][32];
    __shared__ float tf[128][32];
    int t = threadIdx.x;
    int gb = blockIdx.x;
    int b = gb >> 9;               // 512 tiles per batch
    int n0 = (gb & 511) << 5;
    size_t boff = (size_t)b * 128 * HW + n0;
    #pragma unroll
    for (int i = 0; i < 16; ++i) {
        int idx = t + i * 256;
        int c = idx >> 5, j = idx & 31;
        ts[c][j] = outs[boff + (size_t)c * HW + j];
        tf[c][j] = outf[boff + (size_t)c * HW + j];
    }
    __syncthreads();
    int j = t & 31, og = t >> 5;
    for (int o = og; o < 128; o += 8) {
        float a0 = bgsf[o], a1 = bgfs[o];
        const float* w1 = Wgsf + o * 128;
        const float* w2 = Wgfs + o * 128;
        #pragma unroll 8
        for (int c = 0; c < 128; ++c) {
            a0 += w1[c] * ts[c][j];
            a1 += w2[c] * tf[c][j];
        }
        float gf = 1.f / (1.f + expf(-a0));
        float gs = 1.f / (1.f + expf(-a1));
        size_t oidx = boff + (size_t)o * HW + j;
        out[oidx] = x[oidx] + ts[o][j] * gs + tf[o][j] * gf;
    }
}

// ---------------------------------------------------------------------------
// Workspace plan (peak 128 MiB):
//   phase A: V [0,64), vconv [64,128). Sp/S live in d_out. out_s -> d_out.
//   phase B: tmp_ff [0,64); swb [64,128); then per 2-batch chunk:
//            A [0,32), pre [32,64), out_f chunk overwrites swb chunk.
// ---------------------------------------------------------------------------
extern "C" void kernel_launch(void* const* d_in, const int* in_sizes, int n_in,
                              void* d_out, int out_size, void* d_ws, size_t ws_size,
                              hipStream_t stream)
{
    const float* x        = (const float*)d_in[0];
    const float* W_qkv    = (const float*)d_in[1];
    const float* W_dw     = (const float*)d_in[2];
    const float* W_proj_s = (const float*)d_in[3];
    const float* scale_s  = (const float*)d_in[4];
    const float* W_ff1    = (const float*)d_in[5];
    const float* W_ff2    = (const float*)d_in[6];
    const float* W_proj_f = (const float*)d_in[7];
    const float* W_gsf    = (const float*)d_in[8];
    const float* b_gsf    = (const float*)d_in[9];
    const float* W_gfs    = (const float*)d_in[10];
    const float* b_gfs    = (const float*)d_in[11];
    float* out = (float*)d_out;

    char* ws = (char*)d_ws;
    const size_t MB64 = 67108864ull;
    float* V      = (float*)(ws + 0);          // 64 MiB
    float* vconv  = (float*)(ws + MB64);       // 64 MiB
    float* Sp     = out;                        // 1 MiB   (in d_out, phase A)
    float* S      = out + 262144;               // 64 KiB  (in d_out, phase A)
    float* out_s  = out;                        // final residency in d_out
    float* tmp_ff = (float*)(ws + 0);
    float* swb    = (float*)(ws + MB64);
    float2* A     = (float2*)(ws + 0);          // 32 MiB per chunk
    float* pre    = (float*)(ws + MB64 / 2);    // 32 MiB per chunk
    float* out_fp = (float*)(ws + MB64);        // chunks overwrite swb

    // --- spatial attention branch ---
    conv1x1_k<128, 0, false><<<2048, 256, 0, stream>>>(x, nullptr, W_qkv + 256 * 128, V);
    dwconv_k<<<65536, 256, 0, stream>>>(V, W_dw, vconv);
    attn_s_fused_k<<<1024, 256, 0, stream>>>(x, W_qkv, Sp);
    attn_softmax_k<<<4, 256, 0, stream>>>(Sp, S, scale_s);
    attn_pv_k<<<4096, 256, 0, stream>>>(V, S);
    conv1x1_k<128, 0, true><<<2048, 256, 0, stream>>>(V, vconv, W_proj_s, out_s);

    // --- frequency branch ---
    conv1x1_k<128, 1, false><<<2048, 256, 0, stream>>>(x, nullptr, W_ff1, tmp_ff);
    conv1x1_k<128, 0, false><<<2048, 256, 0, stream>>>(tmp_ff, nullptr, W_ff2, swb);
    for (int chunk = 0; chunk < 4; ++chunk) {
        const float* xc  = x   + (size_t)chunk * 2 * 128 * HW;
        const float* swc = swb + (size_t)chunk * 2 * 128 * HW;
        float* ofc = out_fp + (size_t)chunk * 2 * 128 * HW;
        fft_p1_k<<<2048, 256, 0, stream>>>(xc, swc, A);
        fft_p2_k<<<2048, 256, 0, stream>>>(A);
        fft_p3_k<<<16384, 256, 0, stream>>>(A);
        fft_p4_k<<<2048, 256, 0, stream>>>(A);
        fft_p5_k<<<2048, 256, 0, stream>>>(A, pre);
        conv1x1_k<128, 0, false><<<512, 256, 0, stream>>>(pre, nullptr, W_proj_f, ofc);
    }

    // --- gated fusion (in-place on d_out) ---
    fuse_k<<<4096, 256, 0, stream>>>(x, out_s, out_fp, W_gsf, b_gsf, W_gfs, b_gfs, out);
}

// Round 3
// 1619.788 us; speedup vs baseline: 1.1558x; 1.1558x over previous
//
#include <hip/hip_runtime.h>
#include <math.h>

#define HW 16384

// ---------------------------------------------------------------------------
// conv1x1: out[b,o,n] = act( sum_c W[o,c] * (in[b,c,n] (+ in2[b,c,n])) )
// in layout: [b][128][HW]. grid = nBatches*256, block = 256.
// 8-output register blocking: 8 FMA per LDS read, scalar weight loads.
// ---------------------------------------------------------------------------
template<int O, int ACT, bool ADD2>
__global__ __launch_bounds__(256)
void conv1x1_k(const float* __restrict__ in, const float* __restrict__ in2,
               const float* __restrict__ W, float* __restrict__ out)
{
    __shared__ float tile[128][64];
    int t = threadIdx.x;
    int gb = blockIdx.x;
    int b = gb >> 8;              // 256 tiles per batch
    int n0 = (gb & 255) << 6;
    const float* inb = in + (size_t)b * 128 * HW + n0;
    const float* in2b = in2 ? (in2 + (size_t)b * 128 * HW + n0) : nullptr;
    #pragma unroll
    for (int i = 0; i < 32; ++i) {
        int idx = t + i * 256;
        int c = idx >> 6, j = idx & 63;
        float v = inb[(size_t)c * HW + j];
        if (ADD2) v += in2b[(size_t)c * HW + j];
        tile[c][j] = v;
    }
    __syncthreads();
    int j = t & 63;
    int og = __builtin_amdgcn_readfirstlane((int)(t >> 6));  // wave-uniform
    const int PER = O / 4;
    for (int k = 0; k < PER; k += 8) {
        int o0 = og * PER + k;
        const float* w0 = W + (size_t)o0 * 128;
        float acc[8] = {0.f, 0.f, 0.f, 0.f, 0.f, 0.f, 0.f, 0.f};
        #pragma unroll 4
        for (int c = 0; c < 128; ++c) {
            float v = tile[c][j];
            #pragma unroll
            for (int r = 0; r < 8; ++r) acc[r] += w0[r * 128 + c] * v;
        }
        #pragma unroll
        for (int r = 0; r < 8; ++r) {
            float v = acc[r];
            if (ACT == 1) v = 0.5f * v * (1.0f + erff(v * 0.70710678118654752f));
            out[((size_t)b * O + (o0 + r)) * HW + n0 + j] = v;
        }
    }
}

// ---------------------------------------------------------------------------
// depthwise 3x3 SAME on V buffer ([b][128][HW] layout)
// ---------------------------------------------------------------------------
__global__ __launch_bounds__(256)
void dwconv_k(const float* __restrict__ V, const float* __restrict__ Wdw,
              float* __restrict__ vconv)
{
    int tid = blockIdx.x * 256 + threadIdx.x;   // B*128*HW threads
    int e = tid & (HW - 1);
    int bc = tid >> 14;
    int c = bc & 127;
    int y = e >> 7, x = e & 127;
    const float* vin = V + (size_t)bc * HW;
    const float* wf = Wdw + c * 9;
    float acc = 0.f;
    #pragma unroll
    for (int dy = 0; dy < 3; ++dy) {
        int yy = y + dy - 1;
        if (yy < 0 || yy > 127) continue;
        #pragma unroll
        for (int dx = 0; dx < 3; ++dx) {
            int xx = x + dx - 1;
            if (xx < 0 || xx > 127) continue;
            acc += wf[dy * 3 + dx] * vin[yy * 128 + xx];
        }
    }
    vconv[(size_t)bc * HW + e] = acc;
}

// ---------------------------------------------------------------------------
// fused S partials: computes q,k tiles on the fly from x and W_qkv.
// grid = 64 (bh) x 16 (n-slices of 1024), block 256.
// ---------------------------------------------------------------------------
__global__ __launch_bounds__(256)
void attn_s_fused_k(const float* __restrict__ x, const float* __restrict__ Wqkv,
                    float* __restrict__ Sp)
{
    __shared__ float Wq[16][128];
    __shared__ float Wk[16][128];
    __shared__ float xs[128][64];
    __shared__ float qs[16][65];
    __shared__ float ks[16][65];
    int bh = blockIdx.x >> 4;
    int ns = blockIdx.x & 15;
    int b = bh >> 3, h = bh & 7;
    int t = threadIdx.x;
    #pragma unroll
    for (int i = 0; i < 8; ++i) {
        int idx = t + i * 256;       // 0..2047
        int r = idx >> 7, ci = idx & 127;
        Wq[r][ci] = Wqkv[(size_t)(h * 16 + r) * 128 + ci];
        Wk[r][ci] = Wqkv[(size_t)(128 + h * 16 + r) * 128 + ci];
    }
    const float* xb = x + (size_t)b * 128 * HW + ns * 1024;
    float Sacc = 0.f;
    int sc = t >> 4, sd = t & 15;
    for (int nc = 0; nc < 16; ++nc) {
        __syncthreads();
        #pragma unroll
        for (int i = 0; i < 32; ++i) {
            int idx = t + i * 256;
            int ci = idx >> 6, j = idx & 63;
            xs[ci][j] = xb[(size_t)ci * HW + nc * 64 + j];
        }
        __syncthreads();
        #pragma unroll
        for (int i = 0; i < 4; ++i) {
            int vi = t + i * 256;
            int c = vi >> 6, j = vi & 63;
            float aq = 0.f, ak = 0.f;
            #pragma unroll 8
            for (int ci = 0; ci < 128; ++ci) {
                float v = xs[ci][j];
                aq += Wq[c][ci] * v;
                ak += Wk[c][ci] * v;
            }
            qs[c][j] = aq;
            ks[c][j] = ak;
        }
        __syncthreads();
        #pragma unroll 16
        for (int j = 0; j < 64; ++j)
            Sacc += qs[sc][j] * ks[sd][j];
    }
    Sp[(size_t)blockIdx.x * 256 + t] = Sacc;
}

// reduce partials + scale + softmax over d. 1024 rows (bh, c), 16 wide.
__global__ void attn_softmax_k(const float* __restrict__ Sp, float* __restrict__ S,
                               const float* __restrict__ scale)
{
    int row = blockIdx.x * blockDim.x + threadIdx.x;
    if (row >= 64 * 16) return;
    int bh = row >> 4;
    int c = row & 15;
    int h = bh & 7;
    float sc = scale[h];
    float v[16];
    #pragma unroll
    for (int d = 0; d < 16; ++d) {
        float s = 0.f;
        for (int ns = 0; ns < 16; ++ns)
            s += Sp[((size_t)(bh * 16 + ns)) * 256 + c * 16 + d];
        v[d] = s * sc;
    }
    float m = v[0];
    #pragma unroll
    for (int d = 1; d < 16; ++d) m = fmaxf(m, v[d]);
    float sum = 0.f;
    #pragma unroll
    for (int d = 0; d < 16; ++d) { v[d] = expf(v[d] - m); sum += v[d]; }
    float inv = 1.f / sum;
    #pragma unroll
    for (int d = 0; d < 16; ++d) S[(size_t)bh * 256 + c * 16 + d] = v[d] * inv;
}

// PV in-place over V: out[c,n] = sum_d A[c,d] v[d,n]. grid = 64 bh x 64 n-tiles
__global__ __launch_bounds__(256)
void attn_pv_k(float* __restrict__ V, const float* __restrict__ S)
{
    __shared__ float At[256];
    __shared__ float vt[16][256];
    int bh = blockIdx.x >> 6;
    int nt = blockIdx.x & 63;
    int b = bh >> 3, h = bh & 7;
    int t = threadIdx.x;
    At[t] = S[(size_t)bh * 256 + t];
    float* vbase = V + ((size_t)(b * 128) + h * 16) * HW + nt * 256;
    #pragma unroll
    for (int i = 0; i < 16; ++i) {
        int idx = t + i * 256;
        int d = idx >> 8, jj = idx & 255;
        vt[d][jj] = vbase[(size_t)d * HW + jj];
    }
    __syncthreads();
    float vv[16];
    #pragma unroll
    for (int d = 0; d < 16; ++d) vv[d] = vt[d][t];
    #pragma unroll
    for (int c = 0; c < 16; ++c) {
        float acc = 0.f;
        #pragma unroll
        for (int d = 0; d < 16; ++d) acc += At[c * 16 + d] * vv[d];
        vbase[(size_t)c * HW + t] = acc;
    }
}

// ---------------------------------------------------------------------------
// FFT machinery: radix-2, 128-point, LDS twiddle table (128th roots).
// tw[k] = (cos(2*pi*k/128), sin(2*pi*k/128)), k = 0..63.
// forward uses (c, -s); inverse uses (c, +s).
// ---------------------------------------------------------------------------
__device__ __forceinline__ void fft_build_tw(float2* tw, int t)
{
    if (t < 64) {
        float ang = 0.049087385212340519f * (float)t;  // 2*pi/128
        float sn, cs; sincosf(ang, &sn, &cs);
        tw[t] = make_float2(cs, sn);
    }
}

__device__ __forceinline__ void fft_stage_dif(float2 (*buf)[128], const float2* tw,
                                              int t, int s)
{
    int mh = 64 >> s;
    #pragma unroll
    for (int i = 0; i < 4; ++i) {
        int idx = t + i * 256;
        int rl = idx >> 6;
        int bf = idx & 63;
        int blk = bf >> (6 - s);
        int jj = bf & (mh - 1);
        int base = (blk << (7 - s)) + jj;
        float2 a = buf[rl][base];
        float2 b = buf[rl][base + mh];
        float2 w = tw[jj << s];
        float cs = w.x, sn = -w.y;
        float dx = a.x - b.x, dy = a.y - b.y;
        buf[rl][base] = make_float2(a.x + b.x, a.y + b.y);
        buf[rl][base + mh] = make_float2(dx * cs - dy * sn, dx * sn + dy * cs);
    }
}

__device__ __forceinline__ void fft_stage_dit(float2 (*buf)[128], const float2* tw,
                                              int t, int s)
{
    int mh = 64 >> s;
    #pragma unroll
    for (int i = 0; i < 4; ++i) {
        int idx = t + i * 256;
        int rl = idx >> 6;
        int bf = idx & 63;
        int blk = bf >> (6 - s);
        int jj = bf & (mh - 1);
        int base = (blk << (7 - s)) + jj;
        float2 a = buf[rl][base];
        float2 b = buf[rl][base + mh];
        float2 w = tw[jj << s];
        float cs = w.x, sn = w.y;
        float tx = b.x * cs - b.y * sn, ty = b.x * sn + b.y * cs;
        buf[rl][base] = make_float2(a.x + tx, a.y + ty);
        buf[rl][base + mh] = make_float2(a.x - tx, a.y - ty);
    }
}

__device__ __forceinline__ void fft16_fwd(float2 (*buf)[128], const float2* tw, int t)
{
    for (int s = 0; s < 7; ++s) { __syncthreads(); fft_stage_dif(buf, tw, t, s); }
    __syncthreads();
}
__device__ __forceinline__ void fft16_inv(float2 (*buf)[128], const float2* tw, int t)
{
    for (int s = 6; s >= 0; --s) { __syncthreads(); fft_stage_dit(buf, tw, t, s); }
    __syncthreads();
}

// P1: z = x + i*sw, row FFT over w, write transposed A[ch][i1][r]
__global__ __launch_bounds__(256)
void fft_p1_k(const float* __restrict__ x, const float* __restrict__ sw,
              float2* __restrict__ A)
{
    __shared__ float2 buf[16][128];
    __shared__ float2 tw[64];
    int t = threadIdx.x;
    fft_build_tw(tw, t);
    int ch = blockIdx.x >> 3;
    int rg = blockIdx.x & 7;
    size_t base = (size_t)ch * HW + rg * 2048;
    #pragma unroll
    for (int i = 0; i < 8; ++i) {
        int idx = t + i * 256;
        int rl = idx >> 7, cc = idx & 127;
        buf[rl][cc] = make_float2(x[base + rl * 128 + cc], sw[base + rl * 128 + cc]);
    }
    fft16_fwd(buf, tw, t);
    size_t abase = (size_t)ch * HW + rg * 16;
    #pragma unroll
    for (int i = 0; i < 8; ++i) {
        int idx = t + i * 256;
        int rl = idx & 15, k1 = idx >> 4;
        A[abase + (size_t)k1 * 128 + rl] = buf[rl][k1];
    }
}

// P2: in-place forward FFT along second dim
__global__ __launch_bounds__(256)
void fft_p2_k(float2* __restrict__ A)
{
    __shared__ float2 buf[16][128];
    __shared__ float2 tw[64];
    int t = threadIdx.x;
    fft_build_tw(tw, t);
    size_t base = (size_t)(blockIdx.x) * 2048;
    #pragma unroll
    for (int i = 0; i < 8; ++i) {
        int idx = t + i * 256;
        buf[idx >> 7][idx & 127] = A[base + idx];
    }
    fft16_fwd(buf, tw, t);
    #pragma unroll
    for (int i = 0; i < 8; ++i) {
        int idx = t + i * 256;
        A[base + idx] = buf[idx >> 7][idx & 127];
    }
}

// P3: Hermitian split + product (in-place, pair-owner writes both)
__global__ __launch_bounds__(256)
void fft_p3_k(float2* __restrict__ A)
{
    int tid = blockIdx.x * 256 + threadIdx.x;
    int ch = tid >> 14;
    int e = tid & 16383;
    int i1 = e >> 7, i2 = e & 127;
    int k1 = __brev((unsigned)i1) >> 25;
    int k2 = __brev((unsigned)i2) >> 25;
    int j1 = __brev((unsigned)((128 - k1) & 127)) >> 25;
    int j2 = __brev((unsigned)((128 - k2) & 127)) >> 25;
    int ej = j1 * 128 + j2;
    if (e > ej) return;
    size_t cb = (size_t)ch * HW;
    float2 z1 = A[cb + e];
    float2 z2 = A[cb + ej];
    float2 X = make_float2(0.5f * (z1.x + z2.x), 0.5f * (z1.y - z2.y));
    float Dx = z1.x - z2.x, Dy = z1.y + z2.y;
    float2 Wf = make_float2(0.5f * Dy, -0.5f * Dx);
    float2 Y = make_float2(X.x * Wf.x - X.y * Wf.y, X.x * Wf.y + X.y * Wf.x);
    A[cb + e] = Y;
    if (ej != e) A[cb + ej] = make_float2(Y.x, -Y.y);
}

// P4: in-place inverse FFT along second dim
__global__ __launch_bounds__(256)
void fft_p4_k(float2* __restrict__ A)
{
    __shared__ float2 buf[16][128];
    __shared__ float2 tw[64];
    int t = threadIdx.x;
    fft_build_tw(tw, t);
    size_t base = (size_t)(blockIdx.x) * 2048;
    #pragma unroll
    for (int i = 0; i < 8; ++i) {
        int idx = t + i * 256;
        buf[idx >> 7][idx & 127] = A[base + idx];
    }
    fft16_inv(buf, tw, t);
    #pragma unroll
    for (int i = 0; i < 8; ++i) {
        int idx = t + i * 256;
        A[base + idx] = buf[idx >> 7][idx & 127];
    }
}

// P5: inverse FFT over i1 (transposed read), write real out * scale
__global__ __launch_bounds__(256)
void fft_p5_k(const float2* __restrict__ A, float* __restrict__ outp)
{
    __shared__ float2 buf[16][128];
    __shared__ float2 tw[64];
    int t = threadIdx.x;
    fft_build_tw(tw, t);
    int ch = blockIdx.x >> 3;
    int rg = blockIdx.x & 7;
    size_t abase = (size_t)ch * HW + rg * 16;
    #pragma unroll
    for (int i = 0; i < 8; ++i) {
        int idx = t + i * 256;
        int rl = idx & 15, i1 = idx >> 4;
        buf[rl][i1] = A[abase + (size_t)i1 * 128 + rl];
    }
    fft16_inv(buf, tw, t);
    const float scale = 1.f / 2097152.f;   // 1/(128^3)
    size_t obase = (size_t)ch * HW + rg * 2048;
    #pragma unroll
    for (int i = 0; i < 8; ++i) {
        int idx = t + i * 256;
        int rl = idx >> 7, cc = idx & 127;
        outp[obase + rl * 128 + cc] = buf[rl][cc].x * scale;
    }
}

// ---------------------------------------------------------------------------
// fusion (in-place on d_out), conv1x1-style:
// out = x + out_s*sigmoid(Wgfs@out_f + bgfs) + out_f*sigmoid(Wgsf@out_s + bgsf)
// grid = B*HW/64 = 2048, block 256, LDS 2 x [128][64] = 64KB.
// ---------------------------------------------------------------------------
__global__ __launch_bounds__(256)
void fuse_k(const float* __restrict__ x, const float* __restrict__ outs,
            const float* __restrict__ outf,
            const float* __restrict__ Wgsf, const float* __restrict__ bgsf,
            const float* __restrict__ Wgfs, const float* __restrict__ bgfs,
            float* __restrict__ out)
{
    __shared__ float ts[128][64];
    __shared__ float tf[128][64];
    int t = threadIdx.x;
    int gb = blockIdx.x;
    int b = gb >> 8;               // 256 tiles per batch
    int n0 = (gb & 255) << 6;
    size_t boff = (size_t)b * 128 * HW + n0;
    #pragma unroll
    for (int i = 0; i < 32; ++i) {
        int idx = t + i * 256;
        int c = idx >> 6, j = idx & 63;
        ts[c][j] = outs[boff + (size_t)c * HW + j];
        tf[c][j] = outf[boff + (size_t)c * HW + j];
    }
    __syncthreads();
    int j = t & 63;
    int og = __builtin_amdgcn_readfirstlane((int)(t >> 6));  // wave-uniform
    for (int k = 0; k < 32; k += 4) {
        int o0 = og * 32 + k;
        const float* w1 = Wgsf + (size_t)o0 * 128;
        const float* w2 = Wgfs + (size_t)o0 * 128;
        float a0[4], a1[4];
        #pragma unroll
        for (int r = 0; r < 4; ++r) { a0[r] = bgsf[o0 + r]; a1[r] = bgfs[o0 + r]; }
        #pragma unroll 4
        for (int c = 0; c < 128; ++c) {
            float vs = ts[c][j];
            float vf = tf[c][j];
            #pragma unroll
            for (int r = 0; r < 4; ++r) {
                a0[r] += w1[r * 128 + c] * vs;
                a1[r] += w2[r * 128 + c] * vf;
            }
        }
        #pragma unroll
        for (int r = 0; r < 4; ++r) {
            int o = o0 + r;
            float gf = 1.f / (1.f + expf(-a0[r]));   // gates out_f
            float gs = 1.f / (1.f + expf(-a1[r]));   // gates out_s
            size_t oidx = boff + (size_t)o * HW + j;
            out[oidx] = x[oidx] + ts[o][j] * gs + tf[o][j] * gf;
        }
    }
}

// ---------------------------------------------------------------------------
// Workspace plan (peak 128 MiB):
//   phase A: V [0,64), vconv [64,128). Sp/S live in d_out. out_s -> d_out.
//   phase B: tmp_ff [0,64); swb [64,128); then per 2-batch chunk:
//            A [0,32), pre [32,64), out_f chunk overwrites swb chunk.
// ---------------------------------------------------------------------------
extern "C" void kernel_launch(void* const* d_in, const int* in_sizes, int n_in,
                              void* d_out, int out_size, void* d_ws, size_t ws_size,
                              hipStream_t stream)
{
    const float* x        = (const float*)d_in[0];
    const float* W_qkv    = (const float*)d_in[1];
    const float* W_dw     = (const float*)d_in[2];
    const float* W_proj_s = (const float*)d_in[3];
    const float* scale_s  = (const float*)d_in[4];
    const float* W_ff1    = (const float*)d_in[5];
    const float* W_ff2    = (const float*)d_in[6];
    const float* W_proj_f = (const float*)d_in[7];
    const float* W_gsf    = (const float*)d_in[8];
    const float* b_gsf    = (const float*)d_in[9];
    const float* W_gfs    = (const float*)d_in[10];
    const float* b_gfs    = (const float*)d_in[11];
    float* out = (float*)d_out;

    char* ws = (char*)d_ws;
    const size_t MB64 = 67108864ull;
    float* V      = (float*)(ws + 0);          // 64 MiB
    float* vconv  = (float*)(ws + MB64);       // 64 MiB
    float* Sp     = out;                        // 1 MiB   (in d_out, phase A)
    float* S      = out + 262144;               // 64 KiB  (in d_out, phase A)
    float* out_s  = out;                        // final residency in d_out
    float* tmp_ff = (float*)(ws + 0);
    float* swb    = (float*)(ws + MB64);
    float2* A     = (float2*)(ws + 0);          // 32 MiB per chunk
    float* pre    = (float*)(ws + MB64 / 2);    // 32 MiB per chunk
    float* out_fp = (float*)(ws + MB64);        // chunks overwrite swb

    // --- spatial attention branch ---
    conv1x1_k<128, 0, false><<<2048, 256, 0, stream>>>(x, nullptr, W_qkv + 256 * 128, V);
    dwconv_k<<<65536, 256, 0, stream>>>(V, W_dw, vconv);
    attn_s_fused_k<<<1024, 256, 0, stream>>>(x, W_qkv, Sp);
    attn_softmax_k<<<4, 256, 0, stream>>>(Sp, S, scale_s);
    attn_pv_k<<<4096, 256, 0, stream>>>(V, S);
    conv1x1_k<128, 0, true><<<2048, 256, 0, stream>>>(V, vconv, W_proj_s, out_s);

    // --- frequency branch ---
    conv1x1_k<128, 1, false><<<2048, 256, 0, stream>>>(x, nullptr, W_ff1, tmp_ff);
    conv1x1_k<128, 0, false><<<2048, 256, 0, stream>>>(tmp_ff, nullptr, W_ff2, swb);
    for (int chunk = 0; chunk < 4; ++chunk) {
        const float* xc  = x   + (size_t)chunk * 2 * 128 * HW;
        const float* swc = swb + (size_t)chunk * 2 * 128 * HW;
        float* ofc = out_fp + (size_t)chunk * 2 * 128 * HW;
        fft_p1_k<<<2048, 256, 0, stream>>>(xc, swc, A);
        fft_p2_k<<<2048, 256, 0, stream>>>(A);
        fft_p3_k<<<16384, 256, 0, stream>>>(A);
        fft_p4_k<<<2048, 256, 0, stream>>>(A);
        fft_p5_k<<<2048, 256, 0, stream>>>(A, pre);
        conv1x1_k<128, 0, false><<<512, 256, 0, stream>>>(pre, nullptr, W_proj_f, ofc);
    }

    // --- gated fusion (in-place on d_out) ---
    fuse_k<<<2048, 256, 0, stream>>>(x, out_s, out_fp, W_gsf, b_gsf, W_gfs, b_gfs, out);
}

// Round 4
// 1418.252 us; speedup vs baseline: 1.3200x; 1.1421x over previous
//
#include <hip/hip_runtime.h>
#include <math.h>

#define HW 16384

// ---------------------------------------------------------------------------
// conv1x1: out[b,o,n] = act( sum_c W[o,c] * (in[b,c,n] (+ in2[b,c,n])) )
// in layout: [b][128][HW]. grid = nBatches*256, block = 256.
// 8-output register blocking: 8 FMA per LDS read, scalar weight loads.
// ---------------------------------------------------------------------------
template<int O, int ACT, bool ADD2>
__global__ __launch_bounds__(256)
void conv1x1_k(const float* __restrict__ in, const float* __restrict__ in2,
               const float* __restrict__ W, float* __restrict__ out)
{
    __shared__ float tile[128][64];
    int t = threadIdx.x;
    int gb = blockIdx.x;
    int b = gb >> 8;              // 256 tiles per batch
    int n0 = (gb & 255) << 6;
    const float* inb = in + (size_t)b * 128 * HW + n0;
    const float* in2b = in2 ? (in2 + (size_t)b * 128 * HW + n0) : nullptr;
    #pragma unroll
    for (int i = 0; i < 32; ++i) {
        int idx = t + i * 256;
        int c = idx >> 6, j = idx & 63;
        float v = inb[(size_t)c * HW + j];
        if (ADD2) v += in2b[(size_t)c * HW + j];
        tile[c][j] = v;
    }
    __syncthreads();
    int j = t & 63;
    int og = __builtin_amdgcn_readfirstlane((int)(t >> 6));  // wave-uniform
    const int PER = O / 4;
    for (int k = 0; k < PER; k += 8) {
        int o0 = og * PER + k;
        const float* w0 = W + (size_t)o0 * 128;
        float acc[8] = {0.f, 0.f, 0.f, 0.f, 0.f, 0.f, 0.f, 0.f};
        #pragma unroll 4
        for (int c = 0; c < 128; ++c) {
            float v = tile[c][j];
            #pragma unroll
            for (int r = 0; r < 8; ++r) acc[r] += w0[r * 128 + c] * v;
        }
        #pragma unroll
        for (int r = 0; r < 8; ++r) {
            float v = acc[r];
            if (ACT == 1) v = 0.5f * v * (1.0f + erff(v * 0.70710678118654752f));
            out[((size_t)b * O + (o0 + r)) * HW + n0 + j] = v;
        }
    }
}

// ---------------------------------------------------------------------------
// depthwise 3x3 SAME on V buffer ([b][128][HW] layout)
// ---------------------------------------------------------------------------
__global__ __launch_bounds__(256)
void dwconv_k(const float* __restrict__ V, const float* __restrict__ Wdw,
              float* __restrict__ vconv)
{
    int tid = blockIdx.x * 256 + threadIdx.x;   // B*128*HW threads
    int e = tid & (HW - 1);
    int bc = tid >> 14;
    int c = bc & 127;
    int y = e >> 7, x = e & 127;
    const float* vin = V + (size_t)bc * HW;
    const float* wf = Wdw + c * 9;
    float acc = 0.f;
    #pragma unroll
    for (int dy = 0; dy < 3; ++dy) {
        int yy = y + dy - 1;
        if (yy < 0 || yy > 127) continue;
        #pragma unroll
        for (int dx = 0; dx < 3; ++dx) {
            int xx = x + dx - 1;
            if (xx < 0 || xx > 127) continue;
            acc += wf[dy * 3 + dx] * vin[yy * 128 + xx];
        }
    }
    vconv[(size_t)bc * HW + e] = acc;
}

// ---------------------------------------------------------------------------
// Gram matrix partials: G[b] = X_b X_b^T over 16384 px, split-K.
// blk = b*64 + tp*16 + ks ; tp = (ti,tj) 64x64 tile; ks = K-slice of 1024 px.
// Gp[blk][64][64] partial sums. grid = 512, block = 256 (4x4 reg tile).
// ---------------------------------------------------------------------------
__global__ __launch_bounds__(256)
void gram_k(const float* __restrict__ x, float* __restrict__ Gp)
{
    __shared__ float Xi[64][65];
    __shared__ float Xj[64][65];
    int blk = blockIdx.x;
    int b = blk >> 6;
    int tp = (blk >> 4) & 3;
    int ks = blk & 15;
    int ti = tp >> 1, tj = tp & 1;
    int t = threadIdx.x;
    const float* xb = x + (size_t)b * 128 * HW + ks * 1024;
    const float* xi = xb + (size_t)(ti * 64) * HW;
    const float* xj = xb + (size_t)(tj * 64) * HW;
    int ty = t >> 4, tx = t & 15;
    float acc[4][4] = {};
    for (int kc = 0; kc < 16; ++kc) {
        __syncthreads();
        #pragma unroll
        for (int i = 0; i < 16; ++i) {
            int idx = t + i * 256;
            int ci = idx >> 6, jcol = idx & 63;
            Xi[ci][jcol] = xi[(size_t)ci * HW + kc * 64 + jcol];
            Xj[ci][jcol] = xj[(size_t)ci * HW + kc * 64 + jcol];
        }
        __syncthreads();
        #pragma unroll 8
        for (int k = 0; k < 64; ++k) {
            float a[4], bb[4];
            #pragma unroll
            for (int r = 0; r < 4; ++r) a[r] = Xi[ty * 4 + r][k];
            #pragma unroll
            for (int c = 0; c < 4; ++c) bb[c] = Xj[tx * 4 + c][k];
            #pragma unroll
            for (int r = 0; r < 4; ++r)
                #pragma unroll
                for (int c = 0; c < 4; ++c)
                    acc[r][c] += a[r] * bb[c];
        }
    }
    float* gp = Gp + (size_t)blk * 4096;
    #pragma unroll
    for (int r = 0; r < 4; ++r)
        #pragma unroll
        for (int c = 0; c < 4; ++c)
            gp[(ty * 4 + r) * 64 + tx * 4 + c] = acc[r][c];
}

// G[b][i][j] = sum_ks Gp[b*64 + tp*16 + ks][i&63][j&63]
__global__ void gram_reduce_k(const float* __restrict__ Gp, float* __restrict__ G)
{
    int idx = blockIdx.x * 256 + threadIdx.x;   // 8*128*128
    int b = idx >> 14;
    int ij = idx & 16383;
    int i = ij >> 7, j = ij & 127;
    int tp = ((i >> 6) << 1) | (j >> 6);
    int row = i & 63, col = j & 63;
    const float* gp = Gp + ((size_t)(b * 64 + tp * 16)) * 4096 + row * 64 + col;
    float s = 0.f;
    #pragma unroll
    for (int ks = 0; ks < 16; ++ks) s += gp[(size_t)ks * 4096];
    G[idx] = s;
}

// ---------------------------------------------------------------------------
// S_h = softmax( (Wq_h G Wk_h^T) * scale[h] ) — one block per (b,h).
// ---------------------------------------------------------------------------
__global__ __launch_bounds__(256)
void attn_s2_k(const float* __restrict__ G, const float* __restrict__ Wqkv,
               const float* __restrict__ scale, float* __restrict__ S)
{
    __shared__ float Wq[16][129];
    __shared__ float Wk[16][129];
    __shared__ float Ts[16][129];
    int bh = blockIdx.x;
    int b = bh >> 3, h = bh & 7;
    int t = threadIdx.x;
    #pragma unroll
    for (int i = 0; i < 8; ++i) {
        int idx = t + i * 256;
        int r = idx >> 7, ci = idx & 127;
        Wq[r][ci] = Wqkv[(size_t)(h * 16 + r) * 128 + ci];
        Wk[r][ci] = Wqkv[(size_t)(128 + h * 16 + r) * 128 + ci];
    }
    __syncthreads();
    const float* Gb = G + (size_t)b * 16384;
    // T = Wq @ G  (16 x 128)
    #pragma unroll
    for (int i = 0; i < 8; ++i) {
        int idx = t + i * 256;
        int c = idx >> 7, col = idx & 127;
        float s = 0.f;
        #pragma unroll 8
        for (int ci = 0; ci < 128; ++ci)
            s += Wq[c][ci] * Gb[ci * 128 + col];
        Ts[c][col] = s;
    }
    __syncthreads();
    // S[c][d] = sum_col Ts[c][col] * Wk[d][col]; scaled softmax over d
    int c = t >> 4, d = t & 15;
    float s = 0.f;
    #pragma unroll 8
    for (int col = 0; col < 128; ++col)
        s += Ts[c][col] * Wk[d][col];
    s *= scale[h];
    float m = s;
    #pragma unroll
    for (int w = 1; w < 16; w <<= 1)
        m = fmaxf(m, __shfl_xor(m, w, 64));
    float e = expf(s - m);
    float sum = e;
    #pragma unroll
    for (int w = 1; w < 16; w <<= 1)
        sum += __shfl_xor(sum, w, 64);
    S[(size_t)bh * 256 + t] = e / sum;
}

// PV in-place over V: out[c,n] = sum_d A[c,d] v[d,n]. grid = 64 bh x 64 n-tiles
__global__ __launch_bounds__(256)
void attn_pv_k(float* __restrict__ V, const float* __restrict__ S)
{
    __shared__ float At[256];
    __shared__ float vt[16][256];
    int bh = blockIdx.x >> 6;
    int nt = blockIdx.x & 63;
    int b = bh >> 3, h = bh & 7;
    int t = threadIdx.x;
    At[t] = S[(size_t)bh * 256 + t];
    float* vbase = V + ((size_t)(b * 128) + h * 16) * HW + nt * 256;
    #pragma unroll
    for (int i = 0; i < 16; ++i) {
        int idx = t + i * 256;
        int d = idx >> 8, jj = idx & 255;
        vt[d][jj] = vbase[(size_t)d * HW + jj];
    }
    __syncthreads();
    float vv[16];
    #pragma unroll
    for (int d = 0; d < 16; ++d) vv[d] = vt[d][t];
    #pragma unroll
    for (int c = 0; c < 16; ++c) {
        float acc = 0.f;
        #pragma unroll
        for (int d = 0; d < 16; ++d) acc += At[c * 16 + d] * vv[d];
        vbase[(size_t)c * HW + t] = acc;
    }
}

// ---------------------------------------------------------------------------
// FFT machinery: radix-2, 128-point, LDS twiddle table (128th roots).
// ---------------------------------------------------------------------------
__device__ __forceinline__ void fft_build_tw(float2* tw, int t)
{
    if (t < 64) {
        float ang = 0.049087385212340519f * (float)t;  // 2*pi/128
        float sn, cs; sincosf(ang, &sn, &cs);
        tw[t] = make_float2(cs, sn);
    }
}

__device__ __forceinline__ void fft_stage_dif(float2 (*buf)[128], const float2* tw,
                                              int t, int s)
{
    int mh = 64 >> s;
    #pragma unroll
    for (int i = 0; i < 4; ++i) {
        int idx = t + i * 256;
        int rl = idx >> 6;
        int bf = idx & 63;
        int blk = bf >> (6 - s);
        int jj = bf & (mh - 1);
        int base = (blk << (7 - s)) + jj;
        float2 a = buf[rl][base];
        float2 b = buf[rl][base + mh];
        float2 w = tw[jj << s];
        float cs = w.x, sn = -w.y;
        float dx = a.x - b.x, dy = a.y - b.y;
        buf[rl][base] = make_float2(a.x + b.x, a.y + b.y);
        buf[rl][base + mh] = make_float2(dx * cs - dy * sn, dx * sn + dy * cs);
    }
}

__device__ __forceinline__ void fft_stage_dit(float2 (*buf)[128], const float2* tw,
                                              int t, int s)
{
    int mh = 64 >> s;
    #pragma unroll
    for (int i = 0; i < 4; ++i) {
        int idx = t + i * 256;
        int rl = idx >> 6;
        int bf = idx & 63;
        int blk = bf >> (6 - s);
        int jj = bf & (mh - 1);
        int base = (blk << (7 - s)) + jj;
        float2 a = buf[rl][base];
        float2 b = buf[rl][base + mh];
        float2 w = tw[jj << s];
        float cs = w.x, sn = w.y;
        float tx = b.x * cs - b.y * sn, ty = b.x * sn + b.y * cs;
        buf[rl][base] = make_float2(a.x + tx, a.y + ty);
        buf[rl][base + mh] = make_float2(a.x - tx, a.y - ty);
    }
}

__device__ __forceinline__ void fft16_fwd(float2 (*buf)[128], const float2* tw, int t)
{
    for (int s = 0; s < 7; ++s) { __syncthreads(); fft_stage_dif(buf, tw, t, s); }
    __syncthreads();
}
__device__ __forceinline__ void fft16_inv(float2 (*buf)[128], const float2* tw, int t)
{
    for (int s = 6; s >= 0; --s) { __syncthreads(); fft_stage_dit(buf, tw, t, s); }
    __syncthreads();
}

// P1: z = x + i*sw, row FFT over w, write transposed A[ch][i1][r]
__global__ __launch_bounds__(256)
void fft_p1_k(const float* __restrict__ x, const float* __restrict__ sw,
              float2* __restrict__ A)
{
    __shared__ float2 buf[16][128];
    __shared__ float2 tw[64];
    int t = threadIdx.x;
    fft_build_tw(tw, t);
    int ch = blockIdx.x >> 3;
    int rg = blockIdx.x & 7;
    size_t base = (size_t)ch * HW + rg * 2048;
    #pragma unroll
    for (int i = 0; i < 8; ++i) {
        int idx = t + i * 256;
        int rl = idx >> 7, cc = idx & 127;
        buf[rl][cc] = make_float2(x[base + rl * 128 + cc], sw[base + rl * 128 + cc]);
    }
    fft16_fwd(buf, tw, t);
    size_t abase = (size_t)ch * HW + rg * 16;
    #pragma unroll
    for (int i = 0; i < 8; ++i) {
        int idx = t + i * 256;
        int rl = idx & 15, k1 = idx >> 4;
        A[abase + (size_t)k1 * 128 + rl] = buf[rl][k1];
    }
}

// P2: in-place forward FFT along second dim
__global__ __launch_bounds__(256)
void fft_p2_k(float2* __restrict__ A)
{
    __shared__ float2 buf[16][128];
    __shared__ float2 tw[64];
    int t = threadIdx.x;
    fft_build_tw(tw, t);
    size_t base = (size_t)(blockIdx.x) * 2048;
    #pragma unroll
    for (int i = 0; i < 8; ++i) {
        int idx = t + i * 256;
        buf[idx >> 7][idx & 127] = A[base + idx];
    }
    fft16_fwd(buf, tw, t);
    #pragma unroll
    for (int i = 0; i < 8; ++i) {
        int idx = t + i * 256;
        A[base + idx] = buf[idx >> 7][idx & 127];
    }
}

// P3: Hermitian split + product (in-place, pair-owner writes both)
__global__ __launch_bounds__(256)
void fft_p3_k(float2* __restrict__ A)
{
    int tid = blockIdx.x * 256 + threadIdx.x;
    int ch = tid >> 14;
    int e = tid & 16383;
    int i1 = e >> 7, i2 = e & 127;
    int k1 = __brev((unsigned)i1) >> 25;
    int k2 = __brev((unsigned)i2) >> 25;
    int j1 = __brev((unsigned)((128 - k1) & 127)) >> 25;
    int j2 = __brev((unsigned)((128 - k2) & 127)) >> 25;
    int ej = j1 * 128 + j2;
    if (e > ej) return;
    size_t cb = (size_t)ch * HW;
    float2 z1 = A[cb + e];
    float2 z2 = A[cb + ej];
    float2 X = make_float2(0.5f * (z1.x + z2.x), 0.5f * (z1.y - z2.y));
    float Dx = z1.x - z2.x, Dy = z1.y + z2.y;
    float2 Wf = make_float2(0.5f * Dy, -0.5f * Dx);
    float2 Y = make_float2(X.x * Wf.x - X.y * Wf.y, X.x * Wf.y + X.y * Wf.x);
    A[cb + e] = Y;
    if (ej != e) A[cb + ej] = make_float2(Y.x, -Y.y);
}

// P4: in-place inverse FFT along second dim
__global__ __launch_bounds__(256)
void fft_p4_k(float2* __restrict__ A)
{
    __shared__ float2 buf[16][128];
    __shared__ float2 tw[64];
    int t = threadIdx.x;
    fft_build_tw(tw, t);
    size_t base = (size_t)(blockIdx.x) * 2048;
    #pragma unroll
    for (int i = 0; i < 8; ++i) {
        int idx = t + i * 256;
        buf[idx >> 7][idx & 127] = A[base + idx];
    }
    fft16_inv(buf, tw, t);
    #pragma unroll
    for (int i = 0; i < 8; ++i) {
        int idx = t + i * 256;
        A[base + idx] = buf[idx >> 7][idx & 127];
    }
}

// P5: inverse FFT over i1 (transposed read), write real out * scale
__global__ __launch_bounds__(256)
void fft_p5_k(const float2* __restrict__ A, float* __restrict__ outp)
{
    __shared__ float2 buf[16][128];
    __shared__ float2 tw[64];
    int t = threadIdx.x;
    fft_build_tw(tw, t);
    int ch = blockIdx.x >> 3;
    int rg = blockIdx.x & 7;
    size_t abase = (size_t)ch * HW + rg * 16;
    #pragma unroll
    for (int i = 0; i < 8; ++i) {
        int idx = t + i * 256;
        int rl = idx & 15, i1 = idx >> 4;
        buf[rl][i1] = A[abase + (size_t)i1 * 128 + rl];
    }
    fft16_inv(buf, tw, t);
    const float scale = 1.f / 2097152.f;   // 1/(128^3)
    size_t obase = (size_t)ch * HW + rg * 2048;
    #pragma unroll
    for (int i = 0; i < 8; ++i) {
        int idx = t + i * 256;
        int rl = idx >> 7, cc = idx & 127;
        outp[obase + rl * 128 + cc] = buf[rl][cc].x * scale;
    }
}

// ---------------------------------------------------------------------------
// fusion (in-place on d_out), conv1x1-style
// ---------------------------------------------------------------------------
__global__ __launch_bounds__(256)
void fuse_k(const float* __restrict__ x, const float* __restrict__ outs,
            const float* __restrict__ outf,
            const float* __restrict__ Wgsf, const float* __restrict__ bgsf,
            const float* __restrict__ Wgfs, const float* __restrict__ bgfs,
            float* __restrict__ out)
{
    __shared__ float ts[128][64];
    __shared__ float tf[128][64];
    int t = threadIdx.x;
    int gb = blockIdx.x;
    int b = gb >> 8;               // 256 tiles per batch
    int n0 = (gb & 255) << 6;
    size_t boff = (size_t)b * 128 * HW + n0;
    #pragma unroll
    for (int i = 0; i < 32; ++i) {
        int idx = t + i * 256;
        int c = idx >> 6, j = idx & 63;
        ts[c][j] = outs[boff + (size_t)c * HW + j];
        tf[c][j] = outf[boff + (size_t)c * HW + j];
    }
    __syncthreads();
    int j = t & 63;
    int og = __builtin_amdgcn_readfirstlane((int)(t >> 6));  // wave-uniform
    for (int k = 0; k < 32; k += 4) {
        int o0 = og * 32 + k;
        const float* w1 = Wgsf + (size_t)o0 * 128;
        const float* w2 = Wgfs + (size_t)o0 * 128;
        float a0[4], a1[4];
        #pragma unroll
        for (int r = 0; r < 4; ++r) { a0[r] = bgsf[o0 + r]; a1[r] = bgfs[o0 + r]; }
        #pragma unroll 4
        for (int c = 0; c < 128; ++c) {
            float vs = ts[c][j];
            float vf = tf[c][j];
            #pragma unroll
            for (int r = 0; r < 4; ++r) {
                a0[r] += w1[r * 128 + c] * vs;
                a1[r] += w2[r * 128 + c] * vf;
            }
        }
        #pragma unroll
        for (int r = 0; r < 4; ++r) {
            int o = o0 + r;
            float gf = 1.f / (1.f + expf(-a0[r]));   // gates out_f
            float gs = 1.f / (1.f + expf(-a1[r]));   // gates out_s
            size_t oidx = boff + (size_t)o * HW + j;
            out[oidx] = x[oidx] + ts[o][j] * gs + tf[o][j] * gf;
        }
    }
}

// ---------------------------------------------------------------------------
// Workspace plan (peak 128 MiB ws + d_out scratch):
//   phase A: V ws[0,64), vconv ws[64,128). Gp/G/S live in d_out (dead until
//            proj_s writes out_s there).
//   phase B: tmp_ff ws[0,64); swb ws[64,128); per 2-batch chunk:
//            A ws[0,32), pre ws[32,64), out_f chunk overwrites swb chunk.
// ---------------------------------------------------------------------------
extern "C" void kernel_launch(void* const* d_in, const int* in_sizes, int n_in,
                              void* d_out, int out_size, void* d_ws, size_t ws_size,
                              hipStream_t stream)
{
    const float* x        = (const float*)d_in[0];
    const float* W_qkv    = (const float*)d_in[1];
    const float* W_dw     = (const float*)d_in[2];
    const float* W_proj_s = (const float*)d_in[3];
    const float* scale_s  = (const float*)d_in[4];
    const float* W_ff1    = (const float*)d_in[5];
    const float* W_ff2    = (const float*)d_in[6];
    const float* W_proj_f = (const float*)d_in[7];
    const float* W_gsf    = (const float*)d_in[8];
    const float* b_gsf    = (const float*)d_in[9];
    const float* W_gfs    = (const float*)d_in[10];
    const float* b_gfs    = (const float*)d_in[11];
    float* out = (float*)d_out;

    char* ws = (char*)d_ws;
    const size_t MB64 = 67108864ull;
    float* V      = (float*)(ws + 0);          // 64 MiB
    float* vconv  = (float*)(ws + MB64);       // 64 MiB
    float* Gp     = out;                        // 8 MiB   (in d_out, phase A)
    float* G      = out + 2097152;              // 512 KiB (in d_out, phase A)
    float* S      = out + 2097152 + 131072;     // 64 KiB  (in d_out, phase A)
    float* out_s  = out;                        // final residency in d_out
    float* tmp_ff = (float*)(ws + 0);
    float* swb    = (float*)(ws + MB64);
    float2* A     = (float2*)(ws + 0);          // 32 MiB per chunk
    float* pre    = (float*)(ws + MB64 / 2);    // 32 MiB per chunk
    float* out_fp = (float*)(ws + MB64);        // chunks overwrite swb

    // --- spatial attention branch ---
    conv1x1_k<128, 0, false><<<2048, 256, 0, stream>>>(x, nullptr, W_qkv + 256 * 128, V);
    dwconv_k<<<65536, 256, 0, stream>>>(V, W_dw, vconv);
    gram_k<<<512, 256, 0, stream>>>(x, Gp);
    gram_reduce_k<<<512, 256, 0, stream>>>(Gp, G);
    attn_s2_k<<<64, 256, 0, stream>>>(G, W_qkv, scale_s, S);
    attn_pv_k<<<4096, 256, 0, stream>>>(V, S);
    conv1x1_k<128, 0, true><<<2048, 256, 0, stream>>>(V, vconv, W_proj_s, out_s);

    // --- frequency branch ---
    conv1x1_k<128, 1, false><<<2048, 256, 0, stream>>>(x, nullptr, W_ff1, tmp_ff);
    conv1x1_k<128, 0, false><<<2048, 256, 0, stream>>>(tmp_ff, nullptr, W_ff2, swb);
    for (int chunk = 0; chunk < 4; ++chunk) {
        const float* xc  = x   + (size_t)chunk * 2 * 128 * HW;
        const float* swc = swb + (size_t)chunk * 2 * 128 * HW;
        float* ofc = out_fp + (size_t)chunk * 2 * 128 * HW;
        fft_p1_k<<<2048, 256, 0, stream>>>(xc, swc, A);
        fft_p2_k<<<2048, 256, 0, stream>>>(A);
        fft_p3_k<<<16384, 256, 0, stream>>>(A);
        fft_p4_k<<<2048, 256, 0, stream>>>(A);
        fft_p5_k<<<2048, 256, 0, stream>>>(A, pre);
        conv1x1_k<128, 0, false><<<512, 256, 0, stream>>>(pre, nullptr, W_proj_f, ofc);
    }

    // --- gated fusion (in-place on d_out) ---
    fuse_k<<<2048, 256, 0, stream>>>(x, out_s, out_fp, W_gsf, b_gsf, W_gfs, b_gfs, out);
}

// Round 5
// 823.014 us; speedup vs baseline: 2.2747x; 1.7232x over previous
//
#include <hip/hip_runtime.h>
#include <math.h>

#define HW 16384

typedef __attribute__((ext_vector_type(8))) short bf16x8;
typedef __attribute__((ext_vector_type(4))) float f32x4;

__device__ __forceinline__ unsigned f2bf_pk(float a, float b)
{
    unsigned ua = __float_as_uint(a), ub = __float_as_uint(b);
    ua = (ua + 0x7FFFu + ((ua >> 16) & 1u)) >> 16;   // RTN-even
    ub = (ub + 0x7FFFu + ((ub >> 16) & 1u)) >> 16;
    return (ua & 0xFFFFu) | (ub << 16);
}

// ---------------------------------------------------------------------------
// MFMA conv1x1: out[b,o,n] = epilogue( sum_c W[o,c] * (in[b,c,n](+in2)) )
// Tile: O=128 x N=64, K=128 one-shot. 256 thr = 4 waves; wave w owns rows
// [w*32,w*32+32). LDS: W bf16 [128][128] + X^T bf16 [64][128], both stored in
// 16B chunks with chunk ^= (row&7) swizzle (write & read same XOR).
// ACT: 0 none, 1 GELU, 2 sigmoid(v+bias) (gate), 3 final fuse epilogue.
// ---------------------------------------------------------------------------
template<int ACT, bool ADD2>
__global__ __launch_bounds__(256)
void conv_mfma_k(const float* __restrict__ in, const float* __restrict__ in2,
                 const float* __restrict__ Wsrc, const float* __restrict__ bias,
                 const float* __restrict__ xres, const float* outs_e,
                 const float* __restrict__ gf, float* out)
{
    __shared__ short WL[128 * 128];   // 32 KB
    __shared__ short XL[64 * 128];    // 16 KB
    int t = threadIdx.x;
    int gb = blockIdx.x;
    int b = gb >> 8;                  // 256 n-tiles per batch
    int n0 = (gb & 255) << 6;

    // ---- stage W (fp32 global -> bf16 LDS, swizzled) ----
    #pragma unroll
    for (int it = 0; it < 8; ++it) {
        int g = it * 256 + t;         // chunk id 0..2047
        int o = g >> 4, c16 = g & 15;
        const float* wp = Wsrc + o * 128 + c16 * 8;
        int4 p;
        p.x = f2bf_pk(wp[0], wp[1]);
        p.y = f2bf_pk(wp[2], wp[3]);
        p.z = f2bf_pk(wp[4], wp[5]);
        p.w = f2bf_pk(wp[6], wp[7]);
        ((int4*)WL)[o * 16 + (c16 ^ (o & 7))] = p;
    }
    // ---- stage X^T (register transpose: k-octet per lane, coalesced) ----
    const float* inb = in + (size_t)b * 128 * HW + n0;
    const float* in2b = ADD2 ? (in2 + (size_t)b * 128 * HW + n0) : nullptr;
    int nl = t & 63;
    #pragma unroll
    for (int it = 0; it < 4; ++it) {
        int c8 = (t >> 6) + it * 4;   // k-octet 0..15
        float v[8];
        #pragma unroll
        for (int j = 0; j < 8; ++j) {
            size_t a = (size_t)(c8 * 8 + j) * HW + nl;
            v[j] = inb[a];
            if (ADD2) v[j] += in2b[a];
        }
        int4 p;
        p.x = f2bf_pk(v[0], v[1]);
        p.y = f2bf_pk(v[2], v[3]);
        p.z = f2bf_pk(v[4], v[5]);
        p.w = f2bf_pk(v[6], v[7]);
        ((int4*)XL)[nl * 16 + (c8 ^ (nl & 7))] = p;
    }
    __syncthreads();

    // ---- MFMA main: 2 M-frags x 4 N-frags x 4 K-steps ----
    int l = t & 63, w = t >> 6, kg = l >> 4, l15 = l & 15, l7 = l15 & 7;
    f32x4 acc[2][4];
    #pragma unroll
    for (int mf = 0; mf < 2; ++mf)
        #pragma unroll
        for (int nf = 0; nf < 4; ++nf)
            acc[mf][nf] = (f32x4){0.f, 0.f, 0.f, 0.f};
    #pragma unroll
    for (int ks = 0; ks < 4; ++ks) {
        int ch = ks * 4 + kg;
        bf16x8 A0 = ((const bf16x8*)WL)[(w * 32 + l15) * 16 + (ch ^ l7)];
        bf16x8 A1 = ((const bf16x8*)WL)[(w * 32 + 16 + l15) * 16 + (ch ^ l7)];
        #pragma unroll
        for (int nf = 0; nf < 4; ++nf) {
            bf16x8 Bf = ((const bf16x8*)XL)[(nf * 16 + l15) * 16 + (ch ^ l7)];
            acc[0][nf] = __builtin_amdgcn_mfma_f32_16x16x32_bf16(A0, Bf, acc[0][nf], 0, 0, 0);
            acc[1][nf] = __builtin_amdgcn_mfma_f32_16x16x32_bf16(A1, Bf, acc[1][nf], 0, 0, 0);
        }
    }

    // ---- epilogue + store (D: col=lane&15, row=(lane>>4)*4+reg) ----
    #pragma unroll
    for (int mf = 0; mf < 2; ++mf)
        #pragma unroll
        for (int nf = 0; nf < 4; ++nf)
            #pragma unroll
            for (int i = 0; i < 4; ++i) {
                int row = w * 32 + mf * 16 + kg * 4 + i;
                int col = n0 + nf * 16 + l15;
                size_t gidx = ((size_t)b * 128 + row) * HW + col;
                float v = acc[mf][nf][i];
                if (ACT == 1) v = 0.5f * v * (1.0f + erff(v * 0.70710678118654752f));
                if (ACT == 2) v = 1.f / (1.f + expf(-(v + bias[row])));
                if (ACT == 3) {
                    float gs = 1.f / (1.f + expf(-(v + bias[row])));
                    v = xres[gidx] + outs_e[gidx] * gs + in[gidx] * gf[gidx];
                }
                out[gidx] = v;
            }
}

// ---------------------------------------------------------------------------
// depthwise 3x3 SAME on V buffer ([b][128][HW] layout)
// ---------------------------------------------------------------------------
__global__ __launch_bounds__(256)
void dwconv_k(const float* __restrict__ V, const float* __restrict__ Wdw,
              float* __restrict__ vconv)
{
    int tid = blockIdx.x * 256 + threadIdx.x;   // B*128*HW threads
    int e = tid & (HW - 1);
    int bc = tid >> 14;
    int c = bc & 127;
    int y = e >> 7, x = e & 127;
    const float* vin = V + (size_t)bc * HW;
    const float* wf = Wdw + c * 9;
    float acc = 0.f;
    #pragma unroll
    for (int dy = 0; dy < 3; ++dy) {
        int yy = y + dy - 1;
        if (yy < 0 || yy > 127) continue;
        #pragma unroll
        for (int dx = 0; dx < 3; ++dx) {
            int xx = x + dx - 1;
            if (xx < 0 || xx > 127) continue;
            acc += wf[dy * 3 + dx] * vin[yy * 128 + xx];
        }
    }
    vconv[(size_t)bc * HW + e] = acc;
}

// ---------------------------------------------------------------------------
// Gram matrix partials: G[b] = X_b X_b^T, split-K (16 slices of 1024 px).
// ---------------------------------------------------------------------------
__global__ __launch_bounds__(256)
void gram_k(const float* __restrict__ x, float* __restrict__ Gp)
{
    __shared__ float Xi[64][65];
    __shared__ float Xj[64][65];
    int blk = blockIdx.x;
    int b = blk >> 6;
    int tp = (blk >> 4) & 3;
    int ks = blk & 15;
    int ti = tp >> 1, tj = tp & 1;
    int t = threadIdx.x;
    const float* xb = x + (size_t)b * 128 * HW + ks * 1024;
    const float* xi = xb + (size_t)(ti * 64) * HW;
    const float* xj = xb + (size_t)(tj * 64) * HW;
    int ty = t >> 4, tx = t & 15;
    float acc[4][4] = {};
    for (int kc = 0; kc < 16; ++kc) {
        __syncthreads();
        #pragma unroll
        for (int i = 0; i < 16; ++i) {
            int idx = t + i * 256;
            int ci = idx >> 6, jcol = idx & 63;
            Xi[ci][jcol] = xi[(size_t)ci * HW + kc * 64 + jcol];
            Xj[ci][jcol] = xj[(size_t)ci * HW + kc * 64 + jcol];
        }
        __syncthreads();
        #pragma unroll 8
        for (int k = 0; k < 64; ++k) {
            float a[4], bb[4];
            #pragma unroll
            for (int r = 0; r < 4; ++r) a[r] = Xi[ty * 4 + r][k];
            #pragma unroll
            for (int c = 0; c < 4; ++c) bb[c] = Xj[tx * 4 + c][k];
            #pragma unroll
            for (int r = 0; r < 4; ++r)
                #pragma unroll
                for (int c = 0; c < 4; ++c)
                    acc[r][c] += a[r] * bb[c];
        }
    }
    float* gp = Gp + (size_t)blk * 4096;
    #pragma unroll
    for (int r = 0; r < 4; ++r)
        #pragma unroll
        for (int c = 0; c < 4; ++c)
            gp[(ty * 4 + r) * 64 + tx * 4 + c] = acc[r][c];
}

__global__ void gram_reduce_k(const float* __restrict__ Gp, float* __restrict__ G)
{
    int idx = blockIdx.x * 256 + threadIdx.x;   // 8*128*128
    int b = idx >> 14;
    int ij = idx & 16383;
    int i = ij >> 7, j = ij & 127;
    int tp = ((i >> 6) << 1) | (j >> 6);
    int row = i & 63, col = j & 63;
    const float* gp = Gp + ((size_t)(b * 64 + tp * 16)) * 4096 + row * 64 + col;
    float s = 0.f;
    #pragma unroll
    for (int ks = 0; ks < 16; ++ks) s += gp[(size_t)ks * 4096];
    G[idx] = s;
}

// ---------------------------------------------------------------------------
// S_h = softmax( (Wq_h G Wk_h^T) * scale[h] ) — one block per (b,h).
// ---------------------------------------------------------------------------
__global__ __launch_bounds__(256)
void attn_s2_k(const float* __restrict__ G, const float* __restrict__ Wqkv,
               const float* __restrict__ scale, float* __restrict__ S)
{
    __shared__ float Wq[16][129];
    __shared__ float Wk[16][129];
    __shared__ float Ts[16][129];
    int bh = blockIdx.x;
    int b = bh >> 3, h = bh & 7;
    int t = threadIdx.x;
    #pragma unroll
    for (int i = 0; i < 8; ++i) {
        int idx = t + i * 256;
        int r = idx >> 7, ci = idx & 127;
        Wq[r][ci] = Wqkv[(size_t)(h * 16 + r) * 128 + ci];
        Wk[r][ci] = Wqkv[(size_t)(128 + h * 16 + r) * 128 + ci];
    }
    __syncthreads();
    const float* Gb = G + (size_t)b * 16384;
    #pragma unroll
    for (int i = 0; i < 8; ++i) {
        int idx = t + i * 256;
        int c = idx >> 7, col = idx & 127;
        float s = 0.f;
        #pragma unroll 8
        for (int ci = 0; ci < 128; ++ci)
            s += Wq[c][ci] * Gb[ci * 128 + col];
        Ts[c][col] = s;
    }
    __syncthreads();
    int c = t >> 4, d = t & 15;
    float s = 0.f;
    #pragma unroll 8
    for (int col = 0; col < 128; ++col)
        s += Ts[c][col] * Wk[d][col];
    s *= scale[h];
    float m = s;
    #pragma unroll
    for (int w = 1; w < 16; w <<= 1)
        m = fmaxf(m, __shfl_xor(m, w, 64));
    float e = expf(s - m);
    float sum = e;
    #pragma unroll
    for (int w = 1; w < 16; w <<= 1)
        sum += __shfl_xor(sum, w, 64);
    S[(size_t)bh * 256 + t] = e / sum;
}

// PV in-place over V: out[c,n] = sum_d A[c,d] v[d,n]. grid = 64 bh x 64 n-tiles
__global__ __launch_bounds__(256)
void attn_pv_k(float* __restrict__ V, const float* __restrict__ S)
{
    __shared__ float At[256];
    __shared__ float vt[16][256];
    int bh = blockIdx.x >> 6;
    int nt = blockIdx.x & 63;
    int b = bh >> 3, h = bh & 7;
    int t = threadIdx.x;
    At[t] = S[(size_t)bh * 256 + t];
    float* vbase = V + ((size_t)(b * 128) + h * 16) * HW + nt * 256;
    #pragma unroll
    for (int i = 0; i < 16; ++i) {
        int idx = t + i * 256;
        int d = idx >> 8, jj = idx & 255;
        vt[d][jj] = vbase[(size_t)d * HW + jj];
    }
    __syncthreads();
    float vv[16];
    #pragma unroll
    for (int d = 0; d < 16; ++d) vv[d] = vt[d][t];
    #pragma unroll
    for (int c = 0; c < 16; ++c) {
        float acc = 0.f;
        #pragma unroll
        for (int d = 0; d < 16; ++d) acc += At[c * 16 + d] * vv[d];
        vbase[(size_t)c * HW + t] = acc;
    }
}

// ---------------------------------------------------------------------------
// FFT machinery: radix-2, 128-point, LDS twiddle table (128th roots).
// ---------------------------------------------------------------------------
__device__ __forceinline__ void fft_build_tw(float2* tw, int t)
{
    if (t < 64) {
        float ang = 0.049087385212340519f * (float)t;  // 2*pi/128
        float sn, cs; sincosf(ang, &sn, &cs);
        tw[t] = make_float2(cs, sn);
    }
}

__device__ __forceinline__ void fft_stage_dif(float2 (*buf)[128], const float2* tw,
                                              int t, int s)
{
    int mh = 64 >> s;
    #pragma unroll
    for (int i = 0; i < 4; ++i) {
        int idx = t + i * 256;
        int rl = idx >> 6;
        int bf = idx & 63;
        int blk = bf >> (6 - s);
        int jj = bf & (mh - 1);
        int base = (blk << (7 - s)) + jj;
        float2 a = buf[rl][base];
        float2 b = buf[rl][base + mh];
        float2 w = tw[jj << s];
        float cs = w.x, sn = -w.y;
        float dx = a.x - b.x, dy = a.y - b.y;
        buf[rl][base] = make_float2(a.x + b.x, a.y + b.y);
        buf[rl][base + mh] = make_float2(dx * cs - dy * sn, dx * sn + dy * cs);
    }
}

__device__ __forceinline__ void fft_stage_dit(float2 (*buf)[128], const float2* tw,
                                              int t, int s)
{
    int mh = 64 >> s;
    #pragma unroll
    for (int i = 0; i < 4; ++i) {
        int idx = t + i * 256;
        int rl = idx >> 6;
        int bf = idx & 63;
        int blk = bf >> (6 - s);
        int jj = bf & (mh - 1);
        int base = (blk << (7 - s)) + jj;
        float2 a = buf[rl][base];
        float2 b = buf[rl][base + mh];
        float2 w = tw[jj << s];
        float cs = w.x, sn = w.y;
        float tx = b.x * cs - b.y * sn, ty = b.x * sn + b.y * cs;
        buf[rl][base] = make_float2(a.x + tx, a.y + ty);
        buf[rl][base + mh] = make_float2(a.x - tx, a.y - ty);
    }
}

__device__ __forceinline__ void fft16_fwd(float2 (*buf)[128], const float2* tw, int t)
{
    for (int s = 0; s < 7; ++s) { __syncthreads(); fft_stage_dif(buf, tw, t, s); }
    __syncthreads();
}
__device__ __forceinline__ void fft16_inv(float2 (*buf)[128], const float2* tw, int t)
{
    for (int s = 6; s >= 0; --s) { __syncthreads(); fft_stage_dit(buf, tw, t, s); }
    __syncthreads();
}

// P1: z = x + i*sw, row FFT over w, write transposed A[ch][i1][r]
__global__ __launch_bounds__(256)
void fft_p1_k(const float* __restrict__ x, const float* __restrict__ sw,
              float2* __restrict__ A)
{
    __shared__ float2 buf[16][128];
    __shared__ float2 tw[64];
    int t = threadIdx.x;
    fft_build_tw(tw, t);
    int ch = blockIdx.x >> 3;
    int rg = blockIdx.x & 7;
    size_t base = (size_t)ch * HW + rg * 2048;
    #pragma unroll
    for (int i = 0; i < 8; ++i) {
        int idx = t + i * 256;
        int rl = idx >> 7, cc = idx & 127;
        buf[rl][cc] = make_float2(x[base + rl * 128 + cc], sw[base + rl * 128 + cc]);
    }
    fft16_fwd(buf, tw, t);
    size_t abase = (size_t)ch * HW + rg * 16;
    #pragma unroll
    for (int i = 0; i < 8; ++i) {
        int idx = t + i * 256;
        int rl = idx & 15, k1 = idx >> 4;
        A[abase + (size_t)k1 * 128 + rl] = buf[rl][k1];
    }
}

// P2: in-place forward FFT along second dim
__global__ __launch_bounds__(256)
void fft_p2_k(float2* __restrict__ A)
{
    __shared__ float2 buf[16][128];
    __shared__ float2 tw[64];
    int t = threadIdx.x;
    fft_build_tw(tw, t);
    size_t base = (size_t)(blockIdx.x) * 2048;
    #pragma unroll
    for (int i = 0; i < 8; ++i) {
        int idx = t + i * 256;
        buf[idx >> 7][idx & 127] = A[base + idx];
    }
    fft16_fwd(buf, tw, t);
    #pragma unroll
    for (int i = 0; i < 8; ++i) {
        int idx = t + i * 256;
        A[base + idx] = buf[idx >> 7][idx & 127];
    }
}

// P3: Hermitian split + product (in-place, pair-owner writes both)
__global__ __launch_bounds__(256)
void fft_p3_k(float2* __restrict__ A)
{
    int tid = blockIdx.x * 256 + threadIdx.x;
    int ch = tid >> 14;
    int e = tid & 16383;
    int i1 = e >> 7, i2 = e & 127;
    int k1 = __brev((unsigned)i1) >> 25;
    int k2 = __brev((unsigned)i2) >> 25;
    int j1 = __brev((unsigned)((128 - k1) & 127)) >> 25;
    int j2 = __brev((unsigned)((128 - k2) & 127)) >> 25;
    int ej = j1 * 128 + j2;
    if (e > ej) return;
    size_t cb = (size_t)ch * HW;
    float2 z1 = A[cb + e];
    float2 z2 = A[cb + ej];
    float2 X = make_float2(0.5f * (z1.x + z2.x), 0.5f * (z1.y - z2.y));
    float Dx = z1.x - z2.x, Dy = z1.y + z2.y;
    float2 Wf = make_float2(0.5f * Dy, -0.5f * Dx);
    float2 Y = make_float2(X.x * Wf.x - X.y * Wf.y, X.x * Wf.y + X.y * Wf.x);
    A[cb + e] = Y;
    if (ej != e) A[cb + ej] = make_float2(Y.x, -Y.y);
}

// P4: in-place inverse FFT along second dim
__global__ __launch_bounds__(256)
void fft_p4_k(float2* __restrict__ A)
{
    __shared__ float2 buf[16][128];
    __shared__ float2 tw[64];
    int t = threadIdx.x;
    fft_build_tw(tw, t);
    size_t base = (size_t)(blockIdx.x) * 2048;
    #pragma unroll
    for (int i = 0; i < 8; ++i) {
        int idx = t + i * 256;
        buf[idx >> 7][idx & 127] = A[base + idx];
    }
    fft16_inv(buf, tw, t);
    #pragma unroll
    for (int i = 0; i < 8; ++i) {
        int idx = t + i * 256;
        A[base + idx] = buf[idx >> 7][idx & 127];
    }
}

// P5: inverse FFT over i1 (transposed read), write real out * scale
__global__ __launch_bounds__(256)
void fft_p5_k(const float2* __restrict__ A, float* __restrict__ outp)
{
    __shared__ float2 buf[16][128];
    __shared__ float2 tw[64];
    int t = threadIdx.x;
    fft_build_tw(tw, t);
    int ch = blockIdx.x >> 3;
    int rg = blockIdx.x & 7;
    size_t abase = (size_t)ch * HW + rg * 16;
    #pragma unroll
    for (int i = 0; i < 8; ++i) {
        int idx = t + i * 256;
        int rl = idx & 15, i1 = idx >> 4;
        buf[rl][i1] = A[abase + (size_t)i1 * 128 + rl];
    }
    fft16_inv(buf, tw, t);
    const float scale = 1.f / 2097152.f;   // 1/(128^3)
    size_t obase = (size_t)ch * HW + rg * 2048;
    #pragma unroll
    for (int i = 0; i < 8; ++i) {
        int idx = t + i * 256;
        int rl = idx >> 7, cc = idx & 127;
        outp[obase + rl * 128 + cc] = buf[rl][cc].x * scale;
    }
}

// ---------------------------------------------------------------------------
// Workspace plan (peak 128 MiB ws + d_out scratch):
//   phase A: V ws[0,64), vconv ws[64,128). Gp/G/S in d_out. out_s -> d_out.
//   phase B: tmp_ff ws[0,64); swb ws[64,128); per 2-batch chunk:
//            A ws[0,32), pre ws[32,64), out_f chunk overwrites swb chunk.
//   fuse:    gatef ws[0,64) (A/pre dead), out_fp ws[64,128) alive.
// ---------------------------------------------------------------------------
extern "C" void kernel_launch(void* const* d_in, const int* in_sizes, int n_in,
                              void* d_out, int out_size, void* d_ws, size_t ws_size,
                              hipStream_t stream)
{
    const float* x        = (const float*)d_in[0];
    const float* W_qkv    = (const float*)d_in[1];
    const float* W_dw     = (const float*)d_in[2];
    const float* W_proj_s = (const float*)d_in[3];
    const float* scale_s  = (const float*)d_in[4];
    const float* W_ff1    = (const float*)d_in[5];
    const float* W_ff2    = (const float*)d_in[6];
    const float* W_proj_f = (const float*)d_in[7];
    const float* W_gsf    = (const float*)d_in[8];
    const float* b_gsf    = (const float*)d_in[9];
    const float* W_gfs    = (const float*)d_in[10];
    const float* b_gfs    = (const float*)d_in[11];
    float* out = (float*)d_out;

    char* ws = (char*)d_ws;
    const size_t MB64 = 67108864ull;
    float* V      = (float*)(ws + 0);          // 64 MiB
    float* vconv  = (float*)(ws + MB64);       // 64 MiB
    float* Gp     = out;                        // 8 MiB   (in d_out, phase A)
    float* G      = out + 2097152;              // 512 KiB (in d_out, phase A)
    float* S      = out + 2097152 + 131072;     // 64 KiB  (in d_out, phase A)
    float* out_s  = out;                        // final residency in d_out
    float* tmp_ff = (float*)(ws + 0);
    float* swb    = (float*)(ws + MB64);
    float2* A     = (float2*)(ws + 0);          // 32 MiB per chunk
    float* pre    = (float*)(ws + MB64 / 2);    // 32 MiB per chunk
    float* out_fp = (float*)(ws + MB64);        // chunks overwrite swb
    float* gatef  = (float*)(ws + 0);           // 64 MiB (fuse phase)

    // --- spatial attention branch ---
    conv_mfma_k<0, false><<<2048, 256, 0, stream>>>(
        x, nullptr, W_qkv + 256 * 128, nullptr, nullptr, nullptr, nullptr, V);
    dwconv_k<<<65536, 256, 0, stream>>>(V, W_dw, vconv);
    gram_k<<<512, 256, 0, stream>>>(x, Gp);
    gram_reduce_k<<<512, 256, 0, stream>>>(Gp, G);
    attn_s2_k<<<64, 256, 0, stream>>>(G, W_qkv, scale_s, S);
    attn_pv_k<<<4096, 256, 0, stream>>>(V, S);
    conv_mfma_k<0, true><<<2048, 256, 0, stream>>>(
        V, vconv, W_proj_s, nullptr, nullptr, nullptr, nullptr, out_s);

    // --- frequency branch ---
    conv_mfma_k<1, false><<<2048, 256, 0, stream>>>(
        x, nullptr, W_ff1, nullptr, nullptr, nullptr, nullptr, tmp_ff);
    conv_mfma_k<0, false><<<2048, 256, 0, stream>>>(
        tmp_ff, nullptr, W_ff2, nullptr, nullptr, nullptr, nullptr, swb);
    for (int chunk = 0; chunk < 4; ++chunk) {
        const float* xc  = x   + (size_t)chunk * 2 * 128 * HW;
        const float* swc = swb + (size_t)chunk * 2 * 128 * HW;
        float* ofc = out_fp + (size_t)chunk * 2 * 128 * HW;
        fft_p1_k<<<2048, 256, 0, stream>>>(xc, swc, A);
        fft_p2_k<<<2048, 256, 0, stream>>>(A);
        fft_p3_k<<<16384, 256, 0, stream>>>(A);
        fft_p4_k<<<2048, 256, 0, stream>>>(A);
        fft_p5_k<<<2048, 256, 0, stream>>>(A, pre);
        conv_mfma_k<0, false><<<512, 256, 0, stream>>>(
            pre, nullptr, W_proj_f, nullptr, nullptr, nullptr, nullptr, ofc);
    }

    // --- gated fusion ---
    // gate_f = sigmoid(W_gsf @ out_s + b_gsf)
    conv_mfma_k<2, false><<<2048, 256, 0, stream>>>(
        out_s, nullptr, W_gsf, b_gsf, nullptr, nullptr, nullptr, gatef);
    // out = x + out_s * sigmoid(W_gfs @ out_f + b_gfs) + out_f * gate_f
    conv_mfma_k<3, false><<<2048, 256, 0, stream>>>(
        out_fp, nullptr, W_gfs, b_gfs, x, out_s, gatef, out);
}

// Round 6
// 762.354 us; speedup vs baseline: 2.4557x; 1.0796x over previous
//
#include <hip/hip_runtime.h>
#include <math.h>

#define HW 16384

typedef __attribute__((ext_vector_type(8))) short bf16x8;
typedef __attribute__((ext_vector_type(4))) float f32x4;

__device__ __forceinline__ unsigned f2bf_pk(float a, float b)
{
    unsigned ua = __float_as_uint(a), ub = __float_as_uint(b);
    ua = (ua + 0x7FFFu + ((ua >> 16) & 1u)) >> 16;   // RTN-even
    ub = (ub + 0x7FFFu + ((ub >> 16) & 1u)) >> 16;
    return (ua & 0xFFFFu) | (ub << 16);
}

// ---------------------------------------------------------------------------
// MFMA conv1x1: out[b,o,n] = epilogue( sum_c W[o,c] * (in[b,c,n](+in2)) )
// Tile: O=128 x N=64, K=128 one-shot. 256 thr = 4 waves; wave w owns rows
// [w*32,w*32+32). LDS: W bf16 [128][128] + X^T bf16 [64][128], both stored in
// 16B chunks with chunk ^= (row&7) swizzle (write & read same XOR).
// ACT: 0 none, 1 GELU, 2 sigmoid(v+bias) (gate), 3 final fuse epilogue.
// ---------------------------------------------------------------------------
template<int ACT, bool ADD2>
__global__ __launch_bounds__(256)
void conv_mfma_k(const float* __restrict__ in, const float* __restrict__ in2,
                 const float* __restrict__ Wsrc, const float* __restrict__ bias,
                 const float* __restrict__ xres, const float* outs_e,
                 const float* __restrict__ gf, float* out)
{
    __shared__ short WL[128 * 128];   // 32 KB
    __shared__ short XL[64 * 128];    // 16 KB
    int t = threadIdx.x;
    int gb = blockIdx.x;
    int b = gb >> 8;                  // 256 n-tiles per batch
    int n0 = (gb & 255) << 6;

    // ---- stage W (fp32 global -> bf16 LDS, swizzled) ----
    #pragma unroll
    for (int it = 0; it < 8; ++it) {
        int g = it * 256 + t;         // chunk id 0..2047
        int o = g >> 4, c16 = g & 15;
        const float* wp = Wsrc + o * 128 + c16 * 8;
        int4 p;
        p.x = f2bf_pk(wp[0], wp[1]);
        p.y = f2bf_pk(wp[2], wp[3]);
        p.z = f2bf_pk(wp[4], wp[5]);
        p.w = f2bf_pk(wp[6], wp[7]);
        ((int4*)WL)[o * 16 + (c16 ^ (o & 7))] = p;
    }
    // ---- stage X^T (register transpose: k-octet per lane, coalesced) ----
    const float* inb = in + (size_t)b * 128 * HW + n0;
    const float* in2b = ADD2 ? (in2 + (size_t)b * 128 * HW + n0) : nullptr;
    int nl = t & 63;
    #pragma unroll
    for (int it = 0; it < 4; ++it) {
        int c8 = (t >> 6) + it * 4;   // k-octet 0..15
        float v[8];
        #pragma unroll
        for (int j = 0; j < 8; ++j) {
            size_t a = (size_t)(c8 * 8 + j) * HW + nl;
            v[j] = inb[a];
            if (ADD2) v[j] += in2b[a];
        }
        int4 p;
        p.x = f2bf_pk(v[0], v[1]);
        p.y = f2bf_pk(v[2], v[3]);
        p.z = f2bf_pk(v[4], v[5]);
        p.w = f2bf_pk(v[6], v[7]);
        ((int4*)XL)[nl * 16 + (c8 ^ (nl & 7))] = p;
    }
    __syncthreads();

    // ---- MFMA main: 2 M-frags x 4 N-frags x 4 K-steps ----
    int l = t & 63, w = t >> 6, kg = l >> 4, l15 = l & 15, l7 = l15 & 7;
    f32x4 acc[2][4];
    #pragma unroll
    for (int mf = 0; mf < 2; ++mf)
        #pragma unroll
        for (int nf = 0; nf < 4; ++nf)
            acc[mf][nf] = (f32x4){0.f, 0.f, 0.f, 0.f};
    #pragma unroll
    for (int ks = 0; ks < 4; ++ks) {
        int ch = ks * 4 + kg;
        bf16x8 A0 = ((const bf16x8*)WL)[(w * 32 + l15) * 16 + (ch ^ l7)];
        bf16x8 A1 = ((const bf16x8*)WL)[(w * 32 + 16 + l15) * 16 + (ch ^ l7)];
        #pragma unroll
        for (int nf = 0; nf < 4; ++nf) {
            bf16x8 Bf = ((const bf16x8*)XL)[(nf * 16 + l15) * 16 + (ch ^ l7)];
            acc[0][nf] = __builtin_amdgcn_mfma_f32_16x16x32_bf16(A0, Bf, acc[0][nf], 0, 0, 0);
            acc[1][nf] = __builtin_amdgcn_mfma_f32_16x16x32_bf16(A1, Bf, acc[1][nf], 0, 0, 0);
        }
    }

    // ---- epilogue + store (D: col=lane&15, row=(lane>>4)*4+reg) ----
    #pragma unroll
    for (int mf = 0; mf < 2; ++mf)
        #pragma unroll
        for (int nf = 0; nf < 4; ++nf)
            #pragma unroll
            for (int i = 0; i < 4; ++i) {
                int row = w * 32 + mf * 16 + kg * 4 + i;
                int col = n0 + nf * 16 + l15;
                size_t gidx = ((size_t)b * 128 + row) * HW + col;
                float v = acc[mf][nf][i];
                if (ACT == 1) v = 0.5f * v * (1.0f + erff(v * 0.70710678118654752f));
                if (ACT == 2) v = 1.f / (1.f + expf(-(v + bias[row])));
                if (ACT == 3) {
                    float gs = 1.f / (1.f + expf(-(v + bias[row])));
                    v = xres[gidx] + outs_e[gidx] * gs + in[gidx] * gf[gidx];
                }
                out[gidx] = v;
            }
}

// ---------------------------------------------------------------------------
// depthwise 3x3 SAME on V buffer ([b][128][HW] layout)
// ---------------------------------------------------------------------------
__global__ __launch_bounds__(256)
void dwconv_k(const float* __restrict__ V, const float* __restrict__ Wdw,
              float* __restrict__ vconv)
{
    int tid = blockIdx.x * 256 + threadIdx.x;   // B*128*HW threads
    int e = tid & (HW - 1);
    int bc = tid >> 14;
    int c = bc & 127;
    int y = e >> 7, x = e & 127;
    const float* vin = V + (size_t)bc * HW;
    const float* wf = Wdw + c * 9;
    float acc = 0.f;
    #pragma unroll
    for (int dy = 0; dy < 3; ++dy) {
        int yy = y + dy - 1;
        if (yy < 0 || yy > 127) continue;
        #pragma unroll
        for (int dx = 0; dx < 3; ++dx) {
            int xx = x + dx - 1;
            if (xx < 0 || xx > 127) continue;
            acc += wf[dy * 3 + dx] * vin[yy * 128 + xx];
        }
    }
    vconv[(size_t)bc * HW + e] = acc;
}

// ---------------------------------------------------------------------------
// MFMA Gram partials: Gp[blk] = X_b[:, slice] X_b[:, slice]^T, slice = 256 px.
// blk = b*64 + ks. grid = 512, block = 256 (4 waves). LDS: X bf16 [128][128]
// per chunk (2 chunks of 128 k), XOR-octet swizzle. A-frag rows, B-frag rows
// from the SAME tile (B[k][j] = X[j][k] matches the B operand layout).
// Wave w owns rows [w*32, w*32+32) x all 128 cols: acc[2][8].
// ---------------------------------------------------------------------------
__global__ __launch_bounds__(256)
void gram_mfma_k(const float* __restrict__ x, float* __restrict__ Gp)
{
    __shared__ short XL[128 * 128];   // 32 KB
    int t = threadIdx.x;
    int blk = blockIdx.x;
    int b = blk >> 6, ks = blk & 63;
    const float* xb = x + (size_t)b * 128 * HW + ks * 256;
    int l = t & 63, w = t >> 6, kg = l >> 4, l15 = l & 15, l7 = l15 & 7;

    f32x4 acc[2][8];
    #pragma unroll
    for (int mf = 0; mf < 2; ++mf)
        #pragma unroll
        for (int nf = 0; nf < 8; ++nf)
            acc[mf][nf] = (f32x4){0.f, 0.f, 0.f, 0.f};

    #pragma unroll
    for (int kc = 0; kc < 2; ++kc) {
        __syncthreads();
        // stage 128 rows x 128 k (bf16, swizzled)
        #pragma unroll
        for (int it = 0; it < 8; ++it) {
            int g = it * 256 + t;     // 0..2047
            int row = g >> 4, oct = g & 15;
            const float* p = xb + (size_t)row * HW + kc * 128 + oct * 8;
            int4 pk;
            pk.x = f2bf_pk(p[0], p[1]);
            pk.y = f2bf_pk(p[2], p[3]);
            pk.z = f2bf_pk(p[4], p[5]);
            pk.w = f2bf_pk(p[6], p[7]);
            ((int4*)XL)[row * 16 + (oct ^ (row & 7))] = pk;
        }
        __syncthreads();
        #pragma unroll
        for (int s = 0; s < 4; ++s) {
            int oct = s * 4 + kg;
            bf16x8 A0 = ((const bf16x8*)XL)[(w * 32 + l15) * 16 + (oct ^ l7)];
            bf16x8 A1 = ((const bf16x8*)XL)[(w * 32 + 16 + l15) * 16 + (oct ^ l7)];
            #pragma unroll
            for (int nf = 0; nf < 8; ++nf) {
                bf16x8 Bf = ((const bf16x8*)XL)[(nf * 16 + l15) * 16 + (oct ^ l7)];
                acc[0][nf] = __builtin_amdgcn_mfma_f32_16x16x32_bf16(A0, Bf, acc[0][nf], 0, 0, 0);
                acc[1][nf] = __builtin_amdgcn_mfma_f32_16x16x32_bf16(A1, Bf, acc[1][nf], 0, 0, 0);
            }
        }
    }
    float* gp = Gp + (size_t)blk * 16384;
    #pragma unroll
    for (int mf = 0; mf < 2; ++mf)
        #pragma unroll
        for (int nf = 0; nf < 8; ++nf)
            #pragma unroll
            for (int i = 0; i < 4; ++i) {
                int row = w * 32 + mf * 16 + kg * 4 + i;
                int col = nf * 16 + l15;
                gp[row * 128 + col] = acc[mf][nf][i];
            }
}

// G[b][ij] = sum_{ks<64} Gp[b*64+ks][ij]
__global__ void gram_reduce_k(const float* __restrict__ Gp, float* __restrict__ G)
{
    int idx = blockIdx.x * 256 + threadIdx.x;   // 8*16384
    int b = idx >> 14;
    int ij = idx & 16383;
    const float* gp = Gp + (size_t)(b * 64) * 16384 + ij;
    float s = 0.f;
    #pragma unroll
    for (int ks = 0; ks < 64; ++ks) s += gp[(size_t)ks * 16384];
    G[idx] = s;
}

// ---------------------------------------------------------------------------
// S_h = softmax( (Wq_h G Wk_h^T) * scale[h] ) — one block per (b,h).
// ---------------------------------------------------------------------------
__global__ __launch_bounds__(256)
void attn_s2_k(const float* __restrict__ G, const float* __restrict__ Wqkv,
               const float* __restrict__ scale, float* __restrict__ S)
{
    __shared__ float Wq[16][129];
    __shared__ float Wk[16][129];
    __shared__ float Ts[16][129];
    int bh = blockIdx.x;
    int b = bh >> 3, h = bh & 7;
    int t = threadIdx.x;
    #pragma unroll
    for (int i = 0; i < 8; ++i) {
        int idx = t + i * 256;
        int r = idx >> 7, ci = idx & 127;
        Wq[r][ci] = Wqkv[(size_t)(h * 16 + r) * 128 + ci];
        Wk[r][ci] = Wqkv[(size_t)(128 + h * 16 + r) * 128 + ci];
    }
    __syncthreads();
    const float* Gb = G + (size_t)b * 16384;
    #pragma unroll
    for (int i = 0; i < 8; ++i) {
        int idx = t + i * 256;
        int c = idx >> 7, col = idx & 127;
        float s = 0.f;
        #pragma unroll 8
        for (int ci = 0; ci < 128; ++ci)
            s += Wq[c][ci] * Gb[ci * 128 + col];
        Ts[c][col] = s;
    }
    __syncthreads();
    int c = t >> 4, d = t & 15;
    float s = 0.f;
    #pragma unroll 8
    for (int col = 0; col < 128; ++col)
        s += Ts[c][col] * Wk[d][col];
    s *= scale[h];
    float m = s;
    #pragma unroll
    for (int w = 1; w < 16; w <<= 1)
        m = fmaxf(m, __shfl_xor(m, w, 64));
    float e = expf(s - m);
    float sum = e;
    #pragma unroll
    for (int w = 1; w < 16; w <<= 1)
        sum += __shfl_xor(sum, w, 64);
    S[(size_t)bh * 256 + t] = e / sum;
}

// PV in-place over V: out[c,n] = sum_d A[c,d] v[d,n]. grid = 64 bh x 64 n-tiles
__global__ __launch_bounds__(256)
void attn_pv_k(float* __restrict__ V, const float* __restrict__ S)
{
    __shared__ float At[256];
    __shared__ float vt[16][256];
    int bh = blockIdx.x >> 6;
    int nt = blockIdx.x & 63;
    int b = bh >> 3, h = bh & 7;
    int t = threadIdx.x;
    At[t] = S[(size_t)bh * 256 + t];
    float* vbase = V + ((size_t)(b * 128) + h * 16) * HW + nt * 256;
    #pragma unroll
    for (int i = 0; i < 16; ++i) {
        int idx = t + i * 256;
        int d = idx >> 8, jj = idx & 255;
        vt[d][jj] = vbase[(size_t)d * HW + jj];
    }
    __syncthreads();
    float vv[16];
    #pragma unroll
    for (int d = 0; d < 16; ++d) vv[d] = vt[d][t];
    #pragma unroll
    for (int c = 0; c < 16; ++c) {
        float acc = 0.f;
        #pragma unroll
        for (int d = 0; d < 16; ++d) acc += At[c * 16 + d] * vv[d];
        vbase[(size_t)c * HW + t] = acc;
    }
}

// ---------------------------------------------------------------------------
// FFT machinery: radix-2, 128-point, LDS twiddle table (128th roots).
// ---------------------------------------------------------------------------
__device__ __forceinline__ void fft_build_tw(float2* tw, int t)
{
    if (t < 64) {
        float ang = 0.049087385212340519f * (float)t;  // 2*pi/128
        float sn, cs; sincosf(ang, &sn, &cs);
        tw[t] = make_float2(cs, sn);
    }
}

__device__ __forceinline__ void fft_stage_dif(float2 (*buf)[128], const float2* tw,
                                              int t, int s)
{
    int mh = 64 >> s;
    #pragma unroll
    for (int i = 0; i < 4; ++i) {
        int idx = t + i * 256;
        int rl = idx >> 6;
        int bf = idx & 63;
        int blk = bf >> (6 - s);
        int jj = bf & (mh - 1);
        int base = (blk << (7 - s)) + jj;
        float2 a = buf[rl][base];
        float2 b = buf[rl][base + mh];
        float2 w = tw[jj << s];
        float cs = w.x, sn = -w.y;
        float dx = a.x - b.x, dy = a.y - b.y;
        buf[rl][base] = make_float2(a.x + b.x, a.y + b.y);
        buf[rl][base + mh] = make_float2(dx * cs - dy * sn, dx * sn + dy * cs);
    }
}

__device__ __forceinline__ void fft_stage_dit(float2 (*buf)[128], const float2* tw,
                                              int t, int s)
{
    int mh = 64 >> s;
    #pragma unroll
    for (int i = 0; i < 4; ++i) {
        int idx = t + i * 256;
        int rl = idx >> 6;
        int bf = idx & 63;
        int blk = bf >> (6 - s);
        int jj = bf & (mh - 1);
        int base = (blk << (7 - s)) + jj;
        float2 a = buf[rl][base];
        float2 b = buf[rl][base + mh];
        float2 w = tw[jj << s];
        float cs = w.x, sn = w.y;
        float tx = b.x * cs - b.y * sn, ty = b.x * sn + b.y * cs;
        buf[rl][base] = make_float2(a.x + tx, a.y + ty);
        buf[rl][base + mh] = make_float2(a.x - tx, a.y - ty);
    }
}

__device__ __forceinline__ void fft16_fwd(float2 (*buf)[128], const float2* tw, int t)
{
    for (int s = 0; s < 7; ++s) { __syncthreads(); fft_stage_dif(buf, tw, t, s); }
    __syncthreads();
}
__device__ __forceinline__ void fft16_inv(float2 (*buf)[128], const float2* tw, int t)
{
    for (int s = 6; s >= 0; --s) { __syncthreads(); fft_stage_dit(buf, tw, t, s); }
    __syncthreads();
}

// P1: z = x + i*sw, row FFT over w, write transposed A[ch][i1][r]
__global__ __launch_bounds__(256)
void fft_p1_k(const float* __restrict__ x, const float* __restrict__ sw,
              float2* __restrict__ A)
{
    __shared__ float2 buf[16][128];
    __shared__ float2 tw[64];
    int t = threadIdx.x;
    fft_build_tw(tw, t);
    int ch = blockIdx.x >> 3;
    int rg = blockIdx.x & 7;
    size_t base = (size_t)ch * HW + rg * 2048;
    #pragma unroll
    for (int i = 0; i < 8; ++i) {
        int idx = t + i * 256;
        int rl = idx >> 7, cc = idx & 127;
        buf[rl][cc] = make_float2(x[base + rl * 128 + cc], sw[base + rl * 128 + cc]);
    }
    fft16_fwd(buf, tw, t);
    size_t abase = (size_t)ch * HW + rg * 16;
    #pragma unroll
    for (int i = 0; i < 8; ++i) {
        int idx = t + i * 256;
        int rl = idx & 15, k1 = idx >> 4;
        A[abase + (size_t)k1 * 128 + rl] = buf[rl][k1];
    }
}

// P2: in-place forward FFT along second dim
__global__ __launch_bounds__(256)
void fft_p2_k(float2* __restrict__ A)
{
    __shared__ float2 buf[16][128];
    __shared__ float2 tw[64];
    int t = threadIdx.x;
    fft_build_tw(tw, t);
    size_t base = (size_t)(blockIdx.x) * 2048;
    #pragma unroll
    for (int i = 0; i < 8; ++i) {
        int idx = t + i * 256;
        buf[idx >> 7][idx & 127] = A[base + idx];
    }
    fft16_fwd(buf, tw, t);
    #pragma unroll
    for (int i = 0; i < 8; ++i) {
        int idx = t + i * 256;
        A[base + idx] = buf[idx >> 7][idx & 127];
    }
}

// P3: Hermitian split + product (in-place, pair-owner writes both)
__global__ __launch_bounds__(256)
void fft_p3_k(float2* __restrict__ A)
{
    int tid = blockIdx.x * 256 + threadIdx.x;
    int ch = tid >> 14;
    int e = tid & 16383;
    int i1 = e >> 7, i2 = e & 127;
    int k1 = __brev((unsigned)i1) >> 25;
    int k2 = __brev((unsigned)i2) >> 25;
    int j1 = __brev((unsigned)((128 - k1) & 127)) >> 25;
    int j2 = __brev((unsigned)((128 - k2) & 127)) >> 25;
    int ej = j1 * 128 + j2;
    if (e > ej) return;
    size_t cb = (size_t)ch * HW;
    float2 z1 = A[cb + e];
    float2 z2 = A[cb + ej];
    float2 X = make_float2(0.5f * (z1.x + z2.x), 0.5f * (z1.y - z2.y));
    float Dx = z1.x - z2.x, Dy = z1.y + z2.y;
    float2 Wf = make_float2(0.5f * Dy, -0.5f * Dx);
    float2 Y = make_float2(X.x * Wf.x - X.y * Wf.y, X.x * Wf.y + X.y * Wf.x);
    A[cb + e] = Y;
    if (ej != e) A[cb + ej] = make_float2(Y.x, -Y.y);
}

// P4: in-place inverse FFT along second dim
__global__ __launch_bounds__(256)
void fft_p4_k(float2* __restrict__ A)
{
    __shared__ float2 buf[16][128];
    __shared__ float2 tw[64];
    int t = threadIdx.x;
    fft_build_tw(tw, t);
    size_t base = (size_t)(blockIdx.x) * 2048;
    #pragma unroll
    for (int i = 0; i < 8; ++i) {
        int idx = t + i * 256;
        buf[idx >> 7][idx & 127] = A[base + idx];
    }
    fft16_inv(buf, tw, t);
    #pragma unroll
    for (int i = 0; i < 8; ++i) {
        int idx = t + i * 256;
        A[base + idx] = buf[idx >> 7][idx & 127];
    }
}

// P5: inverse FFT over i1 (transposed read), write real out * scale
__global__ __launch_bounds__(256)
void fft_p5_k(const float2* __restrict__ A, float* __restrict__ outp)
{
    __shared__ float2 buf[16][128];
    __shared__ float2 tw[64];
    int t = threadIdx.x;
    fft_build_tw(tw, t);
    int ch = blockIdx.x >> 3;
    int rg = blockIdx.x & 7;
    size_t abase = (size_t)ch * HW + rg * 16;
    #pragma unroll
    for (int i = 0; i < 8; ++i) {
        int idx = t + i * 256;
        int rl = idx & 15, i1 = idx >> 4;
        buf[rl][i1] = A[abase + (size_t)i1 * 128 + rl];
    }
    fft16_inv(buf, tw, t);
    const float scale = 1.f / 2097152.f;   // 1/(128^3)
    size_t obase = (size_t)ch * HW + rg * 2048;
    #pragma unroll
    for (int i = 0; i < 8; ++i) {
        int idx = t + i * 256;
        int rl = idx >> 7, cc = idx & 127;
        outp[obase + rl * 128 + cc] = buf[rl][cc].x * scale;
    }
}

// ---------------------------------------------------------------------------
// Workspace plan (peak 128 MiB ws + d_out scratch):
//   phase A: V ws[0,64), vconv ws[64,128). Gp [0,32MiB)+G+S in d_out (dead
//            until proj_s writes out_s there).
//   phase B: tmp_ff ws[0,64); swb ws[64,128); per 2-batch chunk:
//            A ws[0,32), pre ws[32,64), out_f chunk overwrites swb chunk.
//   fuse:    gatef ws[0,64) (A/pre dead), out_fp ws[64,128) alive.
// ---------------------------------------------------------------------------
extern "C" void kernel_launch(void* const* d_in, const int* in_sizes, int n_in,
                              void* d_out, int out_size, void* d_ws, size_t ws_size,
                              hipStream_t stream)
{
    const float* x        = (const float*)d_in[0];
    const float* W_qkv    = (const float*)d_in[1];
    const float* W_dw     = (const float*)d_in[2];
    const float* W_proj_s = (const float*)d_in[3];
    const float* scale_s  = (const float*)d_in[4];
    const float* W_ff1    = (const float*)d_in[5];
    const float* W_ff2    = (const float*)d_in[6];
    const float* W_proj_f = (const float*)d_in[7];
    const float* W_gsf    = (const float*)d_in[8];
    const float* b_gsf    = (const float*)d_in[9];
    const float* W_gfs    = (const float*)d_in[10];
    const float* b_gfs    = (const float*)d_in[11];
    float* out = (float*)d_out;

    char* ws = (char*)d_ws;
    const size_t MB64 = 67108864ull;
    float* V      = (float*)(ws + 0);          // 64 MiB
    float* vconv  = (float*)(ws + MB64);       // 64 MiB
    float* Gp     = out;                        // 32 MiB  (in d_out, phase A)
    float* G      = out + 8388608;              // 512 KiB (in d_out, phase A)
    float* S      = out + 8388608 + 131072;     // 64 KiB  (in d_out, phase A)
    float* out_s  = out;                        // final residency in d_out
    float* tmp_ff = (float*)(ws + 0);
    float* swb    = (float*)(ws + MB64);
    float2* A     = (float2*)(ws + 0);          // 32 MiB per chunk
    float* pre    = (float*)(ws + MB64 / 2);    // 32 MiB per chunk
    float* out_fp = (float*)(ws + MB64);        // chunks overwrite swb
    float* gatef  = (float*)(ws + 0);           // 64 MiB (fuse phase)

    // --- spatial attention branch ---
    conv_mfma_k<0, false><<<2048, 256, 0, stream>>>(
        x, nullptr, W_qkv + 256 * 128, nullptr, nullptr, nullptr, nullptr, V);
    dwconv_k<<<65536, 256, 0, stream>>>(V, W_dw, vconv);
    gram_mfma_k<<<512, 256, 0, stream>>>(x, Gp);
    gram_reduce_k<<<512, 256, 0, stream>>>(Gp, G);
    attn_s2_k<<<64, 256, 0, stream>>>(G, W_qkv, scale_s, S);
    attn_pv_k<<<4096, 256, 0, stream>>>(V, S);
    conv_mfma_k<0, true><<<2048, 256, 0, stream>>>(
        V, vconv, W_proj_s, nullptr, nullptr, nullptr, nullptr, out_s);

    // --- frequency branch ---
    conv_mfma_k<1, false><<<2048, 256, 0, stream>>>(
        x, nullptr, W_ff1, nullptr, nullptr, nullptr, nullptr, tmp_ff);
    conv_mfma_k<0, false><<<2048, 256, 0, stream>>>(
        tmp_ff, nullptr, W_ff2, nullptr, nullptr, nullptr, nullptr, swb);
    for (int chunk = 0; chunk < 4; ++chunk) {
        const float* xc  = x   + (size_t)chunk * 2 * 128 * HW;
        const float* swc = swb + (size_t)chunk * 2 * 128 * HW;
        float* ofc = out_fp + (size_t)chunk * 2 * 128 * HW;
        fft_p1_k<<<2048, 256, 0, stream>>>(xc, swc, A);
        fft_p2_k<<<2048, 256, 0, stream>>>(A);
        fft_p3_k<<<16384, 256, 0, stream>>>(A);
        fft_p4_k<<<2048, 256, 0, stream>>>(A);
        fft_p5_k<<<2048, 256, 0, stream>>>(A, pre);
        conv_mfma_k<0, false><<<512, 256, 0, stream>>>(
            pre, nullptr, W_proj_f, nullptr, nullptr, nullptr, nullptr, ofc);
    }

    // --- gated fusion ---
    // gate_f = sigmoid(W_gsf @ out_s + b_gsf)
    conv_mfma_k<2, false><<<2048, 256, 0, stream>>>(
        out_s, nullptr, W_gsf, b_gsf, nullptr, nullptr, nullptr, gatef);
    // out = x + out_s * sigmoid(W_gfs @ out_f + b_gfs) + out_f * gate_f
    conv_mfma_k<3, false><<<2048, 256, 0, stream>>>(
        out_fp, nullptr, W_gfs, b_gfs, x, out_s, gatef, out);
}

// Round 7
// 659.497 us; speedup vs baseline: 2.8387x; 1.1560x over previous
//
#include <hip/hip_runtime.h>
#include <math.h>

#define HW 16384

typedef __attribute__((ext_vector_type(8))) short bf16x8;
typedef __attribute__((ext_vector_type(4))) float f32x4;

__device__ __forceinline__ unsigned f2bf_pk(float a, float b)
{
    unsigned ua = __float_as_uint(a), ub = __float_as_uint(b);
    ua = (ua + 0x7FFFu + ((ua >> 16) & 1u)) >> 16;   // RTN-even
    ub = (ub + 0x7FFFu + ((ub >> 16) & 1u)) >> 16;
    return (ua & 0xFFFFu) | (ub << 16);
}

__device__ __forceinline__ int brev7(int v) { return (int)(__brev((unsigned)v) >> 25); }

// ---------------------------------------------------------------------------
// MFMA conv1x1: out[b,o,n] = epilogue( sum_c W[o,c] * (in[b,c,n](+in2)) )
// Tile: O=128 x N=64, K=128 one-shot. 4 waves; wave w owns rows [w*32,w*32+32).
// ACT: 0 none, 1 GELU, 2 sigmoid(v+bias) (gate), 3 final fuse epilogue.
// ---------------------------------------------------------------------------
template<int ACT, bool ADD2>
__global__ __launch_bounds__(256)
void conv_mfma_k(const float* __restrict__ in, const float* __restrict__ in2,
                 const float* __restrict__ Wsrc, const float* __restrict__ bias,
                 const float* __restrict__ xres, const float* outs_e,
                 const float* __restrict__ gf, float* out)
{
    __shared__ short WL[128 * 128];   // 32 KB
    __shared__ short XL[64 * 128];    // 16 KB
    int t = threadIdx.x;
    int gb = blockIdx.x;
    int b = gb >> 8;                  // 256 n-tiles per batch
    int n0 = (gb & 255) << 6;

    // ---- stage W (fp32 global -> bf16 LDS, swizzled) ----
    #pragma unroll
    for (int it = 0; it < 8; ++it) {
        int g = it * 256 + t;         // chunk id 0..2047
        int o = g >> 4, c16 = g & 15;
        const float* wp = Wsrc + o * 128 + c16 * 8;
        int4 p;
        p.x = f2bf_pk(wp[0], wp[1]);
        p.y = f2bf_pk(wp[2], wp[3]);
        p.z = f2bf_pk(wp[4], wp[5]);
        p.w = f2bf_pk(wp[6], wp[7]);
        ((int4*)WL)[o * 16 + (c16 ^ (o & 7))] = p;
    }
    // ---- stage X^T (register transpose: k-octet per lane, coalesced) ----
    const float* inb = in + (size_t)b * 128 * HW + n0;
    const float* in2b = ADD2 ? (in2 + (size_t)b * 128 * HW + n0) : nullptr;
    int nl = t & 63;
    #pragma unroll
    for (int it = 0; it < 4; ++it) {
        int c8 = (t >> 6) + it * 4;   // k-octet 0..15
        float v[8];
        #pragma unroll
        for (int j = 0; j < 8; ++j) {
            size_t a = (size_t)(c8 * 8 + j) * HW + nl;
            v[j] = inb[a];
            if (ADD2) v[j] += in2b[a];
        }
        int4 p;
        p.x = f2bf_pk(v[0], v[1]);
        p.y = f2bf_pk(v[2], v[3]);
        p.z = f2bf_pk(v[4], v[5]);
        p.w = f2bf_pk(v[6], v[7]);
        ((int4*)XL)[nl * 16 + (c8 ^ (nl & 7))] = p;
    }
    __syncthreads();

    // ---- MFMA main: 2 M-frags x 4 N-frags x 4 K-steps ----
    int l = t & 63, w = t >> 6, kg = l >> 4, l15 = l & 15, l7 = l15 & 7;
    f32x4 acc[2][4];
    #pragma unroll
    for (int mf = 0; mf < 2; ++mf)
        #pragma unroll
        for (int nf = 0; nf < 4; ++nf)
            acc[mf][nf] = (f32x4){0.f, 0.f, 0.f, 0.f};
    #pragma unroll
    for (int ks = 0; ks < 4; ++ks) {
        int ch = ks * 4 + kg;
        bf16x8 A0 = ((const bf16x8*)WL)[(w * 32 + l15) * 16 + (ch ^ l7)];
        bf16x8 A1 = ((const bf16x8*)WL)[(w * 32 + 16 + l15) * 16 + (ch ^ l7)];
        #pragma unroll
        for (int nf = 0; nf < 4; ++nf) {
            bf16x8 Bf = ((const bf16x8*)XL)[(nf * 16 + l15) * 16 + (ch ^ l7)];
            acc[0][nf] = __builtin_amdgcn_mfma_f32_16x16x32_bf16(A0, Bf, acc[0][nf], 0, 0, 0);
            acc[1][nf] = __builtin_amdgcn_mfma_f32_16x16x32_bf16(A1, Bf, acc[1][nf], 0, 0, 0);
        }
    }

    // ---- epilogue + store (D: col=lane&15, row=(lane>>4)*4+reg) ----
    #pragma unroll
    for (int mf = 0; mf < 2; ++mf)
        #pragma unroll
        for (int nf = 0; nf < 4; ++nf)
            #pragma unroll
            for (int i = 0; i < 4; ++i) {
                int row = w * 32 + mf * 16 + kg * 4 + i;
                int col = n0 + nf * 16 + l15;
                size_t gidx = ((size_t)b * 128 + row) * HW + col;
                float v = acc[mf][nf][i];
                if (ACT == 1) v = 0.5f * v * (1.0f + erff(v * 0.70710678118654752f));
                if (ACT == 2) v = 1.f / (1.f + expf(-(v + bias[row])));
                if (ACT == 3) {
                    float gs = 1.f / (1.f + expf(-(v + bias[row])));
                    v = xres[gidx] + outs_e[gidx] * gs + in[gidx] * gf[gidx];
                }
                out[gidx] = v;
            }
}

// ---------------------------------------------------------------------------
// depthwise 3x3 SAME, vectorized x4 (float4 loads/stores)
// grid = B*128*HW/1024 = 16384, block 256. 4 px per thread.
// ---------------------------------------------------------------------------
__global__ __launch_bounds__(256)
void dwconv_k(const float* __restrict__ V, const float* __restrict__ Wdw,
              float* __restrict__ vconv)
{
    int tid = blockIdx.x * 256 + threadIdx.x;
    int e4 = tid & 4095;          // 4096 quads per channel image
    int bc = tid >> 12;
    int c = bc & 127;
    int y = e4 >> 5;              // 128 rows, 32 quads per row
    int x0 = (e4 & 31) << 2;
    const float* vin = V + (size_t)bc * HW;
    float wf[9];
    #pragma unroll
    for (int i = 0; i < 9; ++i) wf[i] = Wdw[c * 9 + i];
    float a0 = 0.f, a1 = 0.f, a2 = 0.f, a3 = 0.f;
    #pragma unroll
    for (int dy = 0; dy < 3; ++dy) {
        int yy = y + dy - 1;
        if (yy < 0 || yy > 127) continue;
        const float* r = vin + yy * 128;
        float4 m = *(const float4*)(r + x0);
        float left  = (x0 > 0)   ? r[x0 - 1] : 0.f;
        float right = (x0 < 124) ? r[x0 + 4] : 0.f;
        float w0 = wf[dy * 3], w1 = wf[dy * 3 + 1], w2 = wf[dy * 3 + 2];
        a0 += w0 * left + w1 * m.x + w2 * m.y;
        a1 += w0 * m.x  + w1 * m.y + w2 * m.z;
        a2 += w0 * m.y  + w1 * m.z + w2 * m.w;
        a3 += w0 * m.z  + w1 * m.w + w2 * right;
    }
    *(float4*)(vconv + (size_t)bc * HW + y * 128 + x0) = make_float4(a0, a1, a2, a3);
}

// ---------------------------------------------------------------------------
// MFMA Gram partials: Gp[blk] = X_b[:, slice] X_b[:, slice]^T, slice = 256 px.
// ---------------------------------------------------------------------------
__global__ __launch_bounds__(256)
void gram_mfma_k(const float* __restrict__ x, float* __restrict__ Gp)
{
    __shared__ short XL[128 * 128];   // 32 KB
    int t = threadIdx.x;
    int blk = blockIdx.x;
    int b = blk >> 6, ks = blk & 63;
    const float* xb = x + (size_t)b * 128 * HW + ks * 256;
    int l = t & 63, w = t >> 6, kg = l >> 4, l15 = l & 15, l7 = l15 & 7;

    f32x4 acc[2][8];
    #pragma unroll
    for (int mf = 0; mf < 2; ++mf)
        #pragma unroll
        for (int nf = 0; nf < 8; ++nf)
            acc[mf][nf] = (f32x4){0.f, 0.f, 0.f, 0.f};

    #pragma unroll
    for (int kc = 0; kc < 2; ++kc) {
        __syncthreads();
        #pragma unroll
        for (int it = 0; it < 8; ++it) {
            int g = it * 256 + t;     // 0..2047
            int row = g >> 4, oct = g & 15;
            const float* p = xb + (size_t)row * HW + kc * 128 + oct * 8;
            int4 pk;
            pk.x = f2bf_pk(p[0], p[1]);
            pk.y = f2bf_pk(p[2], p[3]);
            pk.z = f2bf_pk(p[4], p[5]);
            pk.w = f2bf_pk(p[6], p[7]);
            ((int4*)XL)[row * 16 + (oct ^ (row & 7))] = pk;
        }
        __syncthreads();
        #pragma unroll
        for (int s = 0; s < 4; ++s) {
            int oct = s * 4 + kg;
            bf16x8 A0 = ((const bf16x8*)XL)[(w * 32 + l15) * 16 + (oct ^ l7)];
            bf16x8 A1 = ((const bf16x8*)XL)[(w * 32 + 16 + l15) * 16 + (oct ^ l7)];
            #pragma unroll
            for (int nf = 0; nf < 8; ++nf) {
                bf16x8 Bf = ((const bf16x8*)XL)[(nf * 16 + l15) * 16 + (oct ^ l7)];
                acc[0][nf] = __builtin_amdgcn_mfma_f32_16x16x32_bf16(A0, Bf, acc[0][nf], 0, 0, 0);
                acc[1][nf] = __builtin_amdgcn_mfma_f32_16x16x32_bf16(A1, Bf, acc[1][nf], 0, 0, 0);
            }
        }
    }
    float* gp = Gp + (size_t)blk * 16384;
    #pragma unroll
    for (int mf = 0; mf < 2; ++mf)
        #pragma unroll
        for (int nf = 0; nf < 8; ++nf)
            #pragma unroll
            for (int i = 0; i < 4; ++i) {
                int row = w * 32 + mf * 16 + kg * 4 + i;
                int col = nf * 16 + l15;
                gp[row * 128 + col] = acc[mf][nf][i];
            }
}

// G[b][ij] = sum_{ks<64} Gp[b*64+ks][ij]
__global__ void gram_reduce_k(const float* __restrict__ Gp, float* __restrict__ G)
{
    int idx = blockIdx.x * 256 + threadIdx.x;   // 8*16384
    int b = idx >> 14;
    int ij = idx & 16383;
    const float* gp = Gp + (size_t)(b * 64) * 16384 + ij;
    float s = 0.f;
    #pragma unroll
    for (int ks = 0; ks < 64; ++ks) s += gp[(size_t)ks * 16384];
    G[idx] = s;
}

// ---------------------------------------------------------------------------
// S_h = softmax( (Wq_h G Wk_h^T) * scale[h] ) — one block per (b,h).
// ---------------------------------------------------------------------------
__global__ __launch_bounds__(256)
void attn_s2_k(const float* __restrict__ G, const float* __restrict__ Wqkv,
               const float* __restrict__ scale, float* __restrict__ S)
{
    __shared__ float Wq[16][129];
    __shared__ float Wk[16][129];
    __shared__ float Ts[16][129];
    int bh = blockIdx.x;
    int b = bh >> 3, h = bh & 7;
    int t = threadIdx.x;
    #pragma unroll
    for (int i = 0; i < 8; ++i) {
        int idx = t + i * 256;
        int r = idx >> 7, ci = idx & 127;
        Wq[r][ci] = Wqkv[(size_t)(h * 16 + r) * 128 + ci];
        Wk[r][ci] = Wqkv[(size_t)(128 + h * 16 + r) * 128 + ci];
    }
    __syncthreads();
    const float* Gb = G + (size_t)b * 16384;
    #pragma unroll
    for (int i = 0; i < 8; ++i) {
        int idx = t + i * 256;
        int c = idx >> 7, col = idx & 127;
        float s = 0.f;
        #pragma unroll 8
        for (int ci = 0; ci < 128; ++ci)
            s += Wq[c][ci] * Gb[ci * 128 + col];
        Ts[c][col] = s;
    }
    __syncthreads();
    int c = t >> 4, d = t & 15;
    float s = 0.f;
    #pragma unroll 8
    for (int col = 0; col < 128; ++col)
        s += Ts[c][col] * Wk[d][col];
    s *= scale[h];
    float m = s;
    #pragma unroll
    for (int w = 1; w < 16; w <<= 1)
        m = fmaxf(m, __shfl_xor(m, w, 64));
    float e = expf(s - m);
    float sum = e;
    #pragma unroll
    for (int w = 1; w < 16; w <<= 1)
        sum += __shfl_xor(sum, w, 64);
    S[(size_t)bh * 256 + t] = e / sum;
}

// PV in-place over V: out[c,n] = sum_d A[c,d] v[d,n]. grid = 64 bh x 64 n-tiles
__global__ __launch_bounds__(256)
void attn_pv_k(float* __restrict__ V, const float* __restrict__ S)
{
    __shared__ float At[256];
    __shared__ float vt[16][256];
    int bh = blockIdx.x >> 6;
    int nt = blockIdx.x & 63;
    int b = bh >> 3, h = bh & 7;
    int t = threadIdx.x;
    At[t] = S[(size_t)bh * 256 + t];
    float* vbase = V + ((size_t)(b * 128) + h * 16) * HW + nt * 256;
    #pragma unroll
    for (int i = 0; i < 16; ++i) {
        int idx = t + i * 256;
        int d = idx >> 8, jj = idx & 255;
        vt[d][jj] = vbase[(size_t)d * HW + jj];
    }
    __syncthreads();
    float vv[16];
    #pragma unroll
    for (int d = 0; d < 16; ++d) vv[d] = vt[d][t];
    #pragma unroll
    for (int c = 0; c < 16; ++c) {
        float acc = 0.f;
        #pragma unroll
        for (int d = 0; d < 16; ++d) acc += At[c * 16 + d] * vv[d];
        vbase[(size_t)c * HW + t] = acc;
    }
}

// ---------------------------------------------------------------------------
// FFT machinery: radix-2, 128-point, LDS twiddle table (128th roots).
// ---------------------------------------------------------------------------
__device__ __forceinline__ void fft_build_tw(float2* tw, int t)
{
    if (t < 64) {
        float ang = 0.049087385212340519f * (float)t;  // 2*pi/128
        float sn, cs; sincosf(ang, &sn, &cs);
        tw[t] = make_float2(cs, sn);
    }
}

__device__ __forceinline__ void fft_stage_dif(float2 (*buf)[128], const float2* tw,
                                              int t, int s)
{
    int mh = 64 >> s;
    #pragma unroll
    for (int i = 0; i < 4; ++i) {
        int idx = t + i * 256;
        int rl = idx >> 6;
        int bf = idx & 63;
        int blk = bf >> (6 - s);
        int jj = bf & (mh - 1);
        int base = (blk << (7 - s)) + jj;
        float2 a = buf[rl][base];
        float2 b = buf[rl][base + mh];
        float2 w = tw[jj << s];
        float cs = w.x, sn = -w.y;
        float dx = a.x - b.x, dy = a.y - b.y;
        buf[rl][base] = make_float2(a.x + b.x, a.y + b.y);
        buf[rl][base + mh] = make_float2(dx * cs - dy * sn, dx * sn + dy * cs);
    }
}

__device__ __forceinline__ void fft_stage_dit(float2 (*buf)[128], const float2* tw,
                                              int t, int s)
{
    int mh = 64 >> s;
    #pragma unroll
    for (int i = 0; i < 4; ++i) {
        int idx = t + i * 256;
        int rl = idx >> 6;
        int bf = idx & 63;
        int blk = bf >> (6 - s);
        int jj = bf & (mh - 1);
        int base = (blk << (7 - s)) + jj;
        float2 a = buf[rl][base];
        float2 b = buf[rl][base + mh];
        float2 w = tw[jj << s];
        float cs = w.x, sn = w.y;
        float tx = b.x * cs - b.y * sn, ty = b.x * sn + b.y * cs;
        buf[rl][base] = make_float2(a.x + tx, a.y + ty);
        buf[rl][base + mh] = make_float2(a.x - tx, a.y - ty);
    }
}

__device__ __forceinline__ void fft16_fwd(float2 (*buf)[128], const float2* tw, int t)
{
    for (int s = 0; s < 7; ++s) { __syncthreads(); fft_stage_dif(buf, tw, t, s); }
    __syncthreads();
}
__device__ __forceinline__ void fft16_inv(float2 (*buf)[128], const float2* tw, int t)
{
    for (int s = 6; s >= 0; --s) { __syncthreads(); fft_stage_dit(buf, tw, t, s); }
    __syncthreads();
}

// P1: z = x + i*sw, row FFT over w, write transposed A[ch][i1][r]
__global__ __launch_bounds__(256)
void fft_p1_k(const float* __restrict__ x, const float* __restrict__ sw,
              float2* __restrict__ A)
{
    __shared__ float2 buf[16][128];
    __shared__ float2 tw[64];
    int t = threadIdx.x;
    fft_build_tw(tw, t);
    int ch = blockIdx.x >> 3;
    int rg = blockIdx.x & 7;
    size_t base = (size_t)ch * HW + rg * 2048;
    #pragma unroll
    for (int i = 0; i < 8; ++i) {
        int idx = t + i * 256;
        int rl = idx >> 7, cc = idx & 127;
        buf[rl][cc] = make_float2(x[base + rl * 128 + cc], sw[base + rl * 128 + cc]);
    }
    fft16_fwd(buf, tw, t);
    size_t abase = (size_t)ch * HW + rg * 16;
    #pragma unroll
    for (int i = 0; i < 8; ++i) {
        int idx = t + i * 256;
        int rl = idx & 15, k1 = idx >> 4;
        A[abase + (size_t)k1 * 128 + rl] = buf[rl][k1];
    }
}

// ---------------------------------------------------------------------------
// Fused P2+P3+P4: block owns 16 rows of A forming Hermitian row-pairs.
// rg==0: k1 = {0, 64} (self) + pairs (1..7, 127..121); rg>0: (8rg+s, 128-8rg-s).
// Fwd row-FFT -> in-LDS Hermitian split/product -> inv row-FFT -> write back.
// ---------------------------------------------------------------------------
__global__ __launch_bounds__(256)
void fft_p234_k(float2* __restrict__ A)
{
    __shared__ float2 buf[16][128];
    __shared__ float2 tw[64];
    int t = threadIdx.x;
    fft_build_tw(tw, t);
    int ch = blockIdx.x >> 3;
    int rg = blockIdx.x & 7;
    size_t cb = (size_t)ch * HW;

    // load 16 rows (i1 = brev7(k1_of(l)))
    #pragma unroll
    for (int i = 0; i < 8; ++i) {
        int idx = t + i * 256;
        int l = idx >> 7, cc = idx & 127;
        int k1l;
        if (rg == 0) k1l = (l < 2) ? l * 64 : (l < 9 ? l - 1 : 128 - (l - 8));
        else         k1l = (l < 8) ? 8 * rg + l : 128 - (8 * rg + l - 8);
        buf[l][cc] = A[cb + (size_t)brev7(k1l) * 128 + cc];
    }
    fft16_fwd(buf, tw, t);

    // Hermitian split + product, fully in LDS
    int nItems = (rg == 0) ? 1026 : 1024;
    for (int item = t; item < nItems; item += 256) {
        int lA, lB, k2;
        if (rg == 0) {
            if (item < 896) { int s = item >> 7; k2 = item & 127; lA = 2 + s; lB = 9 + s; }
            else            { int r = item - 896; lA = lB = r / 65; k2 = r % 65; }
        } else {
            int s = item >> 7; k2 = item & 127; lA = s; lB = 8 + s;
        }
        int i2 = brev7(k2), j2 = brev7((128 - k2) & 127);
        float2 z1 = buf[lA][i2];
        float2 z2 = buf[lB][j2];
        float2 X = make_float2(0.5f * (z1.x + z2.x), 0.5f * (z1.y - z2.y));
        float Dx = z1.x - z2.x, Dy = z1.y + z2.y;
        float2 Wf = make_float2(0.5f * Dy, -0.5f * Dx);
        float2 Y = make_float2(X.x * Wf.x - X.y * Wf.y, X.x * Wf.y + X.y * Wf.x);
        buf[lA][i2] = Y;
        buf[lB][j2] = make_float2(Y.x, -Y.y);
    }
    fft16_inv(buf, tw, t);

    // write back
    #pragma unroll
    for (int i = 0; i < 8; ++i) {
        int idx = t + i * 256;
        int l = idx >> 7, cc = idx & 127;
        int k1l;
        if (rg == 0) k1l = (l < 2) ? l * 64 : (l < 9 ? l - 1 : 128 - (l - 8));
        else         k1l = (l < 8) ? 8 * rg + l : 128 - (8 * rg + l - 8);
        A[cb + (size_t)brev7(k1l) * 128 + cc] = buf[l][cc];
    }
}

// P5: inverse FFT over i1 (transposed read), write real out * scale
__global__ __launch_bounds__(256)
void fft_p5_k(const float2* __restrict__ A, float* __restrict__ outp)
{
    __shared__ float2 buf[16][128];
    __shared__ float2 tw[64];
    int t = threadIdx.x;
    fft_build_tw(tw, t);
    int ch = blockIdx.x >> 3;
    int rg = blockIdx.x & 7;
    size_t abase = (size_t)ch * HW + rg * 16;
    #pragma unroll
    for (int i = 0; i < 8; ++i) {
        int idx = t + i * 256;
        int rl = idx & 15, i1 = idx >> 4;
        buf[rl][i1] = A[abase + (size_t)i1 * 128 + rl];
    }
    fft16_inv(buf, tw, t);
    const float scale = 1.f / 2097152.f;   // 1/(128^3)
    size_t obase = (size_t)ch * HW + rg * 2048;
    #pragma unroll
    for (int i = 0; i < 8; ++i) {
        int idx = t + i * 256;
        int rl = idx >> 7, cc = idx & 127;
        outp[obase + rl * 128 + cc] = buf[rl][cc].x * scale;
    }
}

// ---------------------------------------------------------------------------
// Workspace plan (peak 128 MiB ws + d_out scratch):
//   phase A: V ws[0,64), vconv ws[64,128). Gp [0,32MiB)+G+S in d_out (dead
//            until proj_s writes out_s there).
//   phase B: tmp_ff ws[0,64); swb ws[64,128); per 2-batch chunk:
//            A ws[0,32), pre ws[32,64), out_f chunk overwrites swb chunk.
//   fuse:    gatef ws[0,64) (A/pre dead), out_fp ws[64,128) alive.
// ---------------------------------------------------------------------------
extern "C" void kernel_launch(void* const* d_in, const int* in_sizes, int n_in,
                              void* d_out, int out_size, void* d_ws, size_t ws_size,
                              hipStream_t stream)
{
    const float* x        = (const float*)d_in[0];
    const float* W_qkv    = (const float*)d_in[1];
    const float* W_dw     = (const float*)d_in[2];
    const float* W_proj_s = (const float*)d_in[3];
    const float* scale_s  = (const float*)d_in[4];
    const float* W_ff1    = (const float*)d_in[5];
    const float* W_ff2    = (const float*)d_in[6];
    const float* W_proj_f = (const float*)d_in[7];
    const float* W_gsf    = (const float*)d_in[8];
    const float* b_gsf    = (const float*)d_in[9];
    const float* W_gfs    = (const float*)d_in[10];
    const float* b_gfs    = (const float*)d_in[11];
    float* out = (float*)d_out;

    char* ws = (char*)d_ws;
    const size_t MB64 = 67108864ull;
    float* V      = (float*)(ws + 0);          // 64 MiB
    float* vconv  = (float*)(ws + MB64);       // 64 MiB
    float* Gp     = out;                        // 32 MiB  (in d_out, phase A)
    float* G      = out + 8388608;              // 512 KiB (in d_out, phase A)
    float* S      = out + 8388608 + 131072;     // 64 KiB  (in d_out, phase A)
    float* out_s  = out;                        // final residency in d_out
    float* tmp_ff = (float*)(ws + 0);
    float* swb    = (float*)(ws + MB64);
    float2* A     = (float2*)(ws + 0);          // 32 MiB per chunk
    float* pre    = (float*)(ws + MB64 / 2);    // 32 MiB per chunk
    float* out_fp = (float*)(ws + MB64);        // chunks overwrite swb
    float* gatef  = (float*)(ws + 0);           // 64 MiB (fuse phase)

    // --- spatial attention branch ---
    conv_mfma_k<0, false><<<2048, 256, 0, stream>>>(
        x, nullptr, W_qkv + 256 * 128, nullptr, nullptr, nullptr, nullptr, V);
    dwconv_k<<<16384, 256, 0, stream>>>(V, W_dw, vconv);
    gram_mfma_k<<<512, 256, 0, stream>>>(x, Gp);
    gram_reduce_k<<<512, 256, 0, stream>>>(Gp, G);
    attn_s2_k<<<64, 256, 0, stream>>>(G, W_qkv, scale_s, S);
    attn_pv_k<<<4096, 256, 0, stream>>>(V, S);
    conv_mfma_k<0, true><<<2048, 256, 0, stream>>>(
        V, vconv, W_proj_s, nullptr, nullptr, nullptr, nullptr, out_s);

    // --- frequency branch ---
    conv_mfma_k<1, false><<<2048, 256, 0, stream>>>(
        x, nullptr, W_ff1, nullptr, nullptr, nullptr, nullptr, tmp_ff);
    conv_mfma_k<0, false><<<2048, 256, 0, stream>>>(
        tmp_ff, nullptr, W_ff2, nullptr, nullptr, nullptr, nullptr, swb);
    for (int chunk = 0; chunk < 4; ++chunk) {
        const float* xc  = x   + (size_t)chunk * 2 * 128 * HW;
        const float* swc = swb + (size_t)chunk * 2 * 128 * HW;
        float* ofc = out_fp + (size_t)chunk * 2 * 128 * HW;
        fft_p1_k<<<2048, 256, 0, stream>>>(xc, swc, A);
        fft_p234_k<<<2048, 256, 0, stream>>>(A);
        fft_p5_k<<<2048, 256, 0, stream>>>(A, pre);
        conv_mfma_k<0, false><<<512, 256, 0, stream>>>(
            pre, nullptr, W_proj_f, nullptr, nullptr, nullptr, nullptr, ofc);
    }

    // --- gated fusion ---
    // gate_f = sigmoid(W_gsf @ out_s + b_gsf)
    conv_mfma_k<2, false><<<2048, 256, 0, stream>>>(
        out_s, nullptr, W_gsf, b_gsf, nullptr, nullptr, nullptr, gatef);
    // out = x + out_s * sigmoid(W_gfs @ out_f + b_gfs) + out_f * gate_f
    conv_mfma_k<3, false><<<2048, 256, 0, stream>>>(
        out_fp, nullptr, W_gfs, b_gfs, x, out_s, gatef, out);
}

// Round 8
// 596.115 us; speedup vs baseline: 3.1405x; 1.1063x over previous
//
#include <hip/hip_runtime.h>
#include <math.h>

#define HW 16384

typedef __attribute__((ext_vector_type(8))) short bf16x8;
typedef __attribute__((ext_vector_type(4))) float f32x4;

__device__ __forceinline__ unsigned f2bf_pk(float a, float b)
{
    unsigned ua = __float_as_uint(a), ub = __float_as_uint(b);
    ua = (ua + 0x7FFFu + ((ua >> 16) & 1u)) >> 16;   // RTN-even
    ub = (ub + 0x7FFFu + ((ub >> 16) & 1u)) >> 16;
    return (ua & 0xFFFFu) | (ub << 16);
}
__device__ __forceinline__ float bf2f(unsigned short u)
{
    return __uint_as_float(((unsigned)u) << 16);
}
__device__ __forceinline__ int brev7(int v) { return (int)(__brev((unsigned)v) >> 25); }
__device__ __forceinline__ float sigmoidf_(float v) { return 1.f / (1.f + expf(-v)); }

// ---------------------------------------------------------------------------
// plain MFMA conv1x1: out[b,o,n] = sum_c W[o,c] * in[b,c,n]
// Tile O=128 x N=64, K=128. LDS swizzle: 16B chunk ^= (row&7).
// ---------------------------------------------------------------------------
__global__ __launch_bounds__(256)
void conv_mfma_k(const float* __restrict__ in, const float* __restrict__ Wsrc,
                 float* __restrict__ out)
{
    __shared__ short WL[128 * 128];   // 32 KB
    __shared__ short XL[64 * 128];    // 16 KB
    int t = threadIdx.x;
    int gb = blockIdx.x;
    int b = gb >> 8;
    int n0 = (gb & 255) << 6;

    #pragma unroll
    for (int it = 0; it < 8; ++it) {
        int g = it * 256 + t;
        int o = g >> 4, c16 = g & 15;
        const float* wp = Wsrc + o * 128 + c16 * 8;
        int4 p;
        p.x = f2bf_pk(wp[0], wp[1]); p.y = f2bf_pk(wp[2], wp[3]);
        p.z = f2bf_pk(wp[4], wp[5]); p.w = f2bf_pk(wp[6], wp[7]);
        ((int4*)WL)[o * 16 + (c16 ^ (o & 7))] = p;
    }
    const float* inb = in + (size_t)b * 128 * HW + n0;
    int nl = t & 63;
    #pragma unroll
    for (int it = 0; it < 4; ++it) {
        int c8 = (t >> 6) + it * 4;
        float v[8];
        #pragma unroll
        for (int j = 0; j < 8; ++j) v[j] = inb[(size_t)(c8 * 8 + j) * HW + nl];
        int4 p;
        p.x = f2bf_pk(v[0], v[1]); p.y = f2bf_pk(v[2], v[3]);
        p.z = f2bf_pk(v[4], v[5]); p.w = f2bf_pk(v[6], v[7]);
        ((int4*)XL)[nl * 16 + (c8 ^ (nl & 7))] = p;
    }
    __syncthreads();

    int l = t & 63, w = t >> 6, kg = l >> 4, l15 = l & 15, l7 = l15 & 7;
    f32x4 acc[2][4];
    #pragma unroll
    for (int mf = 0; mf < 2; ++mf)
        #pragma unroll
        for (int nf = 0; nf < 4; ++nf) acc[mf][nf] = (f32x4){0.f, 0.f, 0.f, 0.f};
    #pragma unroll
    for (int ks = 0; ks < 4; ++ks) {
        int ch = ks * 4 + kg;
        bf16x8 A0 = ((const bf16x8*)WL)[(w * 32 + l15) * 16 + (ch ^ l7)];
        bf16x8 A1 = ((const bf16x8*)WL)[(w * 32 + 16 + l15) * 16 + (ch ^ l7)];
        #pragma unroll
        for (int nf = 0; nf < 4; ++nf) {
            bf16x8 Bf = ((const bf16x8*)XL)[(nf * 16 + l15) * 16 + (ch ^ l7)];
            acc[0][nf] = __builtin_amdgcn_mfma_f32_16x16x32_bf16(A0, Bf, acc[0][nf], 0, 0, 0);
            acc[1][nf] = __builtin_amdgcn_mfma_f32_16x16x32_bf16(A1, Bf, acc[1][nf], 0, 0, 0);
        }
    }
    #pragma unroll
    for (int mf = 0; mf < 2; ++mf)
        #pragma unroll
        for (int nf = 0; nf < 4; ++nf)
            #pragma unroll
            for (int i = 0; i < 4; ++i) {
                int row = w * 32 + mf * 16 + kg * 4 + i;
                int col = n0 + nf * 16 + l15;
                out[((size_t)b * 128 + row) * HW + col] = acc[mf][nf][i];
            }
}

// ---------------------------------------------------------------------------
// depthwise 3x3 SAME, x4 vectorized, bf16 output
// ---------------------------------------------------------------------------
__global__ __launch_bounds__(256)
void dwconv_k(const float* __restrict__ V, const float* __restrict__ Wdw,
              unsigned short* __restrict__ vcb)
{
    int tid = blockIdx.x * 256 + threadIdx.x;
    int e4 = tid & 4095;
    int bc = tid >> 12;
    int c = bc & 127;
    int y = e4 >> 5;
    int x0 = (e4 & 31) << 2;
    const float* vin = V + (size_t)bc * HW;
    float wf[9];
    #pragma unroll
    for (int i = 0; i < 9; ++i) wf[i] = Wdw[c * 9 + i];
    float a0 = 0.f, a1 = 0.f, a2 = 0.f, a3 = 0.f;
    #pragma unroll
    for (int dy = 0; dy < 3; ++dy) {
        int yy = y + dy - 1;
        if (yy < 0 || yy > 127) continue;
        const float* r = vin + yy * 128;
        float4 m = *(const float4*)(r + x0);
        float left  = (x0 > 0)   ? r[x0 - 1] : 0.f;
        float right = (x0 < 124) ? r[x0 + 4] : 0.f;
        float w0 = wf[dy * 3], w1 = wf[dy * 3 + 1], w2 = wf[dy * 3 + 2];
        a0 += w0 * left + w1 * m.x + w2 * m.y;
        a1 += w0 * m.x  + w1 * m.y + w2 * m.z;
        a2 += w0 * m.y  + w1 * m.z + w2 * m.w;
        a3 += w0 * m.z  + w1 * m.w + w2 * right;
    }
    uint2 r2;
    r2.x = f2bf_pk(a0, a1);
    r2.y = f2bf_pk(a2, a3);
    *(uint2*)(vcb + (size_t)bc * HW + y * 128 + x0) = r2;
}

// ---------------------------------------------------------------------------
// MFMA Gram partials: 32 slices of 512 px. blk = b*32+ks. grid 256.
// ---------------------------------------------------------------------------
__global__ __launch_bounds__(256)
void gram_mfma_k(const float* __restrict__ x, float* __restrict__ Gp)
{
    __shared__ short XL[128 * 128];
    int t = threadIdx.x;
    int blk = blockIdx.x;
    int b = blk >> 5, ks = blk & 31;
    const float* xb = x + (size_t)b * 128 * HW + ks * 512;
    int l = t & 63, w = t >> 6, kg = l >> 4, l15 = l & 15, l7 = l15 & 7;

    f32x4 acc[2][8];
    #pragma unroll
    for (int mf = 0; mf < 2; ++mf)
        #pragma unroll
        for (int nf = 0; nf < 8; ++nf) acc[mf][nf] = (f32x4){0.f, 0.f, 0.f, 0.f};

    for (int kc = 0; kc < 4; ++kc) {
        __syncthreads();
        #pragma unroll
        for (int it = 0; it < 8; ++it) {
            int g = it * 256 + t;
            int row = g >> 4, oct = g & 15;
            const float* p = xb + (size_t)row * HW + kc * 128 + oct * 8;
            int4 pk;
            pk.x = f2bf_pk(p[0], p[1]); pk.y = f2bf_pk(p[2], p[3]);
            pk.z = f2bf_pk(p[4], p[5]); pk.w = f2bf_pk(p[6], p[7]);
            ((int4*)XL)[row * 16 + (oct ^ (row & 7))] = pk;
        }
        __syncthreads();
        #pragma unroll
        for (int s = 0; s < 4; ++s) {
            int oct = s * 4 + kg;
            bf16x8 A0 = ((const bf16x8*)XL)[(w * 32 + l15) * 16 + (oct ^ l7)];
            bf16x8 A1 = ((const bf16x8*)XL)[(w * 32 + 16 + l15) * 16 + (oct ^ l7)];
            #pragma unroll
            for (int nf = 0; nf < 8; ++nf) {
                bf16x8 Bf = ((const bf16x8*)XL)[(nf * 16 + l15) * 16 + (oct ^ l7)];
                acc[0][nf] = __builtin_amdgcn_mfma_f32_16x16x32_bf16(A0, Bf, acc[0][nf], 0, 0, 0);
                acc[1][nf] = __builtin_amdgcn_mfma_f32_16x16x32_bf16(A1, Bf, acc[1][nf], 0, 0, 0);
            }
        }
    }
    float* gp = Gp + (size_t)blk * 16384;
    #pragma unroll
    for (int mf = 0; mf < 2; ++mf)
        #pragma unroll
        for (int nf = 0; nf < 8; ++nf)
            #pragma unroll
            for (int i = 0; i < 4; ++i) {
                int row = w * 32 + mf * 16 + kg * 4 + i;
                int col = nf * 16 + l15;
                gp[row * 128 + col] = acc[mf][nf][i];
            }
}

__global__ void gram_reduce_k(const float* __restrict__ Gp, float* __restrict__ G)
{
    int idx = blockIdx.x * 256 + threadIdx.x;   // 8*16384
    int b = idx >> 14;
    int ij = idx & 16383;
    const float* gp = Gp + (size_t)(b * 32) * 16384 + ij;
    float s = 0.f;
    #pragma unroll
    for (int ks = 0; ks < 32; ++ks) s += gp[(size_t)ks * 16384];
    G[idx] = s;
}

// ---------------------------------------------------------------------------
// S_h = softmax( (Wq_h G Wk_h^T) * scale[h] )
// ---------------------------------------------------------------------------
__global__ __launch_bounds__(256)
void attn_s2_k(const float* __restrict__ G, const float* __restrict__ Wqkv,
               const float* __restrict__ scale, float* __restrict__ S)
{
    __shared__ float Wq[16][129];
    __shared__ float Wk[16][129];
    __shared__ float Ts[16][129];
    int bh = blockIdx.x;
    int b = bh >> 3, h = bh & 7;
    int t = threadIdx.x;
    #pragma unroll
    for (int i = 0; i < 8; ++i) {
        int idx = t + i * 256;
        int r = idx >> 7, ci = idx & 127;
        Wq[r][ci] = Wqkv[(size_t)(h * 16 + r) * 128 + ci];
        Wk[r][ci] = Wqkv[(size_t)(128 + h * 16 + r) * 128 + ci];
    }
    __syncthreads();
    const float* Gb = G + (size_t)b * 16384;
    #pragma unroll
    for (int i = 0; i < 8; ++i) {
        int idx = t + i * 256;
        int c = idx >> 7, col = idx & 127;
        float s = 0.f;
        #pragma unroll 8
        for (int ci = 0; ci < 128; ++ci)
            s += Wq[c][ci] * Gb[ci * 128 + col];
        Ts[c][col] = s;
    }
    __syncthreads();
    int c = t >> 4, d = t & 15;
    float s = 0.f;
    #pragma unroll 8
    for (int col = 0; col < 128; ++col)
        s += Ts[c][col] * Wk[d][col];
    s *= scale[h];
    float m = s;
    #pragma unroll
    for (int w = 1; w < 16; w <<= 1)
        m = fmaxf(m, __shfl_xor(m, w, 64));
    float e = expf(s - m);
    float sum = e;
    #pragma unroll
    for (int w = 1; w < 16; w <<= 1)
        sum += __shfl_xor(sum, w, 64);
    S[(size_t)bh * 256 + t] = e / sum;
}

// ---------------------------------------------------------------------------
// proj_s with fused PV: out_s = W_proj_s @ (PV(V) + vconv_bf16)
// staging applies per-head 16x16 S to V on the fly. LDS 56KB.
// ---------------------------------------------------------------------------
__global__ __launch_bounds__(256)
void proj_s_pv_k(const float* __restrict__ V, const unsigned short* __restrict__ vcb,
                 const float* __restrict__ S, const float* __restrict__ Wsrc,
                 float* __restrict__ out_s)
{
    __shared__ short WL[128 * 128];   // 32 KB
    __shared__ short XL[64 * 128];    // 16 KB
    __shared__ float SL[2048];        // 8 KB
    int t = threadIdx.x;
    int gb = blockIdx.x;
    int b = gb >> 8;
    int n0 = (gb & 255) << 6;

    #pragma unroll
    for (int it = 0; it < 8; ++it) {
        int g = it * 256 + t;
        int o = g >> 4, c16 = g & 15;
        const float* wp = Wsrc + o * 128 + c16 * 8;
        int4 p;
        p.x = f2bf_pk(wp[0], wp[1]); p.y = f2bf_pk(wp[2], wp[3]);
        p.z = f2bf_pk(wp[4], wp[5]); p.w = f2bf_pk(wp[6], wp[7]);
        ((int4*)WL)[o * 16 + (c16 ^ (o & 7))] = p;
    }
    #pragma unroll
    for (int i = 0; i < 8; ++i)
        SL[i * 256 + t] = S[(size_t)b * 2048 + i * 256 + t];
    __syncthreads();

    // PV staging: wave w handles heads 2w, 2w+1; lane -> col
    int col = t & 63, w = t >> 6;
    #pragma unroll
    for (int hh = 0; hh < 2; ++hh) {
        int h = w * 2 + hh;
        float v[16];
        #pragma unroll
        for (int d = 0; d < 16; ++d)
            v[d] = V[((size_t)(b * 128 + h * 16 + d)) * HW + n0 + col];
        float o[16];
        #pragma unroll
        for (int c = 0; c < 16; ++c) {
            const float* sl = SL + h * 256 + c * 16;
            float s = 0.f;
            #pragma unroll
            for (int d = 0; d < 16; ++d) s += sl[d] * v[d];
            o[c] = s + bf2f(vcb[((size_t)(b * 128 + h * 16 + c)) * HW + n0 + col]);
        }
        #pragma unroll
        for (int oc = 0; oc < 2; ++oc) {
            int octet = h * 2 + oc;
            int4 p;
            p.x = f2bf_pk(o[oc * 8 + 0], o[oc * 8 + 1]);
            p.y = f2bf_pk(o[oc * 8 + 2], o[oc * 8 + 3]);
            p.z = f2bf_pk(o[oc * 8 + 4], o[oc * 8 + 5]);
            p.w = f2bf_pk(o[oc * 8 + 6], o[oc * 8 + 7]);
            ((int4*)XL)[col * 16 + (octet ^ (col & 7))] = p;
        }
    }
    __syncthreads();

    int l = t & 63, kg = l >> 4, l15 = l & 15, l7 = l15 & 7;
    f32x4 acc[2][4];
    #pragma unroll
    for (int mf = 0; mf < 2; ++mf)
        #pragma unroll
        for (int nf = 0; nf < 4; ++nf) acc[mf][nf] = (f32x4){0.f, 0.f, 0.f, 0.f};
    #pragma unroll
    for (int ks = 0; ks < 4; ++ks) {
        int ch = ks * 4 + kg;
        bf16x8 A0 = ((const bf16x8*)WL)[(w * 32 + l15) * 16 + (ch ^ l7)];
        bf16x8 A1 = ((const bf16x8*)WL)[(w * 32 + 16 + l15) * 16 + (ch ^ l7)];
        #pragma unroll
        for (int nf = 0; nf < 4; ++nf) {
            bf16x8 Bf = ((const bf16x8*)XL)[(nf * 16 + l15) * 16 + (ch ^ l7)];
            acc[0][nf] = __builtin_amdgcn_mfma_f32_16x16x32_bf16(A0, Bf, acc[0][nf], 0, 0, 0);
            acc[1][nf] = __builtin_amdgcn_mfma_f32_16x16x32_bf16(A1, Bf, acc[1][nf], 0, 0, 0);
        }
    }
    #pragma unroll
    for (int mf = 0; mf < 2; ++mf)
        #pragma unroll
        for (int nf = 0; nf < 4; ++nf)
            #pragma unroll
            for (int i = 0; i < 4; ++i) {
                int row = w * 32 + mf * 16 + kg * 4 + i;
                int colg = n0 + nf * 16 + l15;
                out_s[((size_t)b * 128 + row) * HW + colg] = acc[mf][nf][i];
            }
}

// ---------------------------------------------------------------------------
// fused ff1 (GELU) + ff2: swb = W_ff2 @ gelu(W_ff1 @ x). LDS 48KB.
// ---------------------------------------------------------------------------
__global__ __launch_bounds__(256)
void ff_fused_k(const float* __restrict__ x, const float* __restrict__ W1,
                const float* __restrict__ W2, float* __restrict__ outp)
{
    __shared__ short WL[128 * 128];   // 32 KB (W1 then W2)
    __shared__ short XL[64 * 128];    // 16 KB (x^T then gelu(mid)^T)
    int t = threadIdx.x;
    int gb = blockIdx.x;
    int b = gb >> 8;
    int n0 = (gb & 255) << 6;

    #pragma unroll
    for (int it = 0; it < 8; ++it) {
        int g = it * 256 + t;
        int o = g >> 4, c16 = g & 15;
        const float* wp = W1 + o * 128 + c16 * 8;
        int4 p;
        p.x = f2bf_pk(wp[0], wp[1]); p.y = f2bf_pk(wp[2], wp[3]);
        p.z = f2bf_pk(wp[4], wp[5]); p.w = f2bf_pk(wp[6], wp[7]);
        ((int4*)WL)[o * 16 + (c16 ^ (o & 7))] = p;
    }
    const float* inb = x + (size_t)b * 128 * HW + n0;
    int nl = t & 63;
    #pragma unroll
    for (int it = 0; it < 4; ++it) {
        int c8 = (t >> 6) + it * 4;
        float v[8];
        #pragma unroll
        for (int j = 0; j < 8; ++j) v[j] = inb[(size_t)(c8 * 8 + j) * HW + nl];
        int4 p;
        p.x = f2bf_pk(v[0], v[1]); p.y = f2bf_pk(v[2], v[3]);
        p.z = f2bf_pk(v[4], v[5]); p.w = f2bf_pk(v[6], v[7]);
        ((int4*)XL)[nl * 16 + (c8 ^ (nl & 7))] = p;
    }
    __syncthreads();

    int l = t & 63, w = t >> 6, kg = l >> 4, l15 = l & 15, l7 = l15 & 7;
    f32x4 acc[2][4];
    #pragma unroll
    for (int mf = 0; mf < 2; ++mf)
        #pragma unroll
        for (int nf = 0; nf < 4; ++nf) acc[mf][nf] = (f32x4){0.f, 0.f, 0.f, 0.f};
    #pragma unroll
    for (int ks = 0; ks < 4; ++ks) {
        int ch = ks * 4 + kg;
        bf16x8 A0 = ((const bf16x8*)WL)[(w * 32 + l15) * 16 + (ch ^ l7)];
        bf16x8 A1 = ((const bf16x8*)WL)[(w * 32 + 16 + l15) * 16 + (ch ^ l7)];
        #pragma unroll
        for (int nf = 0; nf < 4; ++nf) {
            bf16x8 Bf = ((const bf16x8*)XL)[(nf * 16 + l15) * 16 + (ch ^ l7)];
            acc[0][nf] = __builtin_amdgcn_mfma_f32_16x16x32_bf16(A0, Bf, acc[0][nf], 0, 0, 0);
            acc[1][nf] = __builtin_amdgcn_mfma_f32_16x16x32_bf16(A1, Bf, acc[1][nf], 0, 0, 0);
        }
    }
    __syncthreads();   // all GEMM1 LDS reads done

    // restage W2 over WL; write gelu(acc) transposed into XL
    #pragma unroll
    for (int it = 0; it < 8; ++it) {
        int g = it * 256 + t;
        int o = g >> 4, c16 = g & 15;
        const float* wp = W2 + o * 128 + c16 * 8;
        int4 p;
        p.x = f2bf_pk(wp[0], wp[1]); p.y = f2bf_pk(wp[2], wp[3]);
        p.z = f2bf_pk(wp[4], wp[5]); p.w = f2bf_pk(wp[6], wp[7]);
        ((int4*)WL)[o * 16 + (c16 ^ (o & 7))] = p;
    }
    #pragma unroll
    for (int mf = 0; mf < 2; ++mf)
        #pragma unroll
        for (int nf = 0; nf < 4; ++nf) {
            float g4[4];
            #pragma unroll
            for (int i = 0; i < 4; ++i) {
                float v = acc[mf][nf][i];
                g4[i] = 0.5f * v * (1.0f + erff(v * 0.70710678118654752f));
            }
            int col = nf * 16 + l15;
            int r0 = w * 32 + mf * 16 + kg * 4;
            int octet = r0 >> 3;
            uint2 pk2;
            pk2.x = f2bf_pk(g4[0], g4[1]);
            pk2.y = f2bf_pk(g4[2], g4[3]);
            ((uint2*)XL)[(col * 16 + (octet ^ (col & 7))) * 2 + (kg & 1)] = pk2;
        }
    __syncthreads();

    f32x4 acc2[2][4];
    #pragma unroll
    for (int mf = 0; mf < 2; ++mf)
        #pragma unroll
        for (int nf = 0; nf < 4; ++nf) acc2[mf][nf] = (f32x4){0.f, 0.f, 0.f, 0.f};
    #pragma unroll
    for (int ks = 0; ks < 4; ++ks) {
        int ch = ks * 4 + kg;
        bf16x8 A0 = ((const bf16x8*)WL)[(w * 32 + l15) * 16 + (ch ^ l7)];
        bf16x8 A1 = ((const bf16x8*)WL)[(w * 32 + 16 + l15) * 16 + (ch ^ l7)];
        #pragma unroll
        for (int nf = 0; nf < 4; ++nf) {
            bf16x8 Bf = ((const bf16x8*)XL)[(nf * 16 + l15) * 16 + (ch ^ l7)];
            acc2[0][nf] = __builtin_amdgcn_mfma_f32_16x16x32_bf16(A0, Bf, acc2[0][nf], 0, 0, 0);
            acc2[1][nf] = __builtin_amdgcn_mfma_f32_16x16x32_bf16(A1, Bf, acc2[1][nf], 0, 0, 0);
        }
    }
    #pragma unroll
    for (int mf = 0; mf < 2; ++mf)
        #pragma unroll
        for (int nf = 0; nf < 4; ++nf)
            #pragma unroll
            for (int i = 0; i < 4; ++i) {
                int row = w * 32 + mf * 16 + kg * 4 + i;
                int col = n0 + nf * 16 + l15;
                outp[((size_t)b * 128 + row) * HW + col] = acc2[mf][nf][i];
            }
}

// ---------------------------------------------------------------------------
// fused gates + final: out = x + out_s*sigmoid(Wgfs@out_f+bgfs)
//                            + out_f*sigmoid(Wgsf@out_s+bgsf)
// grid = b*256nt*2half (half innermost). LDS 64KB exactly.
// ---------------------------------------------------------------------------
__global__ __launch_bounds__(256)
void fuse2_k(const float* __restrict__ x, const float* __restrict__ outs,
             const float* __restrict__ outf,
             const float* __restrict__ Wgsf, const float* __restrict__ bgsf,
             const float* __restrict__ Wgfs, const float* __restrict__ bgfs,
             float* __restrict__ out)
{
    __shared__ short WS[64 * 128];  // W_gsf half rows
    __shared__ short WF[64 * 128];  // W_gfs half rows
    __shared__ short XS[64 * 128];  // out_s^T tile (all 128 ch)
    __shared__ short XF[64 * 128];  // out_f^T tile
    int t = threadIdx.x;
    int gb = blockIdx.x;
    int half = gb & 1;
    int nt = (gb >> 1) & 255;
    int b = gb >> 9;
    int n0 = nt << 6;

    #pragma unroll
    for (int it = 0; it < 4; ++it) {
        int g = it * 256 + t;          // 0..1023 chunks
        int o = g >> 4, c16 = g & 15;
        const float* w1 = Wgsf + (size_t)(half * 64 + o) * 128 + c16 * 8;
        const float* w2 = Wgfs + (size_t)(half * 64 + o) * 128 + c16 * 8;
        int4 p1, p2;
        p1.x = f2bf_pk(w1[0], w1[1]); p1.y = f2bf_pk(w1[2], w1[3]);
        p1.z = f2bf_pk(w1[4], w1[5]); p1.w = f2bf_pk(w1[6], w1[7]);
        p2.x = f2bf_pk(w2[0], w2[1]); p2.y = f2bf_pk(w2[2], w2[3]);
        p2.z = f2bf_pk(w2[4], w2[5]); p2.w = f2bf_pk(w2[6], w2[7]);
        ((int4*)WS)[o * 16 + (c16 ^ (o & 7))] = p1;
        ((int4*)WF)[o * 16 + (c16 ^ (o & 7))] = p2;
    }
    const float* sb = outs + (size_t)b * 128 * HW + n0;
    const float* fb = outf + (size_t)b * 128 * HW + n0;
    int nl = t & 63;
    #pragma unroll
    for (int it = 0; it < 4; ++it) {
        int c8 = (t >> 6) + it * 4;
        float vs[8], vf[8];
        #pragma unroll
        for (int j = 0; j < 8; ++j) {
            size_t a = (size_t)(c8 * 8 + j) * HW + nl;
            vs[j] = sb[a];
            vf[j] = fb[a];
        }
        int4 ps, pf;
        ps.x = f2bf_pk(vs[0], vs[1]); ps.y = f2bf_pk(vs[2], vs[3]);
        ps.z = f2bf_pk(vs[4], vs[5]); ps.w = f2bf_pk(vs[6], vs[7]);
        pf.x = f2bf_pk(vf[0], vf[1]); pf.y = f2bf_pk(vf[2], vf[3]);
        pf.z = f2bf_pk(vf[4], vf[5]); pf.w = f2bf_pk(vf[6], vf[7]);
        ((int4*)XS)[nl * 16 + (c8 ^ (nl & 7))] = ps;
        ((int4*)XF)[nl * 16 + (c8 ^ (nl & 7))] = pf;
    }
    __syncthreads();

    int l = t & 63, w = t >> 6, kg = l >> 4, l15 = l & 15, l7 = l15 & 7;
    f32x4 aS[4], aF[4];
    #pragma unroll
    for (int nf = 0; nf < 4; ++nf) {
        aS[nf] = (f32x4){0.f, 0.f, 0.f, 0.f};
        aF[nf] = (f32x4){0.f, 0.f, 0.f, 0.f};
    }
    #pragma unroll
    for (int ks = 0; ks < 4; ++ks) {
        int ch = ks * 4 + kg;
        bf16x8 As = ((const bf16x8*)WS)[(w * 16 + l15) * 16 + (ch ^ l7)];
        bf16x8 Af = ((const bf16x8*)WF)[(w * 16 + l15) * 16 + (ch ^ l7)];
        #pragma unroll
        for (int nf = 0; nf < 4; ++nf) {
            bf16x8 Bs = ((const bf16x8*)XS)[(nf * 16 + l15) * 16 + (ch ^ l7)];
            bf16x8 Bf = ((const bf16x8*)XF)[(nf * 16 + l15) * 16 + (ch ^ l7)];
            aS[nf] = __builtin_amdgcn_mfma_f32_16x16x32_bf16(As, Bs, aS[nf], 0, 0, 0);
            aF[nf] = __builtin_amdgcn_mfma_f32_16x16x32_bf16(Af, Bf, aF[nf], 0, 0, 0);
        }
    }
    #pragma unroll
    for (int nf = 0; nf < 4; ++nf)
        #pragma unroll
        for (int i = 0; i < 4; ++i) {
            int row = half * 64 + w * 16 + kg * 4 + i;
            int cc = nf * 16 + l15;
            float gf = sigmoidf_(aS[nf][i] + bgsf[row]);   // gates out_f
            float gs = sigmoidf_(aF[nf][i] + bgfs[row]);   // gates out_s
            int so = cc * 128 + ((row >> 3) ^ (cc & 7)) * 8 + (row & 7);
            float os = bf2f((unsigned short)XS[so]);
            float of = bf2f((unsigned short)XF[so]);
            size_t gidx = ((size_t)(b * 128) + row) * HW + n0 + cc;
            out[gidx] = x[gidx] + os * gs + of * gf;
        }
}

// ---------------------------------------------------------------------------
// FFT: radix-2 128-pt, LDS twiddles
// ---------------------------------------------------------------------------
__device__ __forceinline__ void fft_build_tw(float2* tw, int t)
{
    if (t < 64) {
        float ang = 0.049087385212340519f * (float)t;
        float sn, cs; sincosf(ang, &sn, &cs);
        tw[t] = make_float2(cs, sn);
    }
}

__device__ __forceinline__ void fft_stage_dif(float2 (*buf)[128], const float2* tw,
                                              int t, int s)
{
    int mh = 64 >> s;
    #pragma unroll
    for (int i = 0; i < 4; ++i) {
        int idx = t + i * 256;
        int rl = idx >> 6;
        int bf = idx & 63;
        int blk = bf >> (6 - s);
        int jj = bf & (mh - 1);
        int base = (blk << (7 - s)) + jj;
        float2 a = buf[rl][base];
        float2 b = buf[rl][base + mh];
        float2 w = tw[jj << s];
        float cs = w.x, sn = -w.y;
        float dx = a.x - b.x, dy = a.y - b.y;
        buf[rl][base] = make_float2(a.x + b.x, a.y + b.y);
        buf[rl][base + mh] = make_float2(dx * cs - dy * sn, dx * sn + dy * cs);
    }
}

__device__ __forceinline__ void fft_stage_dit(float2 (*buf)[128], const float2* tw,
                                              int t, int s)
{
    int mh = 64 >> s;
    #pragma unroll
    for (int i = 0; i < 4; ++i) {
        int idx = t + i * 256;
        int rl = idx >> 6;
        int bf = idx & 63;
        int blk = bf >> (6 - s);
        int jj = bf & (mh - 1);
        int base = (blk << (7 - s)) + jj;
        float2 a = buf[rl][base];
        float2 b = buf[rl][base + mh];
        float2 w = tw[jj << s];
        float cs = w.x, sn = w.y;
        float tx = b.x * cs - b.y * sn, ty = b.x * sn + b.y * cs;
        buf[rl][base] = make_float2(a.x + tx, a.y + ty);
        buf[rl][base + mh] = make_float2(a.x - tx, a.y - ty);
    }
}

__device__ __forceinline__ void fft16_fwd(float2 (*buf)[128], const float2* tw, int t)
{
    for (int s = 0; s < 7; ++s) { __syncthreads(); fft_stage_dif(buf, tw, t, s); }
    __syncthreads();
}
__device__ __forceinline__ void fft16_inv(float2 (*buf)[128], const float2* tw, int t)
{
    for (int s = 6; s >= 0; --s) { __syncthreads(); fft_stage_dit(buf, tw, t, s); }
    __syncthreads();
}

__global__ __launch_bounds__(256)
void fft_p1_k(const float* __restrict__ x, const float* __restrict__ sw,
              float2* __restrict__ A)
{
    __shared__ float2 buf[16][128];
    __shared__ float2 tw[64];
    int t = threadIdx.x;
    fft_build_tw(tw, t);
    int ch = blockIdx.x >> 3;
    int rg = blockIdx.x & 7;
    size_t base = (size_t)ch * HW + rg * 2048;
    #pragma unroll
    for (int i = 0; i < 8; ++i) {
        int idx = t + i * 256;
        int rl = idx >> 7, cc = idx & 127;
        buf[rl][cc] = make_float2(x[base + rl * 128 + cc], sw[base + rl * 128 + cc]);
    }
    fft16_fwd(buf, tw, t);
    size_t abase = (size_t)ch * HW + rg * 16;
    #pragma unroll
    for (int i = 0; i < 8; ++i) {
        int idx = t + i * 256;
        int rl = idx & 15, k1 = idx >> 4;
        A[abase + (size_t)k1 * 128 + rl] = buf[rl][k1];
    }
}

__global__ __launch_bounds__(256)
void fft_p234_k(float2* __restrict__ A)
{
    __shared__ float2 buf[16][128];
    __shared__ float2 tw[64];
    int t = threadIdx.x;
    fft_build_tw(tw, t);
    int ch = blockIdx.x >> 3;
    int rg = blockIdx.x & 7;
    size_t cb = (size_t)ch * HW;

    #pragma unroll
    for (int i = 0; i < 8; ++i) {
        int idx = t + i * 256;
        int l = idx >> 7, cc = idx & 127;
        int k1l;
        if (rg == 0) k1l = (l < 2) ? l * 64 : (l < 9 ? l - 1 : 128 - (l - 8));
        else         k1l = (l < 8) ? 8 * rg + l : 128 - (8 * rg + l - 8);
        buf[l][cc] = A[cb + (size_t)brev7(k1l) * 128 + cc];
    }
    fft16_fwd(buf, tw, t);

    int nItems = (rg == 0) ? 1026 : 1024;
    for (int item = t; item < nItems; item += 256) {
        int lA, lB, k2;
        if (rg == 0) {
            if (item < 896) { int s = item >> 7; k2 = item & 127; lA = 2 + s; lB = 9 + s; }
            else            { int r = item - 896; lA = lB = r / 65; k2 = r % 65; }
        } else {
            int s = item >> 7; k2 = item & 127; lA = s; lB = 8 + s;
        }
        int i2 = brev7(k2), j2 = brev7((128 - k2) & 127);
        float2 z1 = buf[lA][i2];
        float2 z2 = buf[lB][j2];
        float2 X = make_float2(0.5f * (z1.x + z2.x), 0.5f * (z1.y - z2.y));
        float Dx = z1.x - z2.x, Dy = z1.y + z2.y;
        float2 Wf = make_float2(0.5f * Dy, -0.5f * Dx);
        float2 Y = make_float2(X.x * Wf.x - X.y * Wf.y, X.x * Wf.y + X.y * Wf.x);
        buf[lA][i2] = Y;
        buf[lB][j2] = make_float2(Y.x, -Y.y);
    }
    fft16_inv(buf, tw, t);

    #pragma unroll
    for (int i = 0; i < 8; ++i) {
        int idx = t + i * 256;
        int l = idx >> 7, cc = idx & 127;
        int k1l;
        if (rg == 0) k1l = (l < 2) ? l * 64 : (l < 9 ? l - 1 : 128 - (l - 8));
        else         k1l = (l < 8) ? 8 * rg + l : 128 - (8 * rg + l - 8);
        A[cb + (size_t)brev7(k1l) * 128 + cc] = buf[l][cc];
    }
}

__global__ __launch_bounds__(256)
void fft_p5_k(const float2* __restrict__ A, float* __restrict__ outp)
{
    __shared__ float2 buf[16][128];
    __shared__ float2 tw[64];
    int t = threadIdx.x;
    fft_build_tw(tw, t);
    int ch = blockIdx.x >> 3;
    int rg = blockIdx.x & 7;
    size_t abase = (size_t)ch * HW + rg * 16;
    #pragma unroll
    for (int i = 0; i < 8; ++i) {
        int idx = t + i * 256;
        int rl = idx & 15, i1 = idx >> 4;
        buf[rl][i1] = A[abase + (size_t)i1 * 128 + rl];
    }
    fft16_inv(buf, tw, t);
    const float scale = 1.f / 2097152.f;
    size_t obase = (size_t)ch * HW + rg * 2048;
    #pragma unroll
    for (int i = 0; i < 8; ++i) {
        int idx = t + i * 256;
        int rl = idx >> 7, cc = idx & 127;
        outp[obase + rl * 128 + cc] = buf[rl][cc].x * scale;
    }
}

// ---------------------------------------------------------------------------
// Workspace plan (peak 128 MiB ws + d_out scratch):
//  phase A: V ws[0,64); vconv bf16 d_out[0,32MB); Gp d_out[32,48); G,S after;
//           out_s -> ws[64,128).
//  phase B: swb ws[0,64); per 2-batch chunk: A d_out[0,32), pre d_out[32,48),
//           out_f chunk overwrites swb chunk (ws[0,64)).
//  fuse2:   reads out_s(ws hi), out_f(ws lo), x; writes d_out (no race).
// ---------------------------------------------------------------------------
extern "C" void kernel_launch(void* const* d_in, const int* in_sizes, int n_in,
                              void* d_out, int out_size, void* d_ws, size_t ws_size,
                              hipStream_t stream)
{
    const float* x        = (const float*)d_in[0];
    const float* W_qkv    = (const float*)d_in[1];
    const float* W_dw     = (const float*)d_in[2];
    const float* W_proj_s = (const float*)d_in[3];
    const float* scale_s  = (const float*)d_in[4];
    const float* W_ff1    = (const float*)d_in[5];
    const float* W_ff2    = (const float*)d_in[6];
    const float* W_proj_f = (const float*)d_in[7];
    const float* W_gsf    = (const float*)d_in[8];
    const float* b_gsf    = (const float*)d_in[9];
    const float* W_gfs    = (const float*)d_in[10];
    const float* b_gfs    = (const float*)d_in[11];
    float* out = (float*)d_out;

    char* ws = (char*)d_ws;
    const size_t MB64 = 67108864ull;
    float* V      = (float*)(ws + 0);           // 64 MiB, phase A
    float* out_s  = (float*)(ws + MB64);        // 64 MiB, lives to fuse2
    float* swb    = (float*)(ws + 0);           // phase B (V dead)
    float* out_fp = (float*)(ws + 0);           // chunks overwrite swb
    unsigned short* vcb = (unsigned short*)out; // 32 MiB bf16, d_out[0,32)
    float* Gp     = out + 8388608;              // 16 MiB, d_out[32,48)
    float* G      = out + 8388608 + 4194304;    // 512 KiB
    float* S      = G + 131072;                 // 64 KiB
    float2* A     = (float2*)out;               // 32 MiB, phase B
    float* pre    = out + 8388608;              // 16 MiB, phase B

    // --- spatial attention branch ---
    conv_mfma_k<<<2048, 256, 0, stream>>>(x, W_qkv + 256 * 128, V);
    dwconv_k<<<16384, 256, 0, stream>>>(V, W_dw, vcb);
    gram_mfma_k<<<256, 256, 0, stream>>>(x, Gp);
    gram_reduce_k<<<512, 256, 0, stream>>>(Gp, G);
    attn_s2_k<<<64, 256, 0, stream>>>(G, W_qkv, scale_s, S);
    proj_s_pv_k<<<2048, 256, 0, stream>>>(V, vcb, S, W_proj_s, out_s);

    // --- frequency branch ---
    ff_fused_k<<<2048, 256, 0, stream>>>(x, W_ff1, W_ff2, swb);
    for (int chunk = 0; chunk < 4; ++chunk) {
        const float* xc  = x   + (size_t)chunk * 4194304;
        const float* swc = swb + (size_t)chunk * 4194304;
        float* ofc = out_fp + (size_t)chunk * 4194304;
        fft_p1_k<<<2048, 256, 0, stream>>>(xc, swc, A);
        fft_p234_k<<<2048, 256, 0, stream>>>(A);
        fft_p5_k<<<2048, 256, 0, stream>>>(A, pre);
        conv_mfma_k<<<512, 256, 0, stream>>>(pre, W_proj_f, ofc);
    }

    // --- fused gates + final output ---
    fuse2_k<<<4096, 256, 0, stream>>>(x, out_s, out_fp,
                                      W_gsf, b_gsf, W_gfs, b_gfs, out);
}

// Round 9
// 561.297 us; speedup vs baseline: 3.3353x; 1.0620x over previous
//
#include <hip/hip_runtime.h>
#include <math.h>

#define HW 16384

typedef __attribute__((ext_vector_type(8))) short bf16x8;
typedef __attribute__((ext_vector_type(4))) float f32x4;

__device__ __forceinline__ unsigned f2bf_pk(float a, float b)
{
    unsigned ua = __float_as_uint(a), ub = __float_as_uint(b);
    ua = (ua + 0x7FFFu + ((ua >> 16) & 1u)) >> 16;   // RTN-even
    ub = (ub + 0x7FFFu + ((ub >> 16) & 1u)) >> 16;
    return (ua & 0xFFFFu) | (ub << 16);
}
__device__ __forceinline__ unsigned short f2bf(float a)
{
    unsigned ua = __float_as_uint(a);
    ua = (ua + 0x7FFFu + ((ua >> 16) & 1u)) >> 16;
    return (unsigned short)ua;
}
__device__ __forceinline__ float bf2f(unsigned short u)
{
    return __uint_as_float(((unsigned)u) << 16);
}
__device__ __forceinline__ int brev7(int v) { return (int)(__brev((unsigned)v) >> 25); }
__device__ __forceinline__ float sigmoidf_(float v) { return 1.f / (1.f + expf(-v)); }

// ---------------------------------------------------------------------------
// MFMA conv1x1, fp32 in -> bf16 out: out[b,o,n] = sum_c W[o,c] * in[b,c,n]
// Tile O=128 x N=64, K=128. LDS swizzle: 16B chunk ^= (row&7).
// ---------------------------------------------------------------------------
__global__ __launch_bounds__(256)
void conv_mfma_k(const float* __restrict__ in, const float* __restrict__ Wsrc,
                 unsigned short* __restrict__ out)
{
    __shared__ short WL[128 * 128];   // 32 KB
    __shared__ short XL[64 * 128];    // 16 KB
    int t = threadIdx.x;
    int gb = blockIdx.x;
    int b = gb >> 8;
    int n0 = (gb & 255) << 6;

    #pragma unroll
    for (int it = 0; it < 8; ++it) {
        int g = it * 256 + t;
        int o = g >> 4, c16 = g & 15;
        const float* wp = Wsrc + o * 128 + c16 * 8;
        int4 p;
        p.x = f2bf_pk(wp[0], wp[1]); p.y = f2bf_pk(wp[2], wp[3]);
        p.z = f2bf_pk(wp[4], wp[5]); p.w = f2bf_pk(wp[6], wp[7]);
        ((int4*)WL)[o * 16 + (c16 ^ (o & 7))] = p;
    }
    const float* inb = in + (size_t)b * 128 * HW + n0;
    int nl = t & 63;
    #pragma unroll
    for (int it = 0; it < 4; ++it) {
        int c8 = (t >> 6) + it * 4;
        float v[8];
        #pragma unroll
        for (int j = 0; j < 8; ++j) v[j] = inb[(size_t)(c8 * 8 + j) * HW + nl];
        int4 p;
        p.x = f2bf_pk(v[0], v[1]); p.y = f2bf_pk(v[2], v[3]);
        p.z = f2bf_pk(v[4], v[5]); p.w = f2bf_pk(v[6], v[7]);
        ((int4*)XL)[nl * 16 + (c8 ^ (nl & 7))] = p;
    }
    __syncthreads();

    int l = t & 63, w = t >> 6, kg = l >> 4, l15 = l & 15, l7 = l15 & 7;
    f32x4 acc[2][4];
    #pragma unroll
    for (int mf = 0; mf < 2; ++mf)
        #pragma unroll
        for (int nf = 0; nf < 4; ++nf) acc[mf][nf] = (f32x4){0.f, 0.f, 0.f, 0.f};
    #pragma unroll
    for (int ks = 0; ks < 4; ++ks) {
        int ch = ks * 4 + kg;
        bf16x8 A0 = ((const bf16x8*)WL)[(w * 32 + l15) * 16 + (ch ^ l7)];
        bf16x8 A1 = ((const bf16x8*)WL)[(w * 32 + 16 + l15) * 16 + (ch ^ l7)];
        #pragma unroll
        for (int nf = 0; nf < 4; ++nf) {
            bf16x8 Bf = ((const bf16x8*)XL)[(nf * 16 + l15) * 16 + (ch ^ l7)];
            acc[0][nf] = __builtin_amdgcn_mfma_f32_16x16x32_bf16(A0, Bf, acc[0][nf], 0, 0, 0);
            acc[1][nf] = __builtin_amdgcn_mfma_f32_16x16x32_bf16(A1, Bf, acc[1][nf], 0, 0, 0);
        }
    }
    #pragma unroll
    for (int mf = 0; mf < 2; ++mf)
        #pragma unroll
        for (int nf = 0; nf < 4; ++nf)
            #pragma unroll
            for (int i = 0; i < 4; ++i) {
                int row = w * 32 + mf * 16 + kg * 4 + i;
                int col = n0 + nf * 16 + l15;
                out[((size_t)b * 128 + row) * HW + col] = f2bf(acc[mf][nf][i]);
            }
}

// ---------------------------------------------------------------------------
// depthwise 3x3 SAME, x4 vectorized, bf16 in -> bf16 out
// ---------------------------------------------------------------------------
__global__ __launch_bounds__(256)
void dwconv_k(const unsigned short* __restrict__ V, const float* __restrict__ Wdw,
              unsigned short* __restrict__ vcb)
{
    int tid = blockIdx.x * 256 + threadIdx.x;
    int e4 = tid & 4095;
    int bc = tid >> 12;
    int c = bc & 127;
    int y = e4 >> 5;
    int x0 = (e4 & 31) << 2;
    const unsigned short* vin = V + (size_t)bc * HW;
    float wf[9];
    #pragma unroll
    for (int i = 0; i < 9; ++i) wf[i] = Wdw[c * 9 + i];
    float a0 = 0.f, a1 = 0.f, a2 = 0.f, a3 = 0.f;
    #pragma unroll
    for (int dy = 0; dy < 3; ++dy) {
        int yy = y + dy - 1;
        if (yy < 0 || yy > 127) continue;
        const unsigned short* r = vin + yy * 128;
        uint2 mu = *(const uint2*)(r + x0);
        float m0 = bf2f((unsigned short)(mu.x & 0xFFFF));
        float m1 = bf2f((unsigned short)(mu.x >> 16));
        float m2 = bf2f((unsigned short)(mu.y & 0xFFFF));
        float m3 = bf2f((unsigned short)(mu.y >> 16));
        float left  = (x0 > 0)   ? bf2f(r[x0 - 1]) : 0.f;
        float right = (x0 < 124) ? bf2f(r[x0 + 4]) : 0.f;
        float w0 = wf[dy * 3], w1 = wf[dy * 3 + 1], w2 = wf[dy * 3 + 2];
        a0 += w0 * left + w1 * m0 + w2 * m1;
        a1 += w0 * m0   + w1 * m1 + w2 * m2;
        a2 += w0 * m1   + w1 * m2 + w2 * m3;
        a3 += w0 * m2   + w1 * m3 + w2 * right;
    }
    uint2 r2;
    r2.x = f2bf_pk(a0, a1);
    r2.y = f2bf_pk(a2, a3);
    *(uint2*)(vcb + (size_t)bc * HW + y * 128 + x0) = r2;
}

// ---------------------------------------------------------------------------
// MFMA Gram partials: 32 slices of 512 px. blk = b*32+ks. grid 256.
// ---------------------------------------------------------------------------
__global__ __launch_bounds__(256)
void gram_mfma_k(const float* __restrict__ x, float* __restrict__ Gp)
{
    __shared__ short XL[128 * 128];
    int t = threadIdx.x;
    int blk = blockIdx.x;
    int b = blk >> 5, ks = blk & 31;
    const float* xb = x + (size_t)b * 128 * HW + ks * 512;
    int l = t & 63, w = t >> 6, kg = l >> 4, l15 = l & 15, l7 = l15 & 7;

    f32x4 acc[2][8];
    #pragma unroll
    for (int mf = 0; mf < 2; ++mf)
        #pragma unroll
        for (int nf = 0; nf < 8; ++nf) acc[mf][nf] = (f32x4){0.f, 0.f, 0.f, 0.f};

    for (int kc = 0; kc < 4; ++kc) {
        __syncthreads();
        #pragma unroll
        for (int it = 0; it < 8; ++it) {
            int g = it * 256 + t;
            int row = g >> 4, oct = g & 15;
            const float* p = xb + (size_t)row * HW + kc * 128 + oct * 8;
            int4 pk;
            pk.x = f2bf_pk(p[0], p[1]); pk.y = f2bf_pk(p[2], p[3]);
            pk.z = f2bf_pk(p[4], p[5]); pk.w = f2bf_pk(p[6], p[7]);
            ((int4*)XL)[row * 16 + (oct ^ (row & 7))] = pk;
        }
        __syncthreads();
        #pragma unroll
        for (int s = 0; s < 4; ++s) {
            int oct = s * 4 + kg;
            bf16x8 A0 = ((const bf16x8*)XL)[(w * 32 + l15) * 16 + (oct ^ l7)];
            bf16x8 A1 = ((const bf16x8*)XL)[(w * 32 + 16 + l15) * 16 + (oct ^ l7)];
            #pragma unroll
            for (int nf = 0; nf < 8; ++nf) {
                bf16x8 Bf = ((const bf16x8*)XL)[(nf * 16 + l15) * 16 + (oct ^ l7)];
                acc[0][nf] = __builtin_amdgcn_mfma_f32_16x16x32_bf16(A0, Bf, acc[0][nf], 0, 0, 0);
                acc[1][nf] = __builtin_amdgcn_mfma_f32_16x16x32_bf16(A1, Bf, acc[1][nf], 0, 0, 0);
            }
        }
    }
    float* gp = Gp + (size_t)blk * 16384;
    #pragma unroll
    for (int mf = 0; mf < 2; ++mf)
        #pragma unroll
        for (int nf = 0; nf < 8; ++nf)
            #pragma unroll
            for (int i = 0; i < 4; ++i) {
                int row = w * 32 + mf * 16 + kg * 4 + i;
                int col = nf * 16 + l15;
                gp[row * 128 + col] = acc[mf][nf][i];
            }
}

__global__ void gram_reduce_k(const float* __restrict__ Gp, float* __restrict__ G)
{
    int idx = blockIdx.x * 256 + threadIdx.x;   // 8*16384
    int b = idx >> 14;
    int ij = idx & 16383;
    const float* gp = Gp + (size_t)(b * 32) * 16384 + ij;
    float s = 0.f;
    #pragma unroll
    for (int ks = 0; ks < 32; ++ks) s += gp[(size_t)ks * 16384];
    G[idx] = s;
}

// ---------------------------------------------------------------------------
// S_h = softmax( (Wq_h G Wk_h^T) * scale[h] )
// ---------------------------------------------------------------------------
__global__ __launch_bounds__(256)
void attn_s2_k(const float* __restrict__ G, const float* __restrict__ Wqkv,
               const float* __restrict__ scale, float* __restrict__ S)
{
    __shared__ float Wq[16][129];
    __shared__ float Wk[16][129];
    __shared__ float Ts[16][129];
    int bh = blockIdx.x;
    int b = bh >> 3, h = bh & 7;
    int t = threadIdx.x;
    #pragma unroll
    for (int i = 0; i < 8; ++i) {
        int idx = t + i * 256;
        int r = idx >> 7, ci = idx & 127;
        Wq[r][ci] = Wqkv[(size_t)(h * 16 + r) * 128 + ci];
        Wk[r][ci] = Wqkv[(size_t)(128 + h * 16 + r) * 128 + ci];
    }
    __syncthreads();
    const float* Gb = G + (size_t)b * 16384;
    #pragma unroll
    for (int i = 0; i < 8; ++i) {
        int idx = t + i * 256;
        int c = idx >> 7, col = idx & 127;
        float s = 0.f;
        #pragma unroll 8
        for (int ci = 0; ci < 128; ++ci)
            s += Wq[c][ci] * Gb[ci * 128 + col];
        Ts[c][col] = s;
    }
    __syncthreads();
    int c = t >> 4, d = t & 15;
    float s = 0.f;
    #pragma unroll 8
    for (int col = 0; col < 128; ++col)
        s += Ts[c][col] * Wk[d][col];
    s *= scale[h];
    float m = s;
    #pragma unroll
    for (int w = 1; w < 16; w <<= 1)
        m = fmaxf(m, __shfl_xor(m, w, 64));
    float e = expf(s - m);
    float sum = e;
    #pragma unroll
    for (int w = 1; w < 16; w <<= 1)
        sum += __shfl_xor(sum, w, 64);
    S[(size_t)bh * 256 + t] = e / sum;
}

// ---------------------------------------------------------------------------
// proj_s with fused PV: out_s = W_proj_s @ (PV(V) + vconv), bf16 in/out.
// ---------------------------------------------------------------------------
__global__ __launch_bounds__(256)
void proj_s_pv_k(const unsigned short* __restrict__ V,
                 const unsigned short* __restrict__ vcb,
                 const float* __restrict__ S, const float* __restrict__ Wsrc,
                 unsigned short* __restrict__ out_s)
{
    __shared__ short WL[128 * 128];   // 32 KB
    __shared__ short XL[64 * 128];    // 16 KB
    __shared__ float SL[2048];        // 8 KB
    int t = threadIdx.x;
    int gb = blockIdx.x;
    int b = gb >> 8;
    int n0 = (gb & 255) << 6;

    #pragma unroll
    for (int it = 0; it < 8; ++it) {
        int g = it * 256 + t;
        int o = g >> 4, c16 = g & 15;
        const float* wp = Wsrc + o * 128 + c16 * 8;
        int4 p;
        p.x = f2bf_pk(wp[0], wp[1]); p.y = f2bf_pk(wp[2], wp[3]);
        p.z = f2bf_pk(wp[4], wp[5]); p.w = f2bf_pk(wp[6], wp[7]);
        ((int4*)WL)[o * 16 + (c16 ^ (o & 7))] = p;
    }
    #pragma unroll
    for (int i = 0; i < 8; ++i)
        SL[i * 256 + t] = S[(size_t)b * 2048 + i * 256 + t];
    __syncthreads();

    // PV staging: wave w handles heads 2w, 2w+1; lane -> col
    int col = t & 63, w = t >> 6;
    #pragma unroll
    for (int hh = 0; hh < 2; ++hh) {
        int h = w * 2 + hh;
        float v[16];
        #pragma unroll
        for (int d = 0; d < 16; ++d)
            v[d] = bf2f(V[((size_t)(b * 128 + h * 16 + d)) * HW + n0 + col]);
        float o[16];
        #pragma unroll
        for (int c = 0; c < 16; ++c) {
            const float* sl = SL + h * 256 + c * 16;
            float s = 0.f;
            #pragma unroll
            for (int d = 0; d < 16; ++d) s += sl[d] * v[d];
            o[c] = s + bf2f(vcb[((size_t)(b * 128 + h * 16 + c)) * HW + n0 + col]);
        }
        #pragma unroll
        for (int oc = 0; oc < 2; ++oc) {
            int octet = h * 2 + oc;
            int4 p;
            p.x = f2bf_pk(o[oc * 8 + 0], o[oc * 8 + 1]);
            p.y = f2bf_pk(o[oc * 8 + 2], o[oc * 8 + 3]);
            p.z = f2bf_pk(o[oc * 8 + 4], o[oc * 8 + 5]);
            p.w = f2bf_pk(o[oc * 8 + 6], o[oc * 8 + 7]);
            ((int4*)XL)[col * 16 + (octet ^ (col & 7))] = p;
        }
    }
    __syncthreads();

    int l = t & 63, kg = l >> 4, l15 = l & 15, l7 = l15 & 7;
    f32x4 acc[2][4];
    #pragma unroll
    for (int mf = 0; mf < 2; ++mf)
        #pragma unroll
        for (int nf = 0; nf < 4; ++nf) acc[mf][nf] = (f32x4){0.f, 0.f, 0.f, 0.f};
    #pragma unroll
    for (int ks = 0; ks < 4; ++ks) {
        int ch = ks * 4 + kg;
        bf16x8 A0 = ((const bf16x8*)WL)[(w * 32 + l15) * 16 + (ch ^ l7)];
        bf16x8 A1 = ((const bf16x8*)WL)[(w * 32 + 16 + l15) * 16 + (ch ^ l7)];
        #pragma unroll
        for (int nf = 0; nf < 4; ++nf) {
            bf16x8 Bf = ((const bf16x8*)XL)[(nf * 16 + l15) * 16 + (ch ^ l7)];
            acc[0][nf] = __builtin_amdgcn_mfma_f32_16x16x32_bf16(A0, Bf, acc[0][nf], 0, 0, 0);
            acc[1][nf] = __builtin_amdgcn_mfma_f32_16x16x32_bf16(A1, Bf, acc[1][nf], 0, 0, 0);
        }
    }
    #pragma unroll
    for (int mf = 0; mf < 2; ++mf)
        #pragma unroll
        for (int nf = 0; nf < 4; ++nf)
            #pragma unroll
            for (int i = 0; i < 4; ++i) {
                int row = w * 32 + mf * 16 + kg * 4 + i;
                int colg = n0 + nf * 16 + l15;
                out_s[((size_t)b * 128 + row) * HW + colg] = f2bf(acc[mf][nf][i]);
            }
}

// ---------------------------------------------------------------------------
// fused ff1 (GELU) + ff2: swb = W_ff2 @ gelu(W_ff1 @ x). fp32 out (FFT input).
// ---------------------------------------------------------------------------
__global__ __launch_bounds__(256)
void ff_fused_k(const float* __restrict__ x, const float* __restrict__ W1,
                const float* __restrict__ W2, float* __restrict__ outp)
{
    __shared__ short WL[128 * 128];   // 32 KB (W1 then W2)
    __shared__ short XL[64 * 128];    // 16 KB (x^T then gelu(mid)^T)
    int t = threadIdx.x;
    int gb = blockIdx.x;
    int b = gb >> 8;
    int n0 = (gb & 255) << 6;

    #pragma unroll
    for (int it = 0; it < 8; ++it) {
        int g = it * 256 + t;
        int o = g >> 4, c16 = g & 15;
        const float* wp = W1 + o * 128 + c16 * 8;
        int4 p;
        p.x = f2bf_pk(wp[0], wp[1]); p.y = f2bf_pk(wp[2], wp[3]);
        p.z = f2bf_pk(wp[4], wp[5]); p.w = f2bf_pk(wp[6], wp[7]);
        ((int4*)WL)[o * 16 + (c16 ^ (o & 7))] = p;
    }
    const float* inb = x + (size_t)b * 128 * HW + n0;
    int nl = t & 63;
    #pragma unroll
    for (int it = 0; it < 4; ++it) {
        int c8 = (t >> 6) + it * 4;
        float v[8];
        #pragma unroll
        for (int j = 0; j < 8; ++j) v[j] = inb[(size_t)(c8 * 8 + j) * HW + nl];
        int4 p;
        p.x = f2bf_pk(v[0], v[1]); p.y = f2bf_pk(v[2], v[3]);
        p.z = f2bf_pk(v[4], v[5]); p.w = f2bf_pk(v[6], v[7]);
        ((int4*)XL)[nl * 16 + (c8 ^ (nl & 7))] = p;
    }
    __syncthreads();

    int l = t & 63, w = t >> 6, kg = l >> 4, l15 = l & 15, l7 = l15 & 7;
    f32x4 acc[2][4];
    #pragma unroll
    for (int mf = 0; mf < 2; ++mf)
        #pragma unroll
        for (int nf = 0; nf < 4; ++nf) acc[mf][nf] = (f32x4){0.f, 0.f, 0.f, 0.f};
    #pragma unroll
    for (int ks = 0; ks < 4; ++ks) {
        int ch = ks * 4 + kg;
        bf16x8 A0 = ((const bf16x8*)WL)[(w * 32 + l15) * 16 + (ch ^ l7)];
        bf16x8 A1 = ((const bf16x8*)WL)[(w * 32 + 16 + l15) * 16 + (ch ^ l7)];
        #pragma unroll
        for (int nf = 0; nf < 4; ++nf) {
            bf16x8 Bf = ((const bf16x8*)XL)[(nf * 16 + l15) * 16 + (ch ^ l7)];
            acc[0][nf] = __builtin_amdgcn_mfma_f32_16x16x32_bf16(A0, Bf, acc[0][nf], 0, 0, 0);
            acc[1][nf] = __builtin_amdgcn_mfma_f32_16x16x32_bf16(A1, Bf, acc[1][nf], 0, 0, 0);
        }
    }
    __syncthreads();   // all GEMM1 LDS reads done

    // restage W2 over WL; write gelu(acc) transposed into XL
    #pragma unroll
    for (int it = 0; it < 8; ++it) {
        int g = it * 256 + t;
        int o = g >> 4, c16 = g & 15;
        const float* wp = W2 + o * 128 + c16 * 8;
        int4 p;
        p.x = f2bf_pk(wp[0], wp[1]); p.y = f2bf_pk(wp[2], wp[3]);
        p.z = f2bf_pk(wp[4], wp[5]); p.w = f2bf_pk(wp[6], wp[7]);
        ((int4*)WL)[o * 16 + (c16 ^ (o & 7))] = p;
    }
    #pragma unroll
    for (int mf = 0; mf < 2; ++mf)
        #pragma unroll
        for (int nf = 0; nf < 4; ++nf) {
            float g4[4];
            #pragma unroll
            for (int i = 0; i < 4; ++i) {
                float v = acc[mf][nf][i];
                g4[i] = 0.5f * v * (1.0f + erff(v * 0.70710678118654752f));
            }
            int col = nf * 16 + l15;
            int r0 = w * 32 + mf * 16 + kg * 4;
            int octet = r0 >> 3;
            uint2 pk2;
            pk2.x = f2bf_pk(g4[0], g4[1]);
            pk2.y = f2bf_pk(g4[2], g4[3]);
            ((uint2*)XL)[(col * 16 + (octet ^ (col & 7))) * 2 + (kg & 1)] = pk2;
        }
    __syncthreads();

    f32x4 acc2[2][4];
    #pragma unroll
    for (int mf = 0; mf < 2; ++mf)
        #pragma unroll
        for (int nf = 0; nf < 4; ++nf) acc2[mf][nf] = (f32x4){0.f, 0.f, 0.f, 0.f};
    #pragma unroll
    for (int ks = 0; ks < 4; ++ks) {
        int ch = ks * 4 + kg;
        bf16x8 A0 = ((const bf16x8*)WL)[(w * 32 + l15) * 16 + (ch ^ l7)];
        bf16x8 A1 = ((const bf16x8*)WL)[(w * 32 + 16 + l15) * 16 + (ch ^ l7)];
        #pragma unroll
        for (int nf = 0; nf < 4; ++nf) {
            bf16x8 Bf = ((const bf16x8*)XL)[(nf * 16 + l15) * 16 + (ch ^ l7)];
            acc2[0][nf] = __builtin_amdgcn_mfma_f32_16x16x32_bf16(A0, Bf, acc2[0][nf], 0, 0, 0);
            acc2[1][nf] = __builtin_amdgcn_mfma_f32_16x16x32_bf16(A1, Bf, acc2[1][nf], 0, 0, 0);
        }
    }
    #pragma unroll
    for (int mf = 0; mf < 2; ++mf)
        #pragma unroll
        for (int nf = 0; nf < 4; ++nf)
            #pragma unroll
            for (int i = 0; i < 4; ++i) {
                int row = w * 32 + mf * 16 + kg * 4 + i;
                int col = n0 + nf * 16 + l15;
                outp[((size_t)b * 128 + row) * HW + col] = acc2[mf][nf][i];
            }
}

// ---------------------------------------------------------------------------
// fused gates + final: out = x + out_s*sigmoid(Wgfs@out_f+bgfs)
//                            + out_f*sigmoid(Wgsf@out_s+bgsf)
// outs/outf are bf16. Epilogue re-reads os/of from global (L2-hot, coalesced).
// ---------------------------------------------------------------------------
__global__ __launch_bounds__(256)
void fuse2_k(const float* __restrict__ x, const unsigned short* __restrict__ outs,
             const unsigned short* __restrict__ outf,
             const float* __restrict__ Wgsf, const float* __restrict__ bgsf,
             const float* __restrict__ Wgfs, const float* __restrict__ bgfs,
             float* __restrict__ out)
{
    __shared__ short WS[64 * 128];  // W_gsf half rows (16 KB)
    __shared__ short WF[64 * 128];  // W_gfs half rows
    __shared__ short XS[64 * 128];  // out_s^T tile (all 128 ch)
    __shared__ short XF[64 * 128];  // out_f^T tile
    int t = threadIdx.x;
    int gb = blockIdx.x;
    int half = gb & 1;
    int nt = (gb >> 1) & 255;
    int b = gb >> 9;
    int n0 = nt << 6;

    #pragma unroll
    for (int it = 0; it < 4; ++it) {
        int g = it * 256 + t;          // 0..1023 chunks
        int o = g >> 4, c16 = g & 15;
        const float* w1 = Wgsf + (size_t)(half * 64 + o) * 128 + c16 * 8;
        const float* w2 = Wgfs + (size_t)(half * 64 + o) * 128 + c16 * 8;
        int4 p1, p2;
        p1.x = f2bf_pk(w1[0], w1[1]); p1.y = f2bf_pk(w1[2], w1[3]);
        p1.z = f2bf_pk(w1[4], w1[5]); p1.w = f2bf_pk(w1[6], w1[7]);
        p2.x = f2bf_pk(w2[0], w2[1]); p2.y = f2bf_pk(w2[2], w2[3]);
        p2.z = f2bf_pk(w2[4], w2[5]); p2.w = f2bf_pk(w2[6], w2[7]);
        ((int4*)WS)[o * 16 + (c16 ^ (o & 7))] = p1;
        ((int4*)WF)[o * 16 + (c16 ^ (o & 7))] = p2;
    }
    const unsigned short* sb = outs + (size_t)b * 128 * HW + n0;
    const unsigned short* fb = outf + (size_t)b * 128 * HW + n0;
    int nl = t & 63;
    #pragma unroll
    for (int it = 0; it < 4; ++it) {
        int c8 = (t >> 6) + it * 4;
        unsigned us[8], uf[8];
        #pragma unroll
        for (int j = 0; j < 8; ++j) {
            size_t a = (size_t)(c8 * 8 + j) * HW + nl;
            us[j] = sb[a];
            uf[j] = fb[a];
        }
        int4 ps, pf;
        ps.x = (int)(us[0] | (us[1] << 16)); ps.y = (int)(us[2] | (us[3] << 16));
        ps.z = (int)(us[4] | (us[5] << 16)); ps.w = (int)(us[6] | (us[7] << 16));
        pf.x = (int)(uf[0] | (uf[1] << 16)); pf.y = (int)(uf[2] | (uf[3] << 16));
        pf.z = (int)(uf[4] | (uf[5] << 16)); pf.w = (int)(uf[6] | (uf[7] << 16));
        ((int4*)XS)[nl * 16 + (c8 ^ (nl & 7))] = ps;
        ((int4*)XF)[nl * 16 + (c8 ^ (nl & 7))] = pf;
    }
    __syncthreads();

    int l = t & 63, w = t >> 6, kg = l >> 4, l15 = l & 15, l7 = l15 & 7;
    f32x4 aS[4], aF[4];
    #pragma unroll
    for (int nf = 0; nf < 4; ++nf) {
        aS[nf] = (f32x4){0.f, 0.f, 0.f, 0.f};
        aF[nf] = (f32x4){0.f, 0.f, 0.f, 0.f};
    }
    #pragma unroll
    for (int ks = 0; ks < 4; ++ks) {
        int ch = ks * 4 + kg;
        bf16x8 As = ((const bf16x8*)WS)[(w * 16 + l15) * 16 + (ch ^ l7)];
        bf16x8 Af = ((const bf16x8*)WF)[(w * 16 + l15) * 16 + (ch ^ l7)];
        #pragma unroll
        for (int nf = 0; nf < 4; ++nf) {
            bf16x8 Bs = ((const bf16x8*)XS)[(nf * 16 + l15) * 16 + (ch ^ l7)];
            bf16x8 Bf = ((const bf16x8*)XF)[(nf * 16 + l15) * 16 + (ch ^ l7)];
            aS[nf] = __builtin_amdgcn_mfma_f32_16x16x32_bf16(As, Bs, aS[nf], 0, 0, 0);
            aF[nf] = __builtin_amdgcn_mfma_f32_16x16x32_bf16(Af, Bf, aF[nf], 0, 0, 0);
        }
    }
    #pragma unroll
    for (int nf = 0; nf < 4; ++nf)
        #pragma unroll
        for (int i = 0; i < 4; ++i) {
            int row = half * 64 + w * 16 + kg * 4 + i;
            int cc = nf * 16 + l15;
            float gf = sigmoidf_(aS[nf][i] + bgsf[row]);   // gates out_f
            float gs = sigmoidf_(aF[nf][i] + bgfs[row]);   // gates out_s
            size_t gi = ((size_t)(b * 128) + row) * HW + n0 + cc;
            float os = bf2f(outs[gi]);
            float of = bf2f(outf[gi]);
            out[gi] = x[gi] + os * gs + of * gf;
        }
}

// ---------------------------------------------------------------------------
// FFT: radix-2 128-pt, LDS twiddles
// ---------------------------------------------------------------------------
__device__ __forceinline__ void fft_build_tw(float2* tw, int t)
{
    if (t < 64) {
        float ang = 0.049087385212340519f * (float)t;
        float sn, cs; sincosf(ang, &sn, &cs);
        tw[t] = make_float2(cs, sn);
    }
}

__device__ __forceinline__ void fft_stage_dif(float2 (*buf)[128], const float2* tw,
                                              int t, int s)
{
    int mh = 64 >> s;
    #pragma unroll
    for (int i = 0; i < 4; ++i) {
        int idx = t + i * 256;
        int rl = idx >> 6;
        int bf = idx & 63;
        int blk = bf >> (6 - s);
        int jj = bf & (mh - 1);
        int base = (blk << (7 - s)) + jj;
        float2 a = buf[rl][base];
        float2 b = buf[rl][base + mh];
        float2 w = tw[jj << s];
        float cs = w.x, sn = -w.y;
        float dx = a.x - b.x, dy = a.y - b.y;
        buf[rl][base] = make_float2(a.x + b.x, a.y + b.y);
        buf[rl][base + mh] = make_float2(dx * cs - dy * sn, dx * sn + dy * cs);
    }
}

__device__ __forceinline__ void fft_stage_dit(float2 (*buf)[128], const float2* tw,
                                              int t, int s)
{
    int mh = 64 >> s;
    #pragma unroll
    for (int i = 0; i < 4; ++i) {
        int idx = t + i * 256;
        int rl = idx >> 6;
        int bf = idx & 63;
        int blk = bf >> (6 - s);
        int jj = bf & (mh - 1);
        int base = (blk << (7 - s)) + jj;
        float2 a = buf[rl][base];
        float2 b = buf[rl][base + mh];
        float2 w = tw[jj << s];
        float cs = w.x, sn = w.y;
        float tx = b.x * cs - b.y * sn, ty = b.x * sn + b.y * cs;
        buf[rl][base] = make_float2(a.x + tx, a.y + ty);
        buf[rl][base + mh] = make_float2(a.x - tx, a.y - ty);
    }
}

__device__ __forceinline__ void fft16_fwd(float2 (*buf)[128], const float2* tw, int t)
{
    for (int s = 0; s < 7; ++s) { __syncthreads(); fft_stage_dif(buf, tw, t, s); }
    __syncthreads();
}
__device__ __forceinline__ void fft16_inv(float2 (*buf)[128], const float2* tw, int t)
{
    for (int s = 6; s >= 0; --s) { __syncthreads(); fft_stage_dit(buf, tw, t, s); }
    __syncthreads();
}

__global__ __launch_bounds__(256)
void fft_p1_k(const float* __restrict__ x, const float* __restrict__ sw,
              float2* __restrict__ A)
{
    __shared__ float2 buf[16][128];
    __shared__ float2 tw[64];
    int t = threadIdx.x;
    fft_build_tw(tw, t);
    int ch = blockIdx.x >> 3;
    int rg = blockIdx.x & 7;
    size_t base = (size_t)ch * HW + rg * 2048;
    #pragma unroll
    for (int i = 0; i < 8; ++i) {
        int idx = t + i * 256;
        int rl = idx >> 7, cc = idx & 127;
        buf[rl][cc] = make_float2(x[base + rl * 128 + cc], sw[base + rl * 128 + cc]);
    }
    fft16_fwd(buf, tw, t);
    size_t abase = (size_t)ch * HW + rg * 16;
    #pragma unroll
    for (int i = 0; i < 8; ++i) {
        int idx = t + i * 256;
        int rl = idx & 15, k1 = idx >> 4;
        A[abase + (size_t)k1 * 128 + rl] = buf[rl][k1];
    }
}

__global__ __launch_bounds__(256)
void fft_p234_k(float2* __restrict__ A)
{
    __shared__ float2 buf[16][128];
    __shared__ float2 tw[64];
    int t = threadIdx.x;
    fft_build_tw(tw, t);
    int ch = blockIdx.x >> 3;
    int rg = blockIdx.x & 7;
    size_t cb = (size_t)ch * HW;

    #pragma unroll
    for (int i = 0; i < 8; ++i) {
        int idx = t + i * 256;
        int l = idx >> 7, cc = idx & 127;
        int k1l;
        if (rg == 0) k1l = (l < 2) ? l * 64 : (l < 9 ? l - 1 : 128 - (l - 8));
        else         k1l = (l < 8) ? 8 * rg + l : 128 - (8 * rg + l - 8);
        buf[l][cc] = A[cb + (size_t)brev7(k1l) * 128 + cc];
    }
    fft16_fwd(buf, tw, t);

    int nItems = (rg == 0) ? 1026 : 1024;
    for (int item = t; item < nItems; item += 256) {
        int lA, lB, k2;
        if (rg == 0) {
            if (item < 896) { int s = item >> 7; k2 = item & 127; lA = 2 + s; lB = 9 + s; }
            else            { int r = item - 896; lA = lB = r / 65; k2 = r % 65; }
        } else {
            int s = item >> 7; k2 = item & 127; lA = s; lB = 8 + s;
        }
        int i2 = brev7(k2), j2 = brev7((128 - k2) & 127);
        float2 z1 = buf[lA][i2];
        float2 z2 = buf[lB][j2];
        float2 X = make_float2(0.5f * (z1.x + z2.x), 0.5f * (z1.y - z2.y));
        float Dx = z1.x - z2.x, Dy = z1.y + z2.y;
        float2 Wf = make_float2(0.5f * Dy, -0.5f * Dx);
        float2 Y = make_float2(X.x * Wf.x - X.y * Wf.y, X.x * Wf.y + X.y * Wf.x);
        buf[lA][i2] = Y;
        buf[lB][j2] = make_float2(Y.x, -Y.y);
    }
    fft16_inv(buf, tw, t);

    #pragma unroll
    for (int i = 0; i < 8; ++i) {
        int idx = t + i * 256;
        int l = idx >> 7, cc = idx & 127;
        int k1l;
        if (rg == 0) k1l = (l < 2) ? l * 64 : (l < 9 ? l - 1 : 128 - (l - 8));
        else         k1l = (l < 8) ? 8 * rg + l : 128 - (8 * rg + l - 8);
        A[cb + (size_t)brev7(k1l) * 128 + cc] = buf[l][cc];
    }
}

__global__ __launch_bounds__(256)
void fft_p5_k(const float2* __restrict__ A, float* __restrict__ outp)
{
    __shared__ float2 buf[16][128];
    __shared__ float2 tw[64];
    int t = threadIdx.x;
    fft_build_tw(tw, t);
    int ch = blockIdx.x >> 3;
    int rg = blockIdx.x & 7;
    size_t abase = (size_t)ch * HW + rg * 16;
    #pragma unroll
    for (int i = 0; i < 8; ++i) {
        int idx = t + i * 256;
        int rl = idx & 15, i1 = idx >> 4;
        buf[rl][i1] = A[abase + (size_t)i1 * 128 + rl];
    }
    fft16_inv(buf, tw, t);
    const float scale = 1.f / 2097152.f;
    size_t obase = (size_t)ch * HW + rg * 2048;
    #pragma unroll
    for (int i = 0; i < 8; ++i) {
        int idx = t + i * 256;
        int rl = idx >> 7, cc = idx & 127;
        outp[obase + rl * 128 + cc] = buf[rl][cc].x * scale;
    }
}

// ---------------------------------------------------------------------------
// Workspace plan (peak 128 MiB ws + d_out scratch):
//  phase A: V bf16 ws[0,32); vcb bf16 d_out[0,32); Gp d_out[32,48); G,S after;
//           out_s bf16 -> ws[32,64).
//  phase B: swb fp32 ws[64,128); per 2-batch chunk: A d_out[0,32),
//           pre d_out[32,48), out_f bf16 chunk -> ws[0,32) (V dead).
//  fuse2:   reads out_s ws[32,64), out_f ws[0,32), x; writes d_out.
// ---------------------------------------------------------------------------
extern "C" void kernel_launch(void* const* d_in, const int* in_sizes, int n_in,
                              void* d_out, int out_size, void* d_ws, size_t ws_size,
                              hipStream_t stream)
{
    const float* x        = (const float*)d_in[0];
    const float* W_qkv    = (const float*)d_in[1];
    const float* W_dw     = (const float*)d_in[2];
    const float* W_proj_s = (const float*)d_in[3];
    const float* scale_s  = (const float*)d_in[4];
    const float* W_ff1    = (const float*)d_in[5];
    const float* W_ff2    = (const float*)d_in[6];
    const float* W_proj_f = (const float*)d_in[7];
    const float* W_gsf    = (const float*)d_in[8];
    const float* b_gsf    = (const float*)d_in[9];
    const float* W_gfs    = (const float*)d_in[10];
    const float* b_gfs    = (const float*)d_in[11];
    float* out = (float*)d_out;

    char* ws = (char*)d_ws;
    const size_t MB32 = 33554432ull;
    const size_t MB64 = 67108864ull;
    unsigned short* V     = (unsigned short*)(ws);          // 32 MiB phase A
    unsigned short* out_s = (unsigned short*)(ws + MB32);   // 32 MiB
    float* swb            = (float*)(ws + MB64);            // 64 MiB
    unsigned short* out_fp= (unsigned short*)(ws);          // 32 MiB (V dead)
    unsigned short* vcb   = (unsigned short*)out;           // 32 MiB d_out lo
    float* Gp  = out + 8388608;                             // 16 MiB d_out[32,48)
    float* G   = out + 8388608 + 4194304;                   // 512 KiB
    float* S   = G + 131072;                                // 64 KiB
    float2* A  = (float2*)out;                              // 32 MiB phase B
    float* pre = out + 8388608;                             // 16 MiB phase B

    // --- spatial attention branch ---
    conv_mfma_k<<<2048, 256, 0, stream>>>(x, W_qkv + 256 * 128, V);
    dwconv_k<<<16384, 256, 0, stream>>>(V, W_dw, vcb);
    gram_mfma_k<<<256, 256, 0, stream>>>(x, Gp);
    gram_reduce_k<<<512, 256, 0, stream>>>(Gp, G);
    attn_s2_k<<<64, 256, 0, stream>>>(G, W_qkv, scale_s, S);
    proj_s_pv_k<<<2048, 256, 0, stream>>>(V, vcb, S, W_proj_s, out_s);

    // --- frequency branch ---
    ff_fused_k<<<2048, 256, 0, stream>>>(x, W_ff1, W_ff2, swb);
    for (int chunk = 0; chunk < 4; ++chunk) {
        const float* xc  = x   + (size_t)chunk * 4194304;
        const float* swc = swb + (size_t)chunk * 4194304;
        unsigned short* ofc = out_fp + (size_t)chunk * 4194304;
        fft_p1_k<<<2048, 256, 0, stream>>>(xc, swc, A);
        fft_p234_k<<<2048, 256, 0, stream>>>(A);
        fft_p5_k<<<2048, 256, 0, stream>>>(A, pre);
        conv_mfma_k<<<512, 256, 0, stream>>>(pre, W_proj_f, ofc);
    }

    // --- fused gates + final output ---
    fuse2_k<<<4096, 256, 0, stream>>>(x, out_s, out_fp,
                                      W_gsf, b_gsf, W_gfs, b_gfs, out);
}